// Round 1
// baseline (1879.157 us; speedup 1.0000x reference)
//
#include <hip/hip_runtime.h>
#include <math.h>

#define N_NODES 10000
#define N_EDGESC 100000
#define BB 8192
#define KK 10
#define MEMD 172
#define TED 172
#define EFD 172
#define EMBD 172
#define HIDD 80
#define MSGD 688   // 2*MEM + TE + EF
#define F1D 516    // EMB + TE + EF   (lin1 input)
#define F2D 516    // MEM + TE + EMB  (lin2 input)

__global__ void init_lastidx(int* __restrict__ last_idx) {
    int i = blockIdx.x * blockDim.x + threadIdx.x;
    if (i < N_NODES) last_idx[i] = -1;
}

__global__ void scatter_last(const int* __restrict__ sources, int* __restrict__ last_idx) {
    int b = blockIdx.x * blockDim.x + threadIdx.x;
    if (b < BB) atomicMax(&last_idx[sources[b]], b);
}

// one block per node: mem_out[n] = updated (or copied) memory
__global__ __launch_bounds__(192) void rnn_update(
    const int* __restrict__ last_idx,
    const int* __restrict__ destinations,
    const int* __restrict__ edge_idxs,
    const float* __restrict__ timestamps,
    const float* __restrict__ last_updated,
    const float* __restrict__ node_mem,
    const float* __restrict__ edge_features,
    const float* __restrict__ time_w,
    const float* __restrict__ time_b,
    const float* __restrict__ Wih,
    const float* __restrict__ Whh,
    const float* __restrict__ bih,
    const float* __restrict__ bhh,
    float* __restrict__ mem_out)
{
    const int n = blockIdx.x;
    const int t = threadIdx.x;
    const int li = last_idx[n];
    if (li < 0) {
        for (int f = t; f < MEMD; f += blockDim.x)
            mem_out[n * MEMD + f] = node_mem[n * MEMD + f];
        return;
    }
    __shared__ float msg[MSGD];
    const int dst = destinations[li];
    const int ei  = edge_idxs[li];
    const float dt = timestamps[li] - last_updated[n];
    for (int f = t; f < MEMD; f += blockDim.x) {
        msg[f]            = node_mem[n * MEMD + f];   // src_mem (sources[li] == n)
        msg[MEMD + f]     = node_mem[dst * MEMD + f]; // dst_mem
        msg[2 * MEMD + f] = edge_features[ei * EFD + f];
        msg[3 * MEMD + f] = cosf(dt * time_w[f] + time_b[f]);
    }
    __syncthreads();
    if (t < MEMD) {
        float acc = bih[t] + bhh[t];
        const float* wr = &Wih[t * MSGD];
        #pragma unroll 4
        for (int f = 0; f < MSGD; ++f) acc += msg[f] * wr[f];
        const float* hr = &Whh[t * MEMD];
        #pragma unroll 4
        for (int m = 0; m < MEMD; ++m) acc += msg[m] * hr[m];  // msg[0:MEM) == node_mem[n]
        mem_out[n * MEMD + t] = tanhf(acc);
    }
}

// one block per batch row: aggregate neighbors, lin1(sum-folded), lin2, MLP head
__global__ __launch_bounds__(256) void embed_kernel(
    const float* __restrict__ mem,
    const float* __restrict__ tnf,
    const float* __restrict__ edge_features,
    const float* __restrict__ timestamps,
    const float* __restrict__ nbr_edge_times,
    const int* __restrict__ sources,
    const int* __restrict__ neighbors,
    const int* __restrict__ nbr_edge_idxs,
    const float* __restrict__ time_w,
    const float* __restrict__ time_b,
    const float* __restrict__ lin1_w, const float* __restrict__ lin1_b,
    const float* __restrict__ lin2_w, const float* __restrict__ lin2_b,
    const float* __restrict__ w1, const float* __restrict__ b1,
    const float* __restrict__ w2, const float* __restrict__ b2,
    const float* __restrict__ w3, const float* __restrict__ b3,
    float* __restrict__ out)
{
    const int b = blockIdx.x;
    const int t = threadIdx.x;

    __shared__ float g[F1D];     // sum_k nf[b,k,:]
    __shared__ float cat2[F2D];  // [nbr_sum(172) | src_feat(172) | src_t_enc(172)]
    __shared__ float emb[EMBD];
    __shared__ float h1[HIDD];
    __shared__ float h2[10];

    const float ts = timestamps[b];

    // aggregate nf over k (each thread owns fixed f slots -> no races)
    for (int f = t; f < F1D; f += 256) {
        float acc = 0.f;
        for (int k = 0; k < KK; ++k) {
            const int nbr = neighbors[b * KK + k];
            if (f < MEMD) {
                acc += mem[nbr * MEMD + f] + tnf[nbr * MEMD + f];
            } else if (f < MEMD + TED) {
                const int j = f - MEMD;
                const float net = nbr_edge_times[b * KK + k];
                acc += cosf((ts - net) * time_w[j] + time_b[j]);
            } else {
                const int j = f - MEMD - TED;
                const int nei = nbr_edge_idxs[b * KK + k];
                acc += edge_features[nei * EFD + j];
            }
        }
        g[f] = acc;
    }

    // src_feat + src_t_enc
    const int s = sources[b];
    for (int f = t; f < MEMD; f += 256) {
        cat2[EMBD + f]        = mem[s * MEMD + f] + tnf[s * MEMD + f];
        cat2[EMBD + MEMD + f] = cosf(time_b[f]);
    }
    __syncthreads();

    // lin1 folded over the k-sum: sum_k h1 = g @ W1^T + K*b1, then relu
    if (t < EMBD) {
        float acc = (float)KK * lin1_b[t];
        const float* wr = &lin1_w[t * F1D];
        #pragma unroll 4
        for (int f = 0; f < F1D; ++f) acc += g[f] * wr[f];
        cat2[t] = fmaxf(acc, 0.f);
    }
    __syncthreads();

    // lin2
    if (t < EMBD) {
        float acc = lin2_b[t];
        const float* wr = &lin2_w[t * F2D];
        #pragma unroll 4
        for (int f = 0; f < F2D; ++f) acc += cat2[f] * wr[f];
        emb[t] = acc;
    }
    __syncthreads();

    // MLP head
    if (t < HIDD) {
        float acc = b1[t];
        const float* wr = &w1[t * EMBD];
        #pragma unroll 4
        for (int f = 0; f < EMBD; ++f) acc += emb[f] * wr[f];
        h1[t] = fmaxf(acc, 0.f);
    }
    __syncthreads();
    if (t < 10) {
        float acc = b2[t];
        const float* wr = &w2[t * HIDD];
        for (int f = 0; f < HIDD; ++f) acc += h1[f] * wr[f];
        h2[t] = fmaxf(acc, 0.f);
    }
    __syncthreads();
    if (t == 0) {
        float acc = b3[0];
        for (int j = 0; j < 10; ++j) acc += h2[j] * w3[j];
        out[b] = 1.f / (1.f + expf(-acc));
    }
}

extern "C" void kernel_launch(void* const* d_in, const int* in_sizes, int n_in,
                              void* d_out, int out_size, void* d_ws, size_t ws_size,
                              hipStream_t stream) {
    const float* timestamps     = (const float*)d_in[0];
    const float* edge_features  = (const float*)d_in[1];
    const float* tnf            = (const float*)d_in[2];
    const float* node_mem       = (const float*)d_in[3];
    const float* last_updated   = (const float*)d_in[4];
    const float* nbr_edge_times = (const float*)d_in[5];
    const float* time_w         = (const float*)d_in[6];
    const float* time_b         = (const float*)d_in[7];
    const float* Wih            = (const float*)d_in[8];
    const float* Whh            = (const float*)d_in[9];
    const float* bih            = (const float*)d_in[10];
    const float* bhh            = (const float*)d_in[11];
    const float* lin1_w         = (const float*)d_in[12];
    const float* lin1_b         = (const float*)d_in[13];
    const float* lin2_w         = (const float*)d_in[14];
    const float* lin2_b         = (const float*)d_in[15];
    const float* w1             = (const float*)d_in[16];
    const float* b1             = (const float*)d_in[17];
    const float* w2             = (const float*)d_in[18];
    const float* b2             = (const float*)d_in[19];
    const float* w3             = (const float*)d_in[20];
    const float* b3             = (const float*)d_in[21];
    const int* sources          = (const int*)d_in[22];
    const int* destinations     = (const int*)d_in[23];
    const int* edge_idxs        = (const int*)d_in[24];
    const int* neighbors        = (const int*)d_in[25];
    const int* nbr_edge_idxs    = (const int*)d_in[26];
    float* out = (float*)d_out;

    int* last_idx = (int*)d_ws;
    float* mem = (float*)((char*)d_ws + ((N_NODES * sizeof(int) + 255) / 256) * 256);

    hipLaunchKernelGGL(init_lastidx, dim3((N_NODES + 255) / 256), dim3(256), 0, stream, last_idx);
    hipLaunchKernelGGL(scatter_last, dim3((BB + 255) / 256), dim3(256), 0, stream, sources, last_idx);
    hipLaunchKernelGGL(rnn_update, dim3(N_NODES), dim3(192), 0, stream,
                       last_idx, destinations, edge_idxs, timestamps, last_updated,
                       node_mem, edge_features, time_w, time_b,
                       Wih, Whh, bih, bhh, mem);
    hipLaunchKernelGGL(embed_kernel, dim3(BB), dim3(256), 0, stream,
                       mem, tnf, edge_features, timestamps, nbr_edge_times,
                       sources, neighbors, nbr_edge_idxs, time_w, time_b,
                       lin1_w, lin1_b, lin2_w, lin2_b,
                       w1, b1, w2, b2, w3, b3, out);
}

// Round 2
// 462.080 us; speedup vs baseline: 4.0667x; 4.0667x over previous
//
#include <hip/hip_runtime.h>
#include <math.h>

#define N_NODES 10000
#define BB 8192
#define KK 10
#define D 172            // MEM = TE = EF = EMB
#define HIDD 80
#define BK 43            // all K dims are multiples of 43 (172 = 4*43)
#define BM 32
#define ALD 44           // As leading dim (padded)

// ---------------- small prep kernels ----------------

__global__ void init_lastidx(int* __restrict__ last_idx) {
    int i = blockIdx.x * blockDim.x + threadIdx.x;
    if (i < N_NODES) last_idx[i] = -1;
}

__global__ void scatter_last(const int* __restrict__ sources, int* __restrict__ last_idx) {
    int b = blockIdx.x * blockDim.x + threadIdx.x;
    if (b < BB) atomicMax(&last_idx[sources[b]], b);
}

// tiled transpose with zero-pad: WT[k*BNp + n] = (n<N) ? W[n*ldW + k] : 0
__global__ void transpose_pad(const float* __restrict__ W, float* __restrict__ WT,
                              int N, int K, int ldW, int BNp) {
    __shared__ float tile[32][33];
    int kb = blockIdx.x * 32, nb = blockIdx.y * 32;
    int tx = threadIdx.x & 31, ty = threadIdx.x >> 5;   // 256 thr: ty 0..7
    for (int i = ty; i < 32; i += 8) {
        int n = nb + i, k = kb + tx;
        tile[i][tx] = (n < N && k < K) ? W[n * ldW + k] : 0.f;
    }
    __syncthreads();
    for (int i = ty; i < 32; i += 8) {
        int k = kb + i, n = nb + tx;
        if (k < K && n < BNp) WT[k * BNp + n] = tile[tx][i];
    }
}

// WT[k*BNp + n] += W[n*ldW + k]  (fold Whh into W_comb first 172 rows)
__global__ void transpose_add(const float* __restrict__ W, float* __restrict__ WT,
                              int N, int K, int ldW, int BNp) {
    __shared__ float tile[32][33];
    int kb = blockIdx.x * 32, nb = blockIdx.y * 32;
    int tx = threadIdx.x & 31, ty = threadIdx.x >> 5;
    for (int i = ty; i < 32; i += 8) {
        int n = nb + i, k = kb + tx;
        tile[i][tx] = (n < N && k < K) ? W[n * ldW + k] : 0.f;
    }
    __syncthreads();
    for (int i = ty; i < 32; i += 8) {
        int k = kb + i, n = nb + tx;
        if (k < K && n < N) WT[k * BNp + n] += tile[tx][i];
    }
}

__global__ void prep_small(const float* __restrict__ bih, const float* __restrict__ bhh,
                           const float* __restrict__ lin2_w, const float* __restrict__ lin2_b,
                           const float* __restrict__ tb,
                           float* __restrict__ bcomb, float* __restrict__ emb_const) {
    int t = threadIdx.x;
    if (t < D) {
        bcomb[t] = bih[t] + bhh[t];
        float acc = lin2_b[t];
        for (int j = 0; j < D; ++j) acc += lin2_w[t * 516 + 344 + j] * cosf(tb[j]);
        emb_const[t] = acc;
    }
}

// ---------------- shared GEMM inlines ----------------

template<int BN>
__device__ __forceinline__ void load_Btile(const float* __restrict__ BT, int k0,
                                           float* __restrict__ Bs, int t) {
    const float4* src = reinterpret_cast<const float4*>(BT + (size_t)k0 * BN);
    float4* dst = reinterpret_cast<float4*>(Bs);
    for (int idx = t; idx < BK * BN / 4; idx += 256) dst[idx] = src[idx];
}

template<int BN, int TN>
__device__ __forceinline__ void mac_step(const float* __restrict__ As,
                                         const float* __restrict__ Bs,
                                         int tx, int ty, float (&acc)[2][TN]) {
    #pragma unroll
    for (int kk = 0; kk < BK; ++kk) {
        float a0 = As[(ty * 2 + 0) * ALD + kk];
        float a1 = As[(ty * 2 + 1) * ALD + kk];
        #pragma unroll
        for (int q = 0; q < TN / 4; ++q) {
            float4 b4 = *reinterpret_cast<const float4*>(Bs + kk * BN + tx * TN + q * 4);
            acc[0][q*4+0] = fmaf(a0, b4.x, acc[0][q*4+0]);
            acc[0][q*4+1] = fmaf(a0, b4.y, acc[0][q*4+1]);
            acc[0][q*4+2] = fmaf(a0, b4.z, acc[0][q*4+2]);
            acc[0][q*4+3] = fmaf(a0, b4.w, acc[0][q*4+3]);
            acc[1][q*4+0] = fmaf(a1, b4.x, acc[1][q*4+0]);
            acc[1][q*4+1] = fmaf(a1, b4.y, acc[1][q*4+1]);
            acc[1][q*4+2] = fmaf(a1, b4.z, acc[1][q*4+2]);
            acc[1][q*4+3] = fmaf(a1, b4.w, acc[1][q*4+3]);
        }
    }
}

// ---------------- GEMM 1: RNN memory update -> FEAT = mem_new + tnf ----------------
// A[n, 0:688] = [node_mem[n] | node_mem[dst] | ef[ei] | timeenc(dt)], B = W_combT [688][192]
__global__ __launch_bounds__(256) void gemm_rnn(
    const float* __restrict__ WT, const float* __restrict__ bcomb,
    const int* __restrict__ last_idx, const int* __restrict__ destinations,
    const int* __restrict__ edge_idxs, const float* __restrict__ timestamps,
    const float* __restrict__ last_updated, const float* __restrict__ node_mem,
    const float* __restrict__ edge_features, const float* __restrict__ tw,
    const float* __restrict__ tb, const float* __restrict__ tnf,
    float* __restrict__ FEAT)
{
    __shared__ float As[BM * ALD];
    __shared__ __align__(16) float Bs[BK * 192];
    __shared__ int s_li[BM], s_dst[BM], s_ei[BM];
    __shared__ float s_dt[BM];
    const int t = threadIdx.x, tx = t & 15, ty = t >> 4;
    const int row0 = blockIdx.x * BM;
    if (t < BM) {
        int n = row0 + t; if (n > N_NODES - 1) n = N_NODES - 1;
        int li = last_idx[n];
        s_li[t] = li;
        s_dst[t] = li >= 0 ? destinations[li] : 0;
        s_ei[t]  = li >= 0 ? edge_idxs[li] : 0;
        s_dt[t]  = li >= 0 ? timestamps[li] - last_updated[n] : 0.f;
    }
    float acc[2][12] = {};
    __syncthreads();
    #pragma unroll 1
    for (int step = 0; step < 16; ++step) {
        int seg = step >> 2;
        int base = (step & 3) * BK;
        load_Btile<192>(WT, step * BK, Bs, t);
        for (int idx = t; idx < BM * BK; idx += 256) {
            int r = idx / BK, c = idx - r * BK;
            int off = base + c;
            int n = row0 + r; if (n > N_NODES - 1) n = N_NODES - 1;
            float v;
            if (seg == 0)      v = node_mem[n * D + off];
            else if (seg == 1) v = node_mem[s_dst[r] * D + off];
            else if (seg == 2) v = edge_features[s_ei[r] * D + off];
            else               v = cosf(s_dt[r] * tw[off] + tb[off]);
            As[r * ALD + c] = v;
        }
        __syncthreads();
        mac_step<192, 12>(As, Bs, tx, ty, acc);
        __syncthreads();
    }
    #pragma unroll
    for (int i = 0; i < 2; ++i) {
        int n = row0 + ty * 2 + i;
        if (n >= N_NODES) continue;
        int li = s_li[ty * 2 + i];
        #pragma unroll
        for (int j = 0; j < 12; ++j) {
            int col = tx * 12 + j;
            if (col < D) {
                float v = (li >= 0) ? tanhf(acc[i][j] + bcomb[col]) : node_mem[n * D + col];
                FEAT[n * D + col] = v + tnf[n * D + col];
            }
        }
    }
}

// ---------------- GEMM 2: neighbor aggregation fused + lin1 -> H1 = relu(...) ----------------
__global__ __launch_bounds__(256) void gemm_lin1(
    const float* __restrict__ W1T, const float* __restrict__ lin1_b,
    const float* __restrict__ FEAT, const float* __restrict__ edge_features,
    const float* __restrict__ timestamps, const float* __restrict__ nbr_edge_times,
    const int* __restrict__ neighbors, const int* __restrict__ nbr_edge_idxs,
    const float* __restrict__ tw, const float* __restrict__ tb,
    float* __restrict__ H1)
{
    __shared__ float As[BM * ALD];
    __shared__ __align__(16) float Bs[BK * 192];
    __shared__ int s_nbr[BM][KK], s_nei[BM][KK];
    __shared__ float s_net[BM][KK], s_ts[BM];
    const int t = threadIdx.x, tx = t & 15, ty = t >> 4;
    const int row0 = blockIdx.x * BM;
    for (int idx = t; idx < BM * KK; idx += 256) {
        int r = idx / KK, k = idx - r * KK;
        s_nbr[r][k] = neighbors[(row0 + r) * KK + k];
        s_nei[r][k] = nbr_edge_idxs[(row0 + r) * KK + k];
        s_net[r][k] = nbr_edge_times[(row0 + r) * KK + k];
    }
    if (t < BM) s_ts[t] = timestamps[row0 + t];
    float acc[2][12] = {};
    __syncthreads();
    #pragma unroll 1
    for (int step = 0; step < 12; ++step) {
        int seg = step >> 2;
        int base = (step & 3) * BK;
        load_Btile<192>(W1T, step * BK, Bs, t);
        for (int idx = t; idx < BM * BK; idx += 256) {
            int r = idx / BK, c = idx - r * BK;
            int off = base + c;
            float v = 0.f;
            if (seg == 0) {
                #pragma unroll
                for (int k = 0; k < KK; ++k) v += FEAT[s_nbr[r][k] * D + off];
            } else if (seg == 1) {
                float w = tw[off], bb = tb[off], ts = s_ts[r];
                #pragma unroll
                for (int k = 0; k < KK; ++k) v += cosf((ts - s_net[r][k]) * w + bb);
            } else {
                #pragma unroll
                for (int k = 0; k < KK; ++k) v += edge_features[s_nei[r][k] * D + off];
            }
            As[r * ALD + c] = v;
        }
        __syncthreads();
        mac_step<192, 12>(As, Bs, tx, ty, acc);
        __syncthreads();
    }
    #pragma unroll
    for (int i = 0; i < 2; ++i) {
        int b = row0 + ty * 2 + i;
        #pragma unroll
        for (int j = 0; j < 12; ++j) {
            int col = tx * 12 + j;
            if (col < D) H1[b * D + col] = fmaxf(acc[i][j] + 10.0f * lin1_b[col], 0.f);
        }
    }
}

// ---------------- GEMM 3: lin2 over [H1 | FEAT[src]] -> EMB ----------------
__global__ __launch_bounds__(256) void gemm_lin2(
    const float* __restrict__ W2T, const float* __restrict__ emb_const,
    const float* __restrict__ H1, const float* __restrict__ FEAT,
    const int* __restrict__ sources, float* __restrict__ EMB)
{
    __shared__ float As[BM * ALD];
    __shared__ __align__(16) float Bs[BK * 192];
    __shared__ int s_src[BM];
    const int t = threadIdx.x, tx = t & 15, ty = t >> 4;
    const int row0 = blockIdx.x * BM;
    if (t < BM) s_src[t] = sources[row0 + t];
    float acc[2][12] = {};
    __syncthreads();
    #pragma unroll 1
    for (int step = 0; step < 8; ++step) {
        int seg = step >> 2;
        int base = (step & 3) * BK;
        load_Btile<192>(W2T, step * BK, Bs, t);
        for (int idx = t; idx < BM * BK; idx += 256) {
            int r = idx / BK, c = idx - r * BK;
            int off = base + c;
            float v = (seg == 0) ? H1[(row0 + r) * D + off] : FEAT[s_src[r] * D + off];
            As[r * ALD + c] = v;
        }
        __syncthreads();
        mac_step<192, 12>(As, Bs, tx, ty, acc);
        __syncthreads();
    }
    #pragma unroll
    for (int i = 0; i < 2; ++i) {
        int b = row0 + ty * 2 + i;
        #pragma unroll
        for (int j = 0; j < 12; ++j) {
            int col = tx * 12 + j;
            if (col < D) EMB[b * D + col] = acc[i][j] + emb_const[col];
        }
    }
}

// ---------------- GEMM 4: MLP layer 1 -> H = relu(EMB @ w1^T + b1) ----------------
__global__ __launch_bounds__(256) void gemm_mlp1(
    const float* __restrict__ Wm1T, const float* __restrict__ b1,
    const float* __restrict__ EMB, float* __restrict__ H)
{
    __shared__ float As[BM * ALD];
    __shared__ __align__(16) float Bs[BK * 128];
    const int t = threadIdx.x, tx = t & 15, ty = t >> 4;
    const int row0 = blockIdx.x * BM;
    float acc[2][8] = {};
    #pragma unroll 1
    for (int step = 0; step < 4; ++step) {
        load_Btile<128>(Wm1T, step * BK, Bs, t);
        for (int idx = t; idx < BM * BK; idx += 256) {
            int r = idx / BK, c = idx - r * BK;
            As[r * ALD + c] = EMB[(row0 + r) * D + step * BK + c];
        }
        __syncthreads();
        mac_step<128, 8>(As, Bs, tx, ty, acc);
        __syncthreads();
    }
    #pragma unroll
    for (int i = 0; i < 2; ++i) {
        int b = row0 + ty * 2 + i;
        #pragma unroll
        for (int j = 0; j < 8; ++j) {
            int col = tx * 8 + j;
            if (col < HIDD) H[b * HIDD + col] = fmaxf(acc[i][j] + b1[col], 0.f);
        }
    }
}

// ---------------- MLP tail: h2 = relu(H @ w2^T + b2); out = sigmoid(h2 @ w3 + b3) ----------------
__global__ __launch_bounds__(256) void mlp_tail(
    const float* __restrict__ H, const float* __restrict__ w2, const float* __restrict__ b2,
    const float* __restrict__ w3, const float* __restrict__ b3, float* __restrict__ out)
{
    __shared__ float s_w2[10 * HIDD];
    __shared__ float s_b2[10], s_w3[10];
    int t = threadIdx.x;
    for (int i = t; i < 10 * HIDD; i += 256) s_w2[i] = w2[i];
    if (t < 10) { s_b2[t] = b2[t]; s_w3[t] = w3[t]; }
    __syncthreads();
    int row = blockIdx.x * 256 + t;
    float h2[10];
    #pragma unroll
    for (int j = 0; j < 10; ++j) h2[j] = s_b2[j];
    for (int f = 0; f < HIDD; ++f) {
        float hv = H[row * HIDD + f];
        #pragma unroll
        for (int j = 0; j < 10; ++j) h2[j] = fmaf(hv, s_w2[j * HIDD + f], h2[j]);
    }
    float logit = b3[0];
    #pragma unroll
    for (int j = 0; j < 10; ++j) logit += fmaxf(h2[j], 0.f) * s_w3[j];
    out[row] = 1.f / (1.f + expf(-logit));
}

// ---------------- host ----------------

extern "C" void kernel_launch(void* const* d_in, const int* in_sizes, int n_in,
                              void* d_out, int out_size, void* d_ws, size_t ws_size,
                              hipStream_t stream) {
    const float* timestamps     = (const float*)d_in[0];
    const float* edge_features  = (const float*)d_in[1];
    const float* tnf            = (const float*)d_in[2];
    const float* node_mem       = (const float*)d_in[3];
    const float* last_updated   = (const float*)d_in[4];
    const float* nbr_edge_times = (const float*)d_in[5];
    const float* time_w         = (const float*)d_in[6];
    const float* time_b         = (const float*)d_in[7];
    const float* Wih            = (const float*)d_in[8];
    const float* Whh            = (const float*)d_in[9];
    const float* bih            = (const float*)d_in[10];
    const float* bhh            = (const float*)d_in[11];
    const float* lin1_w         = (const float*)d_in[12];
    const float* lin1_b         = (const float*)d_in[13];
    const float* lin2_w         = (const float*)d_in[14];
    const float* lin2_b         = (const float*)d_in[15];
    const float* w1             = (const float*)d_in[16];
    const float* b1             = (const float*)d_in[17];
    const float* w2             = (const float*)d_in[18];
    const float* b2             = (const float*)d_in[19];
    const float* w3             = (const float*)d_in[20];
    const float* b3             = (const float*)d_in[21];
    const int* sources          = (const int*)d_in[22];
    const int* destinations     = (const int*)d_in[23];
    const int* edge_idxs        = (const int*)d_in[24];
    const int* neighbors        = (const int*)d_in[25];
    const int* nbr_edge_idxs    = (const int*)d_in[26];
    float* out = (float*)d_out;

    char* p = (char*)d_ws;
    auto bump = [&p](size_t bytes) { char* r = p; p += (bytes + 255) & ~(size_t)255; return r; };
    int*   last_idx = (int*)  bump(N_NODES * 4);
    float* WcombT   = (float*)bump(688 * 192 * 4);
    float* W1T      = (float*)bump(516 * 192 * 4);
    float* W2T      = (float*)bump(344 * 192 * 4);
    float* Wm1T     = (float*)bump(172 * 128 * 4);
    float* bcomb    = (float*)bump(D * 4);
    float* embc     = (float*)bump(D * 4);
    float* FEAT     = (float*)bump((size_t)N_NODES * D * 4);
    float* H1       = (float*)bump((size_t)BB * D * 4);
    float* EMB      = (float*)bump((size_t)BB * D * 4);
    float* Hbuf     = (float*)bump((size_t)BB * HIDD * 4);

    hipLaunchKernelGGL(init_lastidx, dim3((N_NODES + 255) / 256), dim3(256), 0, stream, last_idx);
    hipLaunchKernelGGL(scatter_last, dim3(BB / 256), dim3(256), 0, stream, sources, last_idx);

    // weight transposes (zero-padded to BN)
    hipLaunchKernelGGL(transpose_pad, dim3((688 + 31) / 32, 192 / 32), dim3(256), 0, stream,
                       Wih, WcombT, D, 688, 688, 192);
    hipLaunchKernelGGL(transpose_add, dim3((172 + 31) / 32, 192 / 32), dim3(256), 0, stream,
                       Whh, WcombT, D, D, D, 192);
    hipLaunchKernelGGL(transpose_pad, dim3((516 + 31) / 32, 192 / 32), dim3(256), 0, stream,
                       lin1_w, W1T, D, 516, 516, 192);
    hipLaunchKernelGGL(transpose_pad, dim3((344 + 31) / 32, 192 / 32), dim3(256), 0, stream,
                       lin2_w, W2T, D, 344, 516, 192);
    hipLaunchKernelGGL(transpose_pad, dim3((172 + 31) / 32, 128 / 32), dim3(256), 0, stream,
                       w1, Wm1T, HIDD, D, D, 128);
    hipLaunchKernelGGL(prep_small, dim3(1), dim3(192), 0, stream,
                       bih, bhh, lin2_w, lin2_b, time_b, bcomb, embc);

    hipLaunchKernelGGL(gemm_rnn, dim3((N_NODES + BM - 1) / BM), dim3(256), 0, stream,
                       WcombT, bcomb, last_idx, destinations, edge_idxs, timestamps,
                       last_updated, node_mem, edge_features, time_w, time_b, tnf, FEAT);
    hipLaunchKernelGGL(gemm_lin1, dim3(BB / BM), dim3(256), 0, stream,
                       W1T, lin1_b, FEAT, edge_features, timestamps, nbr_edge_times,
                       neighbors, nbr_edge_idxs, time_w, time_b, H1);
    hipLaunchKernelGGL(gemm_lin2, dim3(BB / BM), dim3(256), 0, stream,
                       W2T, embc, H1, FEAT, sources, EMB);
    hipLaunchKernelGGL(gemm_mlp1, dim3(BB / BM), dim3(256), 0, stream,
                       Wm1T, b1, EMB, Hbuf);
    hipLaunchKernelGGL(mlp_tail, dim3(BB / 256), dim3(256), 0, stream,
                       Hbuf, w2, b2, w3, b3, out);
}

// Round 3
// 307.209 us; speedup vs baseline: 6.1169x; 1.5041x over previous
//
#include <hip/hip_runtime.h>
#include <math.h>

#define N_NODES 10000
#define BB 8192
#define KK 10
#define D 172            // MEM = TE = EF = EMB
#define HIDD 80
#define BK 43
#define BM 32
#define ALD 33           // As leading dim: [BK][33] layout, bank-stride-1

// ---------------- small prep kernels ----------------

__global__ void init_lastidx(int* __restrict__ last_idx, int* __restrict__ cnt) {
    int i = blockIdx.x * blockDim.x + threadIdx.x;
    if (i < N_NODES) last_idx[i] = -1;
    if (i == 0) *cnt = 0;
}

__global__ void scatter_last(const int* __restrict__ sources, int* __restrict__ last_idx) {
    int b = blockIdx.x * blockDim.x + threadIdx.x;
    if (b < BB) atomicMax(&last_idx[sources[b]], b);
}

__global__ void compact_nodes(const int* __restrict__ last_idx, int* __restrict__ nid,
                              int* __restrict__ li_arr, int* __restrict__ cnt) {
    int n = blockIdx.x * blockDim.x + threadIdx.x;
    if (n < N_NODES) {
        int li = last_idx[n];
        if (li >= 0) { int p = atomicAdd(cnt, 1); nid[p] = n; li_arr[p] = li; }
    }
}

// tiled transpose with zero-pad: WT[k*BNp + n] = (n<N) ? W[n*ldW + k] : 0
__global__ void transpose_pad(const float* __restrict__ W, float* __restrict__ WT,
                              int N, int K, int ldW, int BNp) {
    __shared__ float tile[32][33];
    int kb = blockIdx.x * 32, nb = blockIdx.y * 32;
    int tx = threadIdx.x & 31, ty = threadIdx.x >> 5;
    for (int i = ty; i < 32; i += 8) {
        int n = nb + i, k = kb + tx;
        tile[i][tx] = (n < N && k < K) ? W[n * ldW + k] : 0.f;
    }
    __syncthreads();
    for (int i = ty; i < 32; i += 8) {
        int k = kb + i, n = nb + tx;
        if (k < K && n < BNp) WT[(size_t)k * BNp + n] = tile[tx][i];
    }
}

__global__ void transpose_add(const float* __restrict__ W, float* __restrict__ WT,
                              int N, int K, int ldW, int BNp) {
    __shared__ float tile[32][33];
    int kb = blockIdx.x * 32, nb = blockIdx.y * 32;
    int tx = threadIdx.x & 31, ty = threadIdx.x >> 5;
    for (int i = ty; i < 32; i += 8) {
        int n = nb + i, k = kb + tx;
        tile[i][tx] = (n < N && k < K) ? W[n * ldW + k] : 0.f;
    }
    __syncthreads();
    for (int i = ty; i < 32; i += 8) {
        int k = kb + i, n = nb + tx;
        if (k < K && n < N) WT[(size_t)k * BNp + n] += tile[tx][i];
    }
}

__global__ void prep_small(const float* __restrict__ bih, const float* __restrict__ bhh,
                           const float* __restrict__ lin2_w, const float* __restrict__ lin2_b,
                           const float* __restrict__ tb,
                           float* __restrict__ bcomb, float* __restrict__ emb_const) {
    int t = threadIdx.x;
    if (t < D) {
        bcomb[t] = bih[t] + bhh[t];
        float acc = lin2_b[t];
        for (int j = 0; j < D; ++j) acc += lin2_w[t * 516 + 344 + j] * cosf(tb[j]);
        emb_const[t] = acc;
    }
}

// ---------------- gather kernels ----------------

// FEAT[n] = node_mem[n] + tnf[n]  (all nodes; updated rows overwritten later)
__global__ __launch_bounds__(256) void copy_feat(const float* __restrict__ node_mem,
                                                 const float* __restrict__ tnf,
                                                 float* __restrict__ FEAT) {
    int idx = blockIdx.x * 256 + threadIdx.x;         // over 10000*43 float4s
    if (idx >= N_NODES * 43) return;
    float4 a = *(const float4*)(node_mem + (size_t)idx * 4);
    float4 b = *(const float4*)(tnf + (size_t)idx * 4);
    float4 v; v.x = a.x + b.x; v.y = a.y + b.y; v.z = a.z + b.z; v.w = a.w + b.w;
    *(float4*)(FEAT + (size_t)idx * 4) = v;
}

// MSG[i][688] = [node_mem[nid[i]] | node_mem[dst] | ef[ei] | timeenc(dt)]
__global__ __launch_bounds__(256) void gather_msg(
    const int* __restrict__ nid, const int* __restrict__ li_arr, const int* __restrict__ cnt,
    const int* __restrict__ destinations, const int* __restrict__ edge_idxs,
    const float* __restrict__ timestamps, const float* __restrict__ last_updated,
    const float* __restrict__ node_mem, const float* __restrict__ edge_features,
    const float* __restrict__ tw, const float* __restrict__ tb, float* __restrict__ MSG)
{
    const int i = blockIdx.x;
    if (i >= *cnt) return;
    const int t = threadIdx.x;
    const int n = nid[i], li = li_arr[i];
    float4* dst4 = (float4*)(MSG + (size_t)i * 688);
    if (t < 43) {
        dst4[t] = *(const float4*)(node_mem + (size_t)n * D + t * 4);
    } else if (t < 86) {
        int dd = destinations[li];
        dst4[t] = *(const float4*)(node_mem + (size_t)dd * D + (t - 43) * 4);
    } else if (t < 129) {
        int ei = edge_idxs[li];
        dst4[t] = *(const float4*)(edge_features + (size_t)ei * D + (t - 86) * 4);
    } else if (t < 172) {
        float dt = timestamps[li] - last_updated[n];
        int j0 = (t - 129) * 4;
        float4 w4 = *(const float4*)(tw + j0), b4 = *(const float4*)(tb + j0);
        float4 v;
        v.x = cosf(dt * w4.x + b4.x); v.y = cosf(dt * w4.y + b4.y);
        v.z = cosf(dt * w4.z + b4.z); v.w = cosf(dt * w4.w + b4.w);
        dst4[t] = v;
    }
}

// G[b][516] = [sum_k FEAT[nbr] | sum_k timeenc(ts-net) | sum_k ef[nei]]
__global__ __launch_bounds__(256) void gather_G(
    const float* __restrict__ FEAT, const float* __restrict__ edge_features,
    const float* __restrict__ timestamps, const float* __restrict__ nbr_edge_times,
    const int* __restrict__ neighbors, const int* __restrict__ nbr_edge_idxs,
    const float* __restrict__ tw, const float* __restrict__ tb, float* __restrict__ G)
{
    __shared__ int s_nbr[2][KK], s_nei[2][KK];
    __shared__ float s_net[2][KK], s_ts[2];
    const int t = threadIdx.x;
    const int half = t >> 7, tid = t & 127;
    const int b = blockIdx.x * 2 + half;
    if (tid < KK) {
        s_nbr[half][tid] = neighbors[b * KK + tid];
        s_nei[half][tid] = nbr_edge_idxs[b * KK + tid];
        s_net[half][tid] = nbr_edge_times[b * KK + tid];
    }
    if (tid == KK) s_ts[half] = timestamps[b];
    __syncthreads();
    for (int c = tid; c < 129; c += 128) {
        float4 acc = {0.f, 0.f, 0.f, 0.f};
        if (c < 43) {
            #pragma unroll
            for (int k = 0; k < KK; ++k) {
                const float4 v = *(const float4*)(FEAT + (size_t)s_nbr[half][k] * D + c * 4);
                acc.x += v.x; acc.y += v.y; acc.z += v.z; acc.w += v.w;
            }
        } else if (c < 86) {
            int j0 = (c - 43) * 4;
            float4 w4 = *(const float4*)(tw + j0), b4 = *(const float4*)(tb + j0);
            float ts = s_ts[half];
            #pragma unroll
            for (int k = 0; k < KK; ++k) {
                float dt = ts - s_net[half][k];
                acc.x += cosf(dt * w4.x + b4.x); acc.y += cosf(dt * w4.y + b4.y);
                acc.z += cosf(dt * w4.z + b4.z); acc.w += cosf(dt * w4.w + b4.w);
            }
        } else {
            int j0 = (c - 86) * 4;
            #pragma unroll
            for (int k = 0; k < KK; ++k) {
                const float4 v = *(const float4*)(edge_features + (size_t)s_nei[half][k] * D + j0);
                acc.x += v.x; acc.y += v.y; acc.z += v.z; acc.w += v.w;
            }
        }
        *(float4*)(G + (size_t)b * 516 + c * 4) = acc;
    }
}

// CAT2[b][172:344] = FEAT[src[b]]
__global__ __launch_bounds__(256) void gather_src(const float* __restrict__ FEAT,
                                                  const int* __restrict__ sources,
                                                  float* __restrict__ CAT2) {
    int idx = blockIdx.x * 256 + threadIdx.x;
    if (idx >= BB * 43) return;
    int b = idx / 43, c = idx - b * 43;
    *(float4*)(CAT2 + (size_t)b * 344 + 172 + c * 4) =
        *(const float4*)(FEAT + (size_t)sources[b] * D + c * 4);
}

// ---------------- dense GEMM core: BM=32 x BN=64, 256 thr, TM=2(rows ty,ty+16) TN=4 ----------------

__device__ __forceinline__ void gemm_core(const float* __restrict__ A, int lda, int nsteps,
                                          const float* __restrict__ WT, int ldb, int ncol0,
                                          int row0, int rmax,
                                          float* __restrict__ As, float* __restrict__ Bs,
                                          float (&acc)[2][4])
{
    const int t = threadIdx.x;
    const int tx = t & 15, ty = t >> 4;
    #pragma unroll 1
    for (int step = 0; step < nsteps; ++step) {
        const int k0 = step * BK;
        for (int idx = t; idx < BK * 16; idx += 256) {
            int kk = idx >> 4, q = idx & 15;
            *reinterpret_cast<float4*>(&Bs[kk * 64 + q * 4]) =
                *reinterpret_cast<const float4*>(&WT[(size_t)(k0 + kk) * ldb + ncol0 + q * 4]);
        }
        for (int idx = t; idx < BM * BK; idx += 256) {
            int r = idx / BK, c = idx - r * BK;
            int rg = row0 + r; if (rg > rmax) rg = rmax;
            As[c * ALD + r] = A[(size_t)rg * lda + k0 + c];
        }
        __syncthreads();
        #pragma unroll
        for (int kk = 0; kk < BK; ++kk) {
            float a0 = As[kk * ALD + ty];
            float a1 = As[kk * ALD + 16 + ty];
            float4 b4 = *reinterpret_cast<const float4*>(&Bs[kk * 64 + tx * 4]);
            acc[0][0] = fmaf(a0, b4.x, acc[0][0]);
            acc[0][1] = fmaf(a0, b4.y, acc[0][1]);
            acc[0][2] = fmaf(a0, b4.z, acc[0][2]);
            acc[0][3] = fmaf(a0, b4.w, acc[0][3]);
            acc[1][0] = fmaf(a1, b4.x, acc[1][0]);
            acc[1][1] = fmaf(a1, b4.y, acc[1][1]);
            acc[1][2] = fmaf(a1, b4.z, acc[1][2]);
            acc[1][3] = fmaf(a1, b4.w, acc[1][3]);
        }
        __syncthreads();
    }
}

// GEMM 1: MSG[cnt x 688] @ WcombT -> FEAT[nid] = tanh(acc + bcomb) + tnf
__global__ __launch_bounds__(256) void gemm_rnn(
    const float* __restrict__ MSG, const float* __restrict__ WT,
    const float* __restrict__ bcomb, const int* __restrict__ nid, const int* __restrict__ cnt,
    const float* __restrict__ tnf, float* __restrict__ FEAT)
{
    __shared__ float As[BK * ALD];
    __shared__ __align__(16) float Bs[BK * 64];
    const int row0 = blockIdx.x * BM;
    const int c = *cnt;
    if (row0 >= c) return;
    const int ncol0 = blockIdx.y * 64;
    float acc[2][4] = {};
    gemm_core(MSG, 688, 16, WT, 192, ncol0, row0, c - 1, As, Bs, acc);
    const int tx = threadIdx.x & 15, ty = threadIdx.x >> 4;
    #pragma unroll
    for (int i = 0; i < 2; ++i) {
        int r = row0 + ty + i * 16;
        if (r >= c) continue;
        int n = nid[r];
        #pragma unroll
        for (int j = 0; j < 4; ++j) {
            int col = ncol0 + tx * 4 + j;
            if (col < D)
                FEAT[(size_t)n * D + col] = tanhf(acc[i][j] + bcomb[col]) + tnf[(size_t)n * D + col];
        }
    }
}

// GEMM 2: G[8192 x 516] @ W1T -> CAT2[:, 0:172] = relu(acc + 10*b)
__global__ __launch_bounds__(256) void gemm_lin1(
    const float* __restrict__ G, const float* __restrict__ WT,
    const float* __restrict__ lin1_b, float* __restrict__ CAT2)
{
    __shared__ float As[BK * ALD];
    __shared__ __align__(16) float Bs[BK * 64];
    const int row0 = blockIdx.x * BM;
    const int ncol0 = blockIdx.y * 64;
    float acc[2][4] = {};
    gemm_core(G, 516, 12, WT, 192, ncol0, row0, BB - 1, As, Bs, acc);
    const int tx = threadIdx.x & 15, ty = threadIdx.x >> 4;
    #pragma unroll
    for (int i = 0; i < 2; ++i) {
        int r = row0 + ty + i * 16;
        #pragma unroll
        for (int j = 0; j < 4; ++j) {
            int col = ncol0 + tx * 4 + j;
            if (col < D)
                CAT2[(size_t)r * 344 + col] = fmaxf(acc[i][j] + 10.0f * lin1_b[col], 0.f);
        }
    }
}

// GEMM 3: CAT2[8192 x 344] @ W2T -> EMB = acc + embc
__global__ __launch_bounds__(256) void gemm_lin2(
    const float* __restrict__ CAT2, const float* __restrict__ WT,
    const float* __restrict__ embc, float* __restrict__ EMB)
{
    __shared__ float As[BK * ALD];
    __shared__ __align__(16) float Bs[BK * 64];
    const int row0 = blockIdx.x * BM;
    const int ncol0 = blockIdx.y * 64;
    float acc[2][4] = {};
    gemm_core(CAT2, 344, 8, WT, 192, ncol0, row0, BB - 1, As, Bs, acc);
    const int tx = threadIdx.x & 15, ty = threadIdx.x >> 4;
    #pragma unroll
    for (int i = 0; i < 2; ++i) {
        int r = row0 + ty + i * 16;
        #pragma unroll
        for (int j = 0; j < 4; ++j) {
            int col = ncol0 + tx * 4 + j;
            if (col < D) EMB[(size_t)r * D + col] = acc[i][j] + embc[col];
        }
    }
}

// GEMM 4: EMB[8192 x 172] @ Wm1T -> H = relu(acc + b1)
__global__ __launch_bounds__(256) void gemm_mlp1(
    const float* __restrict__ EMB, const float* __restrict__ WT,
    const float* __restrict__ b1, float* __restrict__ H)
{
    __shared__ float As[BK * ALD];
    __shared__ __align__(16) float Bs[BK * 64];
    const int row0 = blockIdx.x * BM;
    const int ncol0 = blockIdx.y * 64;
    float acc[2][4] = {};
    gemm_core(EMB, 172, 4, WT, 128, ncol0, row0, BB - 1, As, Bs, acc);
    const int tx = threadIdx.x & 15, ty = threadIdx.x >> 4;
    #pragma unroll
    for (int i = 0; i < 2; ++i) {
        int r = row0 + ty + i * 16;
        #pragma unroll
        for (int j = 0; j < 4; ++j) {
            int col = ncol0 + tx * 4 + j;
            if (col < HIDD) H[(size_t)r * HIDD + col] = fmaxf(acc[i][j] + b1[col], 0.f);
        }
    }
}

// MLP tail
__global__ __launch_bounds__(256) void mlp_tail(
    const float* __restrict__ H, const float* __restrict__ w2, const float* __restrict__ b2,
    const float* __restrict__ w3, const float* __restrict__ b3, float* __restrict__ out)
{
    __shared__ float s_w2[10 * HIDD];
    __shared__ float s_b2[10], s_w3[10];
    int t = threadIdx.x;
    for (int i = t; i < 10 * HIDD; i += 256) s_w2[i] = w2[i];
    if (t < 10) { s_b2[t] = b2[t]; s_w3[t] = w3[t]; }
    __syncthreads();
    int row = blockIdx.x * 256 + t;
    float h2[10];
    #pragma unroll
    for (int j = 0; j < 10; ++j) h2[j] = s_b2[j];
    for (int f = 0; f < HIDD; ++f) {
        float hv = H[(size_t)row * HIDD + f];
        #pragma unroll
        for (int j = 0; j < 10; ++j) h2[j] = fmaf(hv, s_w2[j * HIDD + f], h2[j]);
    }
    float logit = b3[0];
    #pragma unroll
    for (int j = 0; j < 10; ++j) logit += fmaxf(h2[j], 0.f) * s_w3[j];
    out[row] = 1.f / (1.f + expf(-logit));
}

// ---------------- host ----------------

extern "C" void kernel_launch(void* const* d_in, const int* in_sizes, int n_in,
                              void* d_out, int out_size, void* d_ws, size_t ws_size,
                              hipStream_t stream) {
    const float* timestamps     = (const float*)d_in[0];
    const float* edge_features  = (const float*)d_in[1];
    const float* tnf            = (const float*)d_in[2];
    const float* node_mem       = (const float*)d_in[3];
    const float* last_updated   = (const float*)d_in[4];
    const float* nbr_edge_times = (const float*)d_in[5];
    const float* time_w         = (const float*)d_in[6];
    const float* time_b         = (const float*)d_in[7];
    const float* Wih            = (const float*)d_in[8];
    const float* Whh            = (const float*)d_in[9];
    const float* bih            = (const float*)d_in[10];
    const float* bhh            = (const float*)d_in[11];
    const float* lin1_w         = (const float*)d_in[12];
    const float* lin1_b         = (const float*)d_in[13];
    const float* lin2_w         = (const float*)d_in[14];
    const float* lin2_b         = (const float*)d_in[15];
    const float* w1             = (const float*)d_in[16];
    const float* b1             = (const float*)d_in[17];
    const float* w2             = (const float*)d_in[18];
    const float* b2             = (const float*)d_in[19];
    const float* w3             = (const float*)d_in[20];
    const float* b3             = (const float*)d_in[21];
    const int* sources          = (const int*)d_in[22];
    const int* destinations     = (const int*)d_in[23];
    const int* edge_idxs        = (const int*)d_in[24];
    const int* neighbors        = (const int*)d_in[25];
    const int* nbr_edge_idxs    = (const int*)d_in[26];
    float* out = (float*)d_out;

    char* p = (char*)d_ws;
    auto bump = [&p](size_t bytes) { char* r = p; p += (bytes + 255) & ~(size_t)255; return r; };
    int*   last_idx = (int*)  bump(N_NODES * 4);
    int*   nid      = (int*)  bump(N_NODES * 4);
    int*   li_arr   = (int*)  bump(N_NODES * 4);
    int*   cnt      = (int*)  bump(256);
    float* WcombT   = (float*)bump((size_t)688 * 192 * 4);
    float* W1T      = (float*)bump((size_t)516 * 192 * 4);
    float* W2T      = (float*)bump((size_t)344 * 192 * 4);
    float* Wm1T     = (float*)bump((size_t)172 * 128 * 4);
    float* bcomb    = (float*)bump(D * 4);
    float* embc     = (float*)bump(D * 4);
    float* FEAT     = (float*)bump((size_t)N_NODES * D * 4);
    // MSG and G share one region: MSG consumed by gemm_rnn before gather_G writes G
    float* MSG      = (float*)bump((size_t)N_NODES * 688 * 4);   // 27.5 MB, also holds G (16.9 MB)
    float* G        = MSG;
    float* CAT2     = (float*)bump((size_t)BB * 344 * 4);
    float* EMB      = (float*)bump((size_t)BB * D * 4);
    float* Hbuf     = (float*)bump((size_t)BB * HIDD * 4);

    hipLaunchKernelGGL(init_lastidx, dim3((N_NODES + 255) / 256), dim3(256), 0, stream, last_idx, cnt);
    hipLaunchKernelGGL(scatter_last, dim3(BB / 256), dim3(256), 0, stream, sources, last_idx);
    hipLaunchKernelGGL(compact_nodes, dim3((N_NODES + 255) / 256), dim3(256), 0, stream,
                       last_idx, nid, li_arr, cnt);

    hipLaunchKernelGGL(transpose_pad, dim3((688 + 31) / 32, 192 / 32), dim3(256), 0, stream,
                       Wih, WcombT, D, 688, 688, 192);
    hipLaunchKernelGGL(transpose_add, dim3((172 + 31) / 32, 192 / 32), dim3(256), 0, stream,
                       Whh, WcombT, D, D, D, 192);
    hipLaunchKernelGGL(transpose_pad, dim3((516 + 31) / 32, 192 / 32), dim3(256), 0, stream,
                       lin1_w, W1T, D, 516, 516, 192);
    hipLaunchKernelGGL(transpose_pad, dim3((344 + 31) / 32, 192 / 32), dim3(256), 0, stream,
                       lin2_w, W2T, D, 344, 516, 192);
    hipLaunchKernelGGL(transpose_pad, dim3((172 + 31) / 32, 128 / 32), dim3(256), 0, stream,
                       w1, Wm1T, HIDD, D, D, 128);
    hipLaunchKernelGGL(prep_small, dim3(1), dim3(192), 0, stream,
                       bih, bhh, lin2_w, lin2_b, time_b, bcomb, embc);

    hipLaunchKernelGGL(copy_feat, dim3((N_NODES * 43 + 255) / 256), dim3(256), 0, stream,
                       node_mem, tnf, FEAT);
    hipLaunchKernelGGL(gather_msg, dim3(N_NODES), dim3(256), 0, stream,
                       nid, li_arr, cnt, destinations, edge_idxs, timestamps, last_updated,
                       node_mem, edge_features, time_w, time_b, MSG);
    hipLaunchKernelGGL(gemm_rnn, dim3((N_NODES + BM - 1) / BM, 3), dim3(256), 0, stream,
                       MSG, WcombT, bcomb, nid, cnt, tnf, FEAT);

    hipLaunchKernelGGL(gather_G, dim3(BB / 2), dim3(256), 0, stream,
                       FEAT, edge_features, timestamps, nbr_edge_times,
                       neighbors, nbr_edge_idxs, time_w, time_b, G);
    hipLaunchKernelGGL(gather_src, dim3((BB * 43 + 255) / 256), dim3(256), 0, stream,
                       FEAT, sources, CAT2);
    hipLaunchKernelGGL(gemm_lin1, dim3(BB / BM, 3), dim3(256), 0, stream,
                       G, W1T, lin1_b, CAT2);
    hipLaunchKernelGGL(gemm_lin2, dim3(BB / BM, 3), dim3(256), 0, stream,
                       CAT2, W2T, embc, EMB);
    hipLaunchKernelGGL(gemm_mlp1, dim3(BB / BM, 2), dim3(256), 0, stream,
                       EMB, Wm1T, b1, Hbuf);
    hipLaunchKernelGGL(mlp_tail, dim3(BB / 256), dim3(256), 0, stream,
                       Hbuf, w2, b2, w3, b3, out);
}

// Round 4
// 234.730 us; speedup vs baseline: 8.0056x; 1.3088x over previous
//
#include <hip/hip_runtime.h>
#include <math.h>

#define N_NODES 10000
#define BB 8192
#define KK 10
#define D 172
#define HIDD 80

typedef _Float16 f16;
typedef f16 f16x8 __attribute__((ext_vector_type(8)));
typedef float f32x4 __attribute__((ext_vector_type(4)));

// ---------------- index prep ----------------

__global__ void init_lastidx(int* __restrict__ last_idx, int* __restrict__ cnt) {
    int i = blockIdx.x * blockDim.x + threadIdx.x;
    if (i < N_NODES) last_idx[i] = -1;
    if (i == 0) *cnt = 0;
}

__global__ void scatter_last(const int* __restrict__ sources, int* __restrict__ last_idx) {
    int b = blockIdx.x * blockDim.x + threadIdx.x;
    if (b < BB) atomicMax(&last_idx[sources[b]], b);
}

__global__ void compact_nodes(const int* __restrict__ last_idx, int* __restrict__ nid,
                              int* __restrict__ li_arr, int* __restrict__ cnt) {
    int n = blockIdx.x * blockDim.x + threadIdx.x;
    if (n < N_NODES) {
        int li = last_idx[n];
        if (li >= 0) { int p = atomicAdd(cnt, 1); nid[p] = n; li_arr[p] = li; }
    }
}

// ---------------- weight conversion to fp16 (segmented 176-wide layout) ----------------
// Wc  [176][704]: seg s of 4 -> Wih[:, s*172 + kk] (+ Whh on seg0)
// W1  [176][544]: seg s of 3 -> lin1_w[:, s*172 + kk]; cols 528.. zero
// W2  [176][352]: seg s of 2 -> lin2_w[:, s*172 + kk]
// Wm1 [ 80][192]: w1[:, k<172]
// y==4: bcomb = bih+bhh; embc = lin2_b + lin2_w[:,344:516] @ cos(tb)
__global__ void conv_weights(const float* __restrict__ Wih, const float* __restrict__ Whh,
                             const float* __restrict__ lin1_w, const float* __restrict__ lin2_w,
                             const float* __restrict__ w1,
                             const float* __restrict__ bih, const float* __restrict__ bhh,
                             const float* __restrict__ lin2_b, const float* __restrict__ tb,
                             f16* __restrict__ Wc, f16* __restrict__ W1, f16* __restrict__ W2,
                             f16* __restrict__ Wm1, float* __restrict__ bcomb, float* __restrict__ embc)
{
    const int which = blockIdx.y;
    const int idx = blockIdx.x * 256 + threadIdx.x;
    if (which == 0) {
        if (idx >= 176 * 704) return;
        int n = idx / 704, k = idx % 704, seg = k / 176, kk = k % 176;
        float v = 0.f;
        if (n < D && kk < D) {
            v = Wih[n * 688 + seg * D + kk];
            if (seg == 0) v += Whh[n * D + kk];
        }
        Wc[idx] = (f16)v;
    } else if (which == 1) {
        if (idx >= 176 * 544) return;
        int n = idx / 544, k = idx % 544, seg = k / 176, kk = k % 176;
        float v = 0.f;
        if (n < D && seg < 3 && kk < D) v = lin1_w[n * 516 + seg * D + kk];
        W1[idx] = (f16)v;
    } else if (which == 2) {
        if (idx >= 176 * 352) return;
        int n = idx / 352, k = idx % 352, seg = k / 176, kk = k % 176;
        float v = 0.f;
        if (n < D && kk < D) v = lin2_w[n * 516 + seg * D + kk];
        W2[idx] = (f16)v;
    } else if (which == 3) {
        if (idx >= 80 * 192) return;
        int n = idx / 192, k = idx % 192;
        Wm1[idx] = (f16)((k < D) ? w1[n * D + k] : 0.f);
    } else {
        if (idx < D) {
            bcomb[idx] = bih[idx] + bhh[idx];
            float acc = lin2_b[idx];
            for (int j = 0; j < D; ++j) acc += lin2_w[idx * 516 + 344 + j] * __cosf(tb[j]);
            embc[idx] = acc;
        }
    }
}

// ---------------- gathers (write fp16 activations) ----------------

// FEAT16[n][176] = fp16(node_mem[n] + tnf[n]), pads zero
__global__ __launch_bounds__(256) void copy_feat16(const float* __restrict__ node_mem,
                                                   const float* __restrict__ tnf,
                                                   f16* __restrict__ FEAT) {
    int idx = blockIdx.x * 256 + threadIdx.x;   // over 10000*22 chunks of 8
    if (idx >= N_NODES * 22) return;
    int n = idx / 22, k0 = (idx % 22) * 8;
    f16x8 o;
    #pragma unroll
    for (int j = 0; j < 8; ++j) {
        int kk = k0 + j;
        float v = (kk < D) ? node_mem[(size_t)n * D + kk] + tnf[(size_t)n * D + kk] : 0.f;
        o[j] = (f16)v;
    }
    *(f16x8*)(FEAT + (size_t)n * 176 + k0) = o;
}

// MSG16[i][704] = [mem_n |176| mem_dst |176| ef |176| timeenc]
__global__ __launch_bounds__(256) void gather_msg(
    const int* __restrict__ nid, const int* __restrict__ li_arr, const int* __restrict__ cnt,
    const int* __restrict__ destinations, const int* __restrict__ edge_idxs,
    const float* __restrict__ timestamps, const float* __restrict__ last_updated,
    const float* __restrict__ node_mem, const float* __restrict__ edge_features,
    const float* __restrict__ tw, const float* __restrict__ tb, f16* __restrict__ MSG)
{
    int idx = blockIdx.x * 256 + threadIdx.x;   // over 10000*88
    int i = idx / 88;
    if (i >= *cnt) return;
    int t = idx % 88, seg = t / 22, k0 = (t % 22) * 8;
    int n = nid[i], li = li_arr[i];
    f16x8 o;
    if (seg < 3) {
        const float* src = (seg == 0) ? node_mem + (size_t)n * D
                         : (seg == 1) ? node_mem + (size_t)destinations[li] * D
                                      : edge_features + (size_t)edge_idxs[li] * D;
        #pragma unroll
        for (int j = 0; j < 8; ++j) {
            int kk = k0 + j;
            o[j] = (f16)((kk < D) ? src[kk] : 0.f);
        }
    } else {
        float dt = timestamps[li] - last_updated[n];
        #pragma unroll
        for (int j = 0; j < 8; ++j) {
            int kk = k0 + j;
            o[j] = (f16)((kk < D) ? __cosf(dt * tw[kk] + tb[kk]) : 0.f);
        }
    }
    *(f16x8*)(MSG + (size_t)i * 704 + seg * 176 + k0) = o;
}

// G16[b][544] = [sum FEAT16[nbr] |176| sum timeenc |176| sum ef |176| 16 zeros]
// also CAT2[b][176..347] = FEAT16[src[b]]
__global__ __launch_bounds__(256) void gather_G(
    const f16* __restrict__ FEAT, const float* __restrict__ edge_features,
    const float* __restrict__ timestamps, const float* __restrict__ nbr_edge_times,
    const int* __restrict__ neighbors, const int* __restrict__ nbr_edge_idxs,
    const int* __restrict__ sources,
    const float* __restrict__ tw, const float* __restrict__ tb,
    f16* __restrict__ G, f16* __restrict__ CAT2)
{
    __shared__ int s_nbr[2][KK], s_nei[2][KK], s_src[2];
    __shared__ float s_net[2][KK], s_ts[2];
    const int t = threadIdx.x;
    const int b0 = blockIdx.x * 2;
    if (t < 20)       { int h = t / KK, k = t % KK; s_nbr[h][k] = neighbors[(b0 + h) * KK + k]; }
    else if (t < 40)  { int u = t - 20; int h = u / KK, k = u % KK; s_nei[h][k] = nbr_edge_idxs[(b0 + h) * KK + k]; }
    else if (t < 60)  { int u = t - 40; int h = u / KK, k = u % KK; s_net[h][k] = nbr_edge_times[(b0 + h) * KK + k]; }
    else if (t < 62)  { s_ts[t - 60] = timestamps[b0 + t - 60]; }
    else if (t < 64)  { s_src[t - 62] = sources[b0 + t - 62]; }
    __syncthreads();
    if (t < 136) {
        const int h = t / 68, c = t % 68;
        const int b = b0 + h;
        float a[8] = {0.f,0.f,0.f,0.f,0.f,0.f,0.f,0.f};
        if (c < 22) {
            int k0 = c * 8;
            #pragma unroll
            for (int k = 0; k < KK; ++k) {
                f16x8 v = *(const f16x8*)(FEAT + (size_t)s_nbr[h][k] * 176 + k0);
                #pragma unroll
                for (int j = 0; j < 8; ++j) a[j] += (float)v[j];
            }
        } else if (c < 44) {
            int k0 = (c - 22) * 8;
            float ts = s_ts[h];
            #pragma unroll
            for (int j = 0; j < 8; ++j) {
                int kk = k0 + j;
                if (kk < D) {
                    float w = tw[kk], bb = tb[kk];
                    #pragma unroll
                    for (int k = 0; k < KK; ++k) a[j] += __cosf((ts - s_net[h][k]) * w + bb);
                }
            }
        } else if (c < 66) {
            int k0 = (c - 44) * 8;
            #pragma unroll
            for (int k = 0; k < KK; ++k) {
                const float* e = edge_features + (size_t)s_nei[h][k] * D;
                #pragma unroll
                for (int j = 0; j < 8; ++j) {
                    int kk = k0 + j;
                    if (kk < D) a[j] += e[kk];
                }
            }
        }
        f16x8 o;
        #pragma unroll
        for (int j = 0; j < 8; ++j) o[j] = (f16)a[j];
        int cc = (c < 22) ? c : (c < 44) ? 22 + (c - 22) : 44 + (c - 44);
        *(f16x8*)(G + (size_t)b * 544 + cc * 8) = o;
    } else if (t < 180) {
        int u = t - 136;
        int h = u / 22, c = u % 22;
        int b = b0 + h;
        *(f16x8*)(CAT2 + (size_t)b * 352 + 176 + c * 8) =
            *(const f16x8*)(FEAT + (size_t)s_src[h] * 176 + c * 8);
    } else if (t < 184) {
        int u = t - 180;
        int h = u >> 1, c = 66 + (u & 1);
        f16x8 z = {};
        *(f16x8*)(G + (size_t)(b0 + h) * 544 + c * 8) = z;
    }
}

// ---------------- MFMA GEMM core (LDS-free, direct fragment loads) ----------------
// Lane l: A row = R0+(l&15), k-chunk = 8*(l>>4); B col = (l&15)+16f, same k-chunk.
// D layout: col = l&15 (+16f), row = R0 + 4*(l>>4) + reg   [m89-verified]

template<int KSTEPS, int NFRAG>
__device__ __forceinline__ void mfma_core(const f16* __restrict__ Arow, int lda,
                                          const f16* __restrict__ W, int ldb,
                                          f32x4 (&acc)[NFRAG])
{
    const int l = threadIdx.x & 63;
    const int koff = (l >> 4) * 8;
    const int nlane = l & 15;
    #pragma unroll 2
    for (int s = 0; s < KSTEPS; ++s) {
        const int k0 = s * 32 + koff;
        f16x8 a = *(const f16x8*)(Arow + k0);
        #pragma unroll
        for (int f = 0; f < NFRAG; ++f) {
            f16x8 b = *(const f16x8*)(W + (size_t)(nlane + 16 * f) * ldb + k0);
            acc[f] = __builtin_amdgcn_mfma_f32_16x16x32_f16(a, b, acc[f], 0, 0, 0);
        }
    }
}

// GEMM 1: MSG16[cnt x 704] @ Wc^T -> FEAT16[nid[r]] = fp16(tanh(acc+bcomb) + tnf)
__global__ __launch_bounds__(128) void gemm_rnn(
    const f16* __restrict__ MSG, const f16* __restrict__ Wc, const float* __restrict__ bcomb,
    const int* __restrict__ nid, const int* __restrict__ cnt,
    const float* __restrict__ tnf, f16* __restrict__ FEAT)
{
    const int c = *cnt;
    const int R0 = blockIdx.x * 32 + (threadIdx.x >> 6) * 16;
    if (R0 >= c) return;
    const int l = threadIdx.x & 63;
    int rowA = R0 + (l & 15); if (rowA >= c) rowA = c - 1;
    f32x4 acc[11] = {};
    mfma_core<22, 11>(MSG + (size_t)rowA * 704, 704, Wc, 704, acc);
    const int col0 = l & 15;
    const int rbase = R0 + (l >> 4) * 4;
    #pragma unroll
    for (int reg = 0; reg < 4; ++reg) {
        int r = rbase + reg;
        if (r >= c) continue;
        int n = nid[r];
        #pragma unroll
        for (int f = 0; f < 11; ++f) {
            int col = f * 16 + col0;
            if (col < D) {
                float v = tanhf(acc[f][reg] + bcomb[col]) + tnf[(size_t)n * D + col];
                FEAT[(size_t)n * 176 + col] = (f16)v;
            }
        }
    }
}

// GEMM 2: G16[8192 x 544] @ W1^T -> CAT2[:,0:172] = fp16(relu(acc + 10*b1)), pads 0
__global__ __launch_bounds__(128) void gemm_lin1(
    const f16* __restrict__ G, const f16* __restrict__ W1,
    const float* __restrict__ lin1_b, f16* __restrict__ CAT2)
{
    const int R0 = blockIdx.x * 32 + (threadIdx.x >> 6) * 16;
    const int l = threadIdx.x & 63;
    f32x4 acc[11] = {};
    mfma_core<17, 11>(G + (size_t)(R0 + (l & 15)) * 544, 544, W1, 544, acc);
    const int col0 = l & 15;
    const int rbase = R0 + (l >> 4) * 4;
    #pragma unroll
    for (int reg = 0; reg < 4; ++reg) {
        int r = rbase + reg;
        #pragma unroll
        for (int f = 0; f < 11; ++f) {
            int col = f * 16 + col0;
            f16 v = (f16)0.f;
            if (col < D) v = (f16)fmaxf(acc[f][reg] + 10.0f * lin1_b[col], 0.f);
            CAT2[(size_t)r * 352 + col] = v;
        }
    }
}

// GEMM 3: CAT2[8192 x 352] @ W2^T -> EMB16 = fp16(acc + embc), cols 172..191 zero
__global__ __launch_bounds__(128) void gemm_lin2(
    const f16* __restrict__ CAT2, const f16* __restrict__ W2,
    const float* __restrict__ embc, f16* __restrict__ EMB)
{
    const int R0 = blockIdx.x * 32 + (threadIdx.x >> 6) * 16;
    const int l = threadIdx.x & 63;
    f32x4 acc[11] = {};
    mfma_core<11, 11>(CAT2 + (size_t)(R0 + (l & 15)) * 352, 352, W2, 352, acc);
    const int col0 = l & 15;
    const int rbase = R0 + (l >> 4) * 4;
    #pragma unroll
    for (int reg = 0; reg < 4; ++reg) {
        int r = rbase + reg;
        #pragma unroll
        for (int f = 0; f < 11; ++f) {
            int col = f * 16 + col0;
            f16 v = (f16)0.f;
            if (col < D) v = (f16)(acc[f][reg] + embc[col]);
            EMB[(size_t)r * 192 + col] = v;
        }
        EMB[(size_t)r * 192 + 176 + col0] = (f16)0.f;   // zero pad cols 176..191
    }
}

// GEMM 4: EMB16[8192 x 192] @ Wm1^T -> H[8192 x 80] = relu(acc + b1) (f32)
__global__ __launch_bounds__(128) void gemm_mlp1(
    const f16* __restrict__ EMB, const f16* __restrict__ Wm1,
    const float* __restrict__ b1, float* __restrict__ H)
{
    const int R0 = blockIdx.x * 32 + (threadIdx.x >> 6) * 16;
    const int l = threadIdx.x & 63;
    f32x4 acc[5] = {};
    mfma_core<6, 5>(EMB + (size_t)(R0 + (l & 15)) * 192, 192, Wm1, 192, acc);
    const int col0 = l & 15;
    const int rbase = R0 + (l >> 4) * 4;
    #pragma unroll
    for (int reg = 0; reg < 4; ++reg) {
        int r = rbase + reg;
        #pragma unroll
        for (int f = 0; f < 5; ++f) {
            int col = f * 16 + col0;
            H[(size_t)r * HIDD + col] = fmaxf(acc[f][reg] + b1[col], 0.f);
        }
    }
}

// ---------------- MLP tail ----------------
__global__ __launch_bounds__(256) void mlp_tail(
    const float* __restrict__ H, const float* __restrict__ w2, const float* __restrict__ b2,
    const float* __restrict__ w3, const float* __restrict__ b3, float* __restrict__ out)
{
    __shared__ float s_w2[10 * HIDD];
    __shared__ float s_b2[10], s_w3[10];
    int t = threadIdx.x;
    for (int i = t; i < 10 * HIDD; i += 256) s_w2[i] = w2[i];
    if (t < 10) { s_b2[t] = b2[t]; s_w3[t] = w3[t]; }
    __syncthreads();
    int row = blockIdx.x * 256 + t;
    float h2[10];
    #pragma unroll
    for (int j = 0; j < 10; ++j) h2[j] = s_b2[j];
    for (int f = 0; f < HIDD; ++f) {
        float hv = H[(size_t)row * HIDD + f];
        #pragma unroll
        for (int j = 0; j < 10; ++j) h2[j] = fmaf(hv, s_w2[j * HIDD + f], h2[j]);
    }
    float logit = b3[0];
    #pragma unroll
    for (int j = 0; j < 10; ++j) logit += fmaxf(h2[j], 0.f) * s_w3[j];
    out[row] = 1.f / (1.f + expf(-logit));
}

// ---------------- host ----------------

extern "C" void kernel_launch(void* const* d_in, const int* in_sizes, int n_in,
                              void* d_out, int out_size, void* d_ws, size_t ws_size,
                              hipStream_t stream) {
    const float* timestamps     = (const float*)d_in[0];
    const float* edge_features  = (const float*)d_in[1];
    const float* tnf            = (const float*)d_in[2];
    const float* node_mem       = (const float*)d_in[3];
    const float* last_updated   = (const float*)d_in[4];
    const float* nbr_edge_times = (const float*)d_in[5];
    const float* time_w         = (const float*)d_in[6];
    const float* time_b         = (const float*)d_in[7];
    const float* Wih            = (const float*)d_in[8];
    const float* Whh            = (const float*)d_in[9];
    const float* bih            = (const float*)d_in[10];
    const float* bhh            = (const float*)d_in[11];
    const float* lin1_w         = (const float*)d_in[12];
    const float* lin1_b         = (const float*)d_in[13];
    const float* lin2_w         = (const float*)d_in[14];
    const float* lin2_b         = (const float*)d_in[15];
    const float* w1             = (const float*)d_in[16];
    const float* b1             = (const float*)d_in[17];
    const float* w2             = (const float*)d_in[18];
    const float* b2             = (const float*)d_in[19];
    const float* w3             = (const float*)d_in[20];
    const float* b3             = (const float*)d_in[21];
    const int* sources          = (const int*)d_in[22];
    const int* destinations     = (const int*)d_in[23];
    const int* edge_idxs        = (const int*)d_in[24];
    const int* neighbors        = (const int*)d_in[25];
    const int* nbr_edge_idxs    = (const int*)d_in[26];
    float* out = (float*)d_out;

    char* p = (char*)d_ws;
    auto bump = [&p](size_t bytes) { char* r = p; p += (bytes + 255) & ~(size_t)255; return r; };
    int* last_idx = (int*)bump(N_NODES * 4);
    int* nid      = (int*)bump(N_NODES * 4);
    int* li_arr   = (int*)bump(N_NODES * 4);
    int* cnt      = (int*)bump(256);
    f16* Wc16     = (f16*)bump((size_t)176 * 704 * 2);
    f16* W1_16    = (f16*)bump((size_t)176 * 544 * 2);
    f16* W2_16    = (f16*)bump((size_t)176 * 352 * 2);
    f16* Wm1_16   = (f16*)bump((size_t)80 * 192 * 2);
    float* bcomb  = (float*)bump(D * 4);
    float* embc   = (float*)bump(D * 4);
    f16* FEAT16   = (f16*)bump((size_t)N_NODES * 176 * 2);
    f16* MSG16    = (f16*)bump((size_t)N_NODES * 704 * 2);
    f16* G16      = (f16*)bump((size_t)BB * 544 * 2);
    f16* CAT2_16  = (f16*)bump((size_t)BB * 352 * 2);
    f16* EMB16    = (f16*)bump((size_t)BB * 192 * 2);
    float* Hbuf   = (float*)bump((size_t)BB * HIDD * 4);

    hipLaunchKernelGGL(init_lastidx, dim3((N_NODES + 255) / 256), dim3(256), 0, stream, last_idx, cnt);
    hipLaunchKernelGGL(scatter_last, dim3(BB / 256), dim3(256), 0, stream, sources, last_idx);
    hipLaunchKernelGGL(compact_nodes, dim3((N_NODES + 255) / 256), dim3(256), 0, stream,
                       last_idx, nid, li_arr, cnt);

    hipLaunchKernelGGL(conv_weights, dim3((176 * 704 + 255) / 256, 5), dim3(256), 0, stream,
                       Wih, Whh, lin1_w, lin2_w, w1, bih, bhh, lin2_b, time_b,
                       Wc16, W1_16, W2_16, Wm1_16, bcomb, embc);

    hipLaunchKernelGGL(copy_feat16, dim3((N_NODES * 22 + 255) / 256), dim3(256), 0, stream,
                       node_mem, tnf, FEAT16);
    hipLaunchKernelGGL(gather_msg, dim3((N_NODES * 88 + 255) / 256), dim3(256), 0, stream,
                       nid, li_arr, cnt, destinations, edge_idxs, timestamps, last_updated,
                       node_mem, edge_features, time_w, time_b, MSG16);
    hipLaunchKernelGGL(gemm_rnn, dim3((N_NODES + 31) / 32), dim3(128), 0, stream,
                       MSG16, Wc16, bcomb, nid, cnt, tnf, FEAT16);

    hipLaunchKernelGGL(gather_G, dim3(BB / 2), dim3(256), 0, stream,
                       FEAT16, edge_features, timestamps, nbr_edge_times,
                       neighbors, nbr_edge_idxs, sources, time_w, time_b, G16, CAT2_16);

    hipLaunchKernelGGL(gemm_lin1, dim3(BB / 32), dim3(128), 0, stream,
                       G16, W1_16, lin1_b, CAT2_16);
    hipLaunchKernelGGL(gemm_lin2, dim3(BB / 32), dim3(128), 0, stream,
                       CAT2_16, W2_16, embc, EMB16);
    hipLaunchKernelGGL(gemm_mlp1, dim3(BB / 32), dim3(128), 0, stream,
                       EMB16, Wm1_16, b1, Hbuf);
    hipLaunchKernelGGL(mlp_tail, dim3(BB / 256), dim3(256), 0, stream,
                       Hbuf, w2, b2, w3, b3, out);
}

// Round 5
// 202.168 us; speedup vs baseline: 9.2950x; 1.1611x over previous
//
#include <hip/hip_runtime.h>
#include <math.h>

#define N_NODES 10000
#define BB 8192
#define KK 10
#define D 172
#define HIDD 80

typedef _Float16 f16;
typedef f16 f16x8 __attribute__((ext_vector_type(8)));
typedef float f32x4 __attribute__((ext_vector_type(4)));

// ---------------- index prep ----------------

__global__ void init_lastidx(int* __restrict__ last_idx, int* __restrict__ cnt) {
    int i = blockIdx.x * blockDim.x + threadIdx.x;
    if (i < N_NODES) last_idx[i] = -1;
    if (i == 0) *cnt = 0;
}

__global__ void scatter_last(const int* __restrict__ sources, int* __restrict__ last_idx) {
    int b = blockIdx.x * blockDim.x + threadIdx.x;
    if (b < BB) atomicMax(&last_idx[sources[b]], b);
}

__global__ void compact_nodes(const int* __restrict__ last_idx, int* __restrict__ nid,
                              int* __restrict__ li_arr, int* __restrict__ cnt) {
    int n = blockIdx.x * blockDim.x + threadIdx.x;
    if (n < N_NODES) {
        int li = last_idx[n];
        if (li >= 0) { int p = atomicAdd(cnt, 1); nid[p] = n; li_arr[p] = li; }
    }
}

// ---------------- weight conversion to fp16 (segmented 176-wide layout) ----------------
__global__ void conv_weights(const float* __restrict__ Wih, const float* __restrict__ Whh,
                             const float* __restrict__ lin1_w, const float* __restrict__ lin2_w,
                             const float* __restrict__ w1,
                             const float* __restrict__ bih, const float* __restrict__ bhh,
                             const float* __restrict__ lin2_b, const float* __restrict__ tb,
                             f16* __restrict__ Wc, f16* __restrict__ W1, f16* __restrict__ W2,
                             f16* __restrict__ Wm1, float* __restrict__ bcomb, float* __restrict__ embc)
{
    const int which = blockIdx.y;
    const int idx = blockIdx.x * 256 + threadIdx.x;
    if (which == 0) {
        if (idx >= 176 * 704) return;
        int n = idx / 704, k = idx % 704, seg = k / 176, kk = k % 176;
        float v = 0.f;
        if (n < D && kk < D) {
            v = Wih[n * 688 + seg * D + kk];
            if (seg == 0) v += Whh[n * D + kk];
        }
        Wc[idx] = (f16)v;
    } else if (which == 1) {
        if (idx >= 176 * 544) return;
        int n = idx / 544, k = idx % 544, seg = k / 176, kk = k % 176;
        float v = 0.f;
        if (n < D && seg < 3 && kk < D) v = lin1_w[n * 516 + seg * D + kk];
        W1[idx] = (f16)v;
    } else if (which == 2) {
        if (idx >= 176 * 352) return;
        int n = idx / 352, k = idx % 352, seg = k / 176, kk = k % 176;
        float v = 0.f;
        if (n < D && kk < D) v = lin2_w[n * 516 + seg * D + kk];
        W2[idx] = (f16)v;
    } else if (which == 3) {
        if (idx >= 80 * 192) return;
        int n = idx / 192, k = idx % 192;
        Wm1[idx] = (f16)((k < D) ? w1[n * D + k] : 0.f);
    } else {
        if (idx < D) {
            bcomb[idx] = bih[idx] + bhh[idx];
            float acc = lin2_b[idx];
            for (int j = 0; j < D; ++j) acc += lin2_w[idx * 516 + 344 + j] * __cosf(tb[j]);
            embc[idx] = acc;
        }
    }
}

// ---------------- gathers ----------------

// FEAT16[n][176] = fp16(node_mem[n] + tnf[n]), pads zero
__global__ __launch_bounds__(256) void copy_feat16(const float* __restrict__ node_mem,
                                                   const float* __restrict__ tnf,
                                                   f16* __restrict__ FEAT) {
    int idx = blockIdx.x * 256 + threadIdx.x;
    if (idx >= N_NODES * 22) return;
    int n = idx / 22, k0 = (idx % 22) * 8;
    f16x8 o;
    #pragma unroll
    for (int j = 0; j < 8; ++j) {
        int kk = k0 + j;
        float v = (kk < D) ? node_mem[(size_t)n * D + kk] + tnf[(size_t)n * D + kk] : 0.f;
        o[j] = (f16)v;
    }
    *(f16x8*)(FEAT + (size_t)n * 176 + k0) = o;
}

// MSG16[i][704] = [mem_n |176| mem_dst |176| ef |176| timeenc]
__global__ __launch_bounds__(256) void gather_msg(
    const int* __restrict__ nid, const int* __restrict__ li_arr, const int* __restrict__ cnt,
    const int* __restrict__ destinations, const int* __restrict__ edge_idxs,
    const float* __restrict__ timestamps, const float* __restrict__ last_updated,
    const float* __restrict__ node_mem, const float* __restrict__ edge_features,
    const float* __restrict__ tw, const float* __restrict__ tb, f16* __restrict__ MSG)
{
    int idx = blockIdx.x * 256 + threadIdx.x;
    int i = idx / 88;
    if (i >= *cnt) return;
    int t = idx % 88, seg = t / 22, k0 = (t % 22) * 8;
    int n = nid[i], li = li_arr[i];
    f16x8 o;
    if (seg < 3) {
        const float* src = (seg == 0) ? node_mem + (size_t)n * D
                         : (seg == 1) ? node_mem + (size_t)destinations[li] * D
                                      : edge_features + (size_t)edge_idxs[li] * D;
        #pragma unroll
        for (int j = 0; j < 8; ++j) {
            int kk = k0 + j;
            o[j] = (f16)((kk < D) ? src[kk] : 0.f);
        }
    } else {
        float dt = timestamps[li] - last_updated[n];
        #pragma unroll
        for (int j = 0; j < 8; ++j) {
            int kk = k0 + j;
            o[j] = (f16)((kk < D) ? __cosf(dt * tw[kk] + tb[kk]) : 0.f);
        }
    }
    *(f16x8*)(MSG + (size_t)i * 704 + seg * 176 + k0) = o;
}

// Flattened gather_G: gid over 8192 rows x 90 chunks, 100% thread utilization.
// chunks: 0..21 FEAT-sum -> G[0:176); 22..43 timeenc -> G[176:352); 44..65 ef-sum -> G[352:528);
//         66..67 zero-pad -> G[528:544); 68..89 src-copy -> CAT2[176:352)
__global__ __launch_bounds__(256, 4) void gather_G(
    const f16* __restrict__ FEAT, const float* __restrict__ edge_features,
    const float* __restrict__ timestamps, const float* __restrict__ nbr_edge_times,
    const int* __restrict__ neighbors, const int* __restrict__ nbr_edge_idxs,
    const int* __restrict__ sources,
    const float* __restrict__ tw, const float* __restrict__ tb,
    f16* __restrict__ G, f16* __restrict__ CAT2)
{
    int gid = blockIdx.x * 256 + threadIdx.x;
    if (gid >= BB * 90) return;
    int b = gid / 90, c = gid - b * 90;
    if (c < 22) {
        f16x8 v[KK];
        #pragma unroll
        for (int k = 0; k < KK; ++k)
            v[k] = *(const f16x8*)(FEAT + (size_t)neighbors[b * KK + k] * 176 + c * 8);
        float a[8] = {};
        #pragma unroll
        for (int k = 0; k < KK; ++k) {
            #pragma unroll
            for (int j = 0; j < 8; ++j) a[j] += (float)v[k][j];
        }
        f16x8 o;
        #pragma unroll
        for (int j = 0; j < 8; ++j) o[j] = (f16)a[j];
        *(f16x8*)(G + (size_t)b * 544 + c * 8) = o;
    } else if (c < 44) {
        int k0 = (c - 22) * 8;
        float ts = timestamps[b];
        float net[KK];
        #pragma unroll
        for (int k = 0; k < KK; ++k) net[k] = nbr_edge_times[b * KK + k];
        f16x8 o;
        #pragma unroll
        for (int j = 0; j < 8; ++j) {
            int kk = k0 + j;
            float a = 0.f;
            if (kk < D) {
                float w = tw[kk], bb = tb[kk];
                #pragma unroll
                for (int k = 0; k < KK; ++k) a += __cosf((ts - net[k]) * w + bb);
            }
            o[j] = (f16)a;
        }
        *(f16x8*)(G + (size_t)b * 544 + 176 + k0) = o;
    } else if (c < 66) {
        int k0 = (c - 44) * 8;
        const bool full = (c != 65);            // c==65: elements 168..175, only 168..171 valid
        float4 e0[KK], e1[KK];
        #pragma unroll
        for (int k = 0; k < KK; ++k) {
            const float* e = edge_features + (size_t)nbr_edge_idxs[b * KK + k] * D + k0;
            e0[k] = *(const float4*)e;
            if (full) e1[k] = *(const float4*)(e + 4);
            else      e1[k] = make_float4(0.f, 0.f, 0.f, 0.f);
        }
        float a[8] = {};
        #pragma unroll
        for (int k = 0; k < KK; ++k) {
            a[0] += e0[k].x; a[1] += e0[k].y; a[2] += e0[k].z; a[3] += e0[k].w;
            a[4] += e1[k].x; a[5] += e1[k].y; a[6] += e1[k].z; a[7] += e1[k].w;
        }
        f16x8 o;
        #pragma unroll
        for (int j = 0; j < 8; ++j) o[j] = (f16)a[j];
        *(f16x8*)(G + (size_t)b * 544 + 352 + k0) = o;
    } else if (c < 68) {
        f16x8 z = {};
        *(f16x8*)(G + (size_t)b * 544 + 528 + (c - 66) * 8) = z;
    } else {
        int cc = c - 68;
        *(f16x8*)(CAT2 + (size_t)b * 352 + 176 + cc * 8) =
            *(const f16x8*)(FEAT + (size_t)sources[b] * 176 + cc * 8);
    }
}

// ---------------- MFMA GEMM core (LDS-free, direct fragment loads) ----------------

template<int KSTEPS, int NFRAG>
__device__ __forceinline__ void mfma_core(const f16* __restrict__ Arow, int lda,
                                          const f16* __restrict__ W, int ldb,
                                          f32x4 (&acc)[NFRAG])
{
    const int l = threadIdx.x & 63;
    const int koff = (l >> 4) * 8;
    const int nlane = l & 15;
    #pragma unroll 2
    for (int s = 0; s < KSTEPS; ++s) {
        const int k0 = s * 32 + koff;
        f16x8 a = *(const f16x8*)(Arow + k0);
        #pragma unroll
        for (int f = 0; f < NFRAG; ++f) {
            f16x8 b = *(const f16x8*)(W + (size_t)(nlane + 16 * f) * ldb + k0);
            acc[f] = __builtin_amdgcn_mfma_f32_16x16x32_f16(a, b, acc[f], 0, 0, 0);
        }
    }
}

// GEMM 1: MSG16[cnt x 704] @ Wc^T -> FEAT16[nid[r]] = fp16(tanh(acc+bcomb) + tnf)
__global__ __launch_bounds__(128) void gemm_rnn(
    const f16* __restrict__ MSG, const f16* __restrict__ Wc, const float* __restrict__ bcomb,
    const int* __restrict__ nid, const int* __restrict__ cnt,
    const float* __restrict__ tnf, f16* __restrict__ FEAT)
{
    const int c = *cnt;
    const int R0 = blockIdx.x * 32 + (threadIdx.x >> 6) * 16;
    if (R0 >= c) return;
    const int l = threadIdx.x & 63;
    int rowA = R0 + (l & 15); if (rowA >= c) rowA = c - 1;
    f32x4 acc[11] = {};
    mfma_core<22, 11>(MSG + (size_t)rowA * 704, 704, Wc, 704, acc);
    const int col0 = l & 15;
    const int rbase = R0 + (l >> 4) * 4;
    #pragma unroll
    for (int reg = 0; reg < 4; ++reg) {
        int r = rbase + reg;
        if (r >= c) continue;
        int n = nid[r];
        #pragma unroll
        for (int f = 0; f < 11; ++f) {
            int col = f * 16 + col0;
            if (col < D) {
                float v = tanhf(acc[f][reg] + bcomb[col]) + tnf[(size_t)n * D + col];
                FEAT[(size_t)n * 176 + col] = (f16)v;
            }
        }
    }
}

// GEMM 2: G16[8192 x 544] @ W1^T -> CAT2[:,0:172] = fp16(relu(acc + 10*b1)), pads 0
__global__ __launch_bounds__(128) void gemm_lin1(
    const f16* __restrict__ G, const f16* __restrict__ W1,
    const float* __restrict__ lin1_b, f16* __restrict__ CAT2)
{
    const int R0 = blockIdx.x * 32 + (threadIdx.x >> 6) * 16;
    const int l = threadIdx.x & 63;
    f32x4 acc[11] = {};
    mfma_core<17, 11>(G + (size_t)(R0 + (l & 15)) * 544, 544, W1, 544, acc);
    const int col0 = l & 15;
    const int rbase = R0 + (l >> 4) * 4;
    #pragma unroll
    for (int reg = 0; reg < 4; ++reg) {
        int r = rbase + reg;
        #pragma unroll
        for (int f = 0; f < 11; ++f) {
            int col = f * 16 + col0;
            f16 v = (f16)0.f;
            if (col < D) v = (f16)fmaxf(acc[f][reg] + 10.0f * lin1_b[col], 0.f);
            CAT2[(size_t)r * 352 + col] = v;
        }
    }
}

// GEMM 3: CAT2[8192 x 352] @ W2^T -> EMB16 = fp16(acc + embc), cols 172..191 zero
__global__ __launch_bounds__(128) void gemm_lin2(
    const f16* __restrict__ CAT2, const f16* __restrict__ W2,
    const float* __restrict__ embc, f16* __restrict__ EMB)
{
    const int R0 = blockIdx.x * 32 + (threadIdx.x >> 6) * 16;
    const int l = threadIdx.x & 63;
    f32x4 acc[11] = {};
    mfma_core<11, 11>(CAT2 + (size_t)(R0 + (l & 15)) * 352, 352, W2, 352, acc);
    const int col0 = l & 15;
    const int rbase = R0 + (l >> 4) * 4;
    #pragma unroll
    for (int reg = 0; reg < 4; ++reg) {
        int r = rbase + reg;
        #pragma unroll
        for (int f = 0; f < 11; ++f) {
            int col = f * 16 + col0;
            f16 v = (f16)0.f;
            if (col < D) v = (f16)(acc[f][reg] + embc[col]);
            EMB[(size_t)r * 192 + col] = v;
        }
        EMB[(size_t)r * 192 + 176 + col0] = (f16)0.f;
    }
}

// GEMM 4 + MLP tail fused: EMB16 @ Wm1^T -> H(LDS) -> h2 -> sigmoid -> out
__global__ __launch_bounds__(128) void gemm_mlp(
    const f16* __restrict__ EMB, const f16* __restrict__ Wm1, const float* __restrict__ b1,
    const float* __restrict__ w2, const float* __restrict__ b2,
    const float* __restrict__ w3, const float* __restrict__ b3, float* __restrict__ out)
{
    __shared__ float sH[32][84];
    __shared__ float s_w2[10 * HIDD];
    __shared__ float s_b2[10], s_w3[10], s_b3;
    const int t = threadIdx.x;
    for (int i = t; i < 10 * HIDD; i += 128) s_w2[i] = w2[i];
    if (t < 10) { s_b2[t] = b2[t]; s_w3[t] = w3[t]; }
    if (t == 10) s_b3 = b3[0];
    const int R0 = blockIdx.x * 32 + (t >> 6) * 16;
    const int l = t & 63;
    f32x4 acc[5] = {};
    mfma_core<6, 5>(EMB + (size_t)(R0 + (l & 15)) * 192, 192, Wm1, 192, acc);
    const int col0 = l & 15;
    const int rloc = (t >> 6) * 16 + (l >> 4) * 4;
    #pragma unroll
    for (int reg = 0; reg < 4; ++reg) {
        #pragma unroll
        for (int f = 0; f < 5; ++f) {
            int col = f * 16 + col0;
            sH[rloc + reg][col] = fmaxf(acc[f][reg] + b1[col], 0.f);
        }
    }
    __syncthreads();
    if (t < 32) {
        float h2[10];
        #pragma unroll
        for (int j = 0; j < 10; ++j) h2[j] = s_b2[j];
        for (int f = 0; f < HIDD; ++f) {
            float hv = sH[t][f];
            #pragma unroll
            for (int j = 0; j < 10; ++j) h2[j] = fmaf(hv, s_w2[j * HIDD + f], h2[j]);
        }
        float logit = s_b3;
        #pragma unroll
        for (int j = 0; j < 10; ++j) logit += fmaxf(h2[j], 0.f) * s_w3[j];
        out[blockIdx.x * 32 + t] = 1.f / (1.f + expf(-logit));
    }
}

// ---------------- host ----------------

extern "C" void kernel_launch(void* const* d_in, const int* in_sizes, int n_in,
                              void* d_out, int out_size, void* d_ws, size_t ws_size,
                              hipStream_t stream) {
    const float* timestamps     = (const float*)d_in[0];
    const float* edge_features  = (const float*)d_in[1];
    const float* tnf            = (const float*)d_in[2];
    const float* node_mem       = (const float*)d_in[3];
    const float* last_updated   = (const float*)d_in[4];
    const float* nbr_edge_times = (const float*)d_in[5];
    const float* time_w         = (const float*)d_in[6];
    const float* time_b         = (const float*)d_in[7];
    const float* Wih            = (const float*)d_in[8];
    const float* Whh            = (const float*)d_in[9];
    const float* bih            = (const float*)d_in[10];
    const float* bhh            = (const float*)d_in[11];
    const float* lin1_w         = (const float*)d_in[12];
    const float* lin1_b         = (const float*)d_in[13];
    const float* lin2_w         = (const float*)d_in[14];
    const float* lin2_b         = (const float*)d_in[15];
    const float* w1             = (const float*)d_in[16];
    const float* b1             = (const float*)d_in[17];
    const float* w2             = (const float*)d_in[18];
    const float* b2             = (const float*)d_in[19];
    const float* w3             = (const float*)d_in[20];
    const float* b3             = (const float*)d_in[21];
    const int* sources          = (const int*)d_in[22];
    const int* destinations     = (const int*)d_in[23];
    const int* edge_idxs        = (const int*)d_in[24];
    const int* neighbors        = (const int*)d_in[25];
    const int* nbr_edge_idxs    = (const int*)d_in[26];
    float* out = (float*)d_out;

    char* p = (char*)d_ws;
    auto bump = [&p](size_t bytes) { char* r = p; p += (bytes + 255) & ~(size_t)255; return r; };
    int* last_idx = (int*)bump(N_NODES * 4);
    int* nid      = (int*)bump(N_NODES * 4);
    int* li_arr   = (int*)bump(N_NODES * 4);
    int* cnt      = (int*)bump(256);
    f16* Wc16     = (f16*)bump((size_t)176 * 704 * 2);
    f16* W1_16    = (f16*)bump((size_t)176 * 544 * 2);
    f16* W2_16    = (f16*)bump((size_t)176 * 352 * 2);
    f16* Wm1_16   = (f16*)bump((size_t)80 * 192 * 2);
    float* bcomb  = (float*)bump(D * 4);
    float* embc   = (float*)bump(D * 4);
    f16* FEAT16   = (f16*)bump((size_t)N_NODES * 176 * 2);
    f16* MSG16    = (f16*)bump((size_t)N_NODES * 704 * 2);
    f16* G16      = (f16*)bump((size_t)BB * 544 * 2);
    f16* CAT2_16  = (f16*)bump((size_t)BB * 352 * 2);
    f16* EMB16    = (f16*)bump((size_t)BB * 192 * 2);

    hipLaunchKernelGGL(init_lastidx, dim3((N_NODES + 255) / 256), dim3(256), 0, stream, last_idx, cnt);
    hipLaunchKernelGGL(scatter_last, dim3(BB / 256), dim3(256), 0, stream, sources, last_idx);
    hipLaunchKernelGGL(compact_nodes, dim3((N_NODES + 255) / 256), dim3(256), 0, stream,
                       last_idx, nid, li_arr, cnt);

    hipLaunchKernelGGL(conv_weights, dim3((176 * 704 + 255) / 256, 5), dim3(256), 0, stream,
                       Wih, Whh, lin1_w, lin2_w, w1, bih, bhh, lin2_b, time_b,
                       Wc16, W1_16, W2_16, Wm1_16, bcomb, embc);

    hipLaunchKernelGGL(copy_feat16, dim3((N_NODES * 22 + 255) / 256), dim3(256), 0, stream,
                       node_mem, tnf, FEAT16);
    hipLaunchKernelGGL(gather_msg, dim3((N_NODES * 88 + 255) / 256), dim3(256), 0, stream,
                       nid, li_arr, cnt, destinations, edge_idxs, timestamps, last_updated,
                       node_mem, edge_features, time_w, time_b, MSG16);
    hipLaunchKernelGGL(gemm_rnn, dim3((N_NODES + 31) / 32), dim3(128), 0, stream,
                       MSG16, Wc16, bcomb, nid, cnt, tnf, FEAT16);

    hipLaunchKernelGGL(gather_G, dim3((BB * 90 + 255) / 256), dim3(256), 0, stream,
                       FEAT16, edge_features, timestamps, nbr_edge_times,
                       neighbors, nbr_edge_idxs, sources, time_w, time_b, G16, CAT2_16);

    hipLaunchKernelGGL(gemm_lin1, dim3(BB / 32), dim3(128), 0, stream,
                       G16, W1_16, lin1_b, CAT2_16);
    hipLaunchKernelGGL(gemm_lin2, dim3(BB / 32), dim3(128), 0, stream,
                       CAT2_16, W2_16, embc, EMB16);
    hipLaunchKernelGGL(gemm_mlp, dim3(BB / 32), dim3(128), 0, stream,
                       EMB16, Wm1_16, b1, w2, b2, w3, b3, out);
}

// Round 6
// 142.069 us; speedup vs baseline: 13.2270x; 1.4230x over previous
//
#include <hip/hip_runtime.h>
#include <math.h>

#define N_NODES 10000
#define BB 8192
#define KK 10
#define D 172
#define HIDD 80

typedef _Float16 f16;
typedef f16 f16x8 __attribute__((ext_vector_type(8)));
typedef float f32x4 __attribute__((ext_vector_type(4)));

// ---------------- index prep ----------------

__global__ void init_lastidx(int* __restrict__ last_idx, int* __restrict__ cnt) {
    int i = blockIdx.x * blockDim.x + threadIdx.x;
    if (i < N_NODES) last_idx[i] = -1;
    if (i == 0) *cnt = 0;
}

__global__ void scatter_last(const int* __restrict__ sources, int* __restrict__ last_idx) {
    int b = blockIdx.x * blockDim.x + threadIdx.x;
    if (b < BB) atomicMax(&last_idx[sources[b]], b);
}

__global__ void compact_nodes(const int* __restrict__ last_idx, int* __restrict__ nid,
                              int* __restrict__ li_arr, int* __restrict__ cnt) {
    int n = blockIdx.x * blockDim.x + threadIdx.x;
    if (n < N_NODES) {
        int li = last_idx[n];
        if (li >= 0) { int p = atomicAdd(cnt, 1); nid[p] = n; li_arr[p] = li; }
    }
}

// ---------------- weight conversion to fp16 (segmented 176-wide layout) ----------------
__global__ void conv_weights(const float* __restrict__ Wih, const float* __restrict__ Whh,
                             const float* __restrict__ lin1_w, const float* __restrict__ lin2_w,
                             const float* __restrict__ w1,
                             const float* __restrict__ bih, const float* __restrict__ bhh,
                             const float* __restrict__ lin2_b, const float* __restrict__ tb,
                             f16* __restrict__ Wc, f16* __restrict__ W1, f16* __restrict__ W2,
                             f16* __restrict__ Wm1, float* __restrict__ bcomb, float* __restrict__ embc)
{
    const int which = blockIdx.y;
    const int idx = blockIdx.x * 256 + threadIdx.x;
    if (which == 0) {
        if (idx >= 176 * 704) return;
        int n = idx / 704, k = idx % 704, seg = k / 176, kk = k % 176;
        float v = 0.f;
        if (n < D && kk < D) {
            v = Wih[n * 688 + seg * D + kk];
            if (seg == 0) v += Whh[n * D + kk];
        }
        Wc[idx] = (f16)v;
    } else if (which == 1) {
        if (idx >= 176 * 544) return;
        int n = idx / 544, k = idx % 544, seg = k / 176, kk = k % 176;
        float v = 0.f;
        if (n < D && seg < 3 && kk < D) v = lin1_w[n * 516 + seg * D + kk];
        W1[idx] = (f16)v;
    } else if (which == 2) {
        if (idx >= 176 * 352) return;
        int n = idx / 352, k = idx % 352, seg = k / 176, kk = k % 176;
        float v = 0.f;
        if (n < D && kk < D) v = lin2_w[n * 516 + seg * D + kk];
        W2[idx] = (f16)v;
    } else if (which == 3) {
        if (idx >= 80 * 192) return;
        int n = idx / 192, k = idx % 192;
        Wm1[idx] = (f16)((k < D) ? w1[n * D + k] : 0.f);
    } else {
        if (idx < D) {
            bcomb[idx] = bih[idx] + bhh[idx];
            float acc = lin2_b[idx];
            for (int j = 0; j < D; ++j) acc += lin2_w[idx * 516 + 344 + j] * __cosf(tb[j]);
            embc[idx] = acc;
        }
    }
}

// ---------------- gathers ----------------

// FEAT16[n][176] = fp16(node_mem[n] + tnf[n]), pads zero
__global__ __launch_bounds__(256) void copy_feat16(const float* __restrict__ node_mem,
                                                   const float* __restrict__ tnf,
                                                   f16* __restrict__ FEAT) {
    int idx = blockIdx.x * 256 + threadIdx.x;
    if (idx >= N_NODES * 22) return;
    int n = idx / 22, k0 = (idx % 22) * 8;
    f16x8 o;
    #pragma unroll
    for (int j = 0; j < 8; ++j) {
        int kk = k0 + j;
        float v = (kk < D) ? node_mem[(size_t)n * D + kk] + tnf[(size_t)n * D + kk] : 0.f;
        o[j] = (f16)v;
    }
    *(f16x8*)(FEAT + (size_t)n * 176 + k0) = o;
}

// MSG16[i][704] = [mem_n |176| mem_dst |176| ef |176| timeenc]
__global__ __launch_bounds__(256) void gather_msg(
    const int* __restrict__ nid, const int* __restrict__ li_arr, const int* __restrict__ cnt,
    const int* __restrict__ destinations, const int* __restrict__ edge_idxs,
    const float* __restrict__ timestamps, const float* __restrict__ last_updated,
    const float* __restrict__ node_mem, const float* __restrict__ edge_features,
    const float* __restrict__ tw, const float* __restrict__ tb, f16* __restrict__ MSG)
{
    int idx = blockIdx.x * 256 + threadIdx.x;
    int i = idx / 88;
    if (i >= *cnt) return;
    int t = idx % 88, seg = t / 22, k0 = (t % 22) * 8;
    int n = nid[i], li = li_arr[i];
    f16x8 o;
    if (seg < 3) {
        const float* src = (seg == 0) ? node_mem + (size_t)n * D
                         : (seg == 1) ? node_mem + (size_t)destinations[li] * D
                                      : edge_features + (size_t)edge_idxs[li] * D;
        #pragma unroll
        for (int j = 0; j < 8; ++j) {
            int kk = k0 + j;
            o[j] = (f16)((kk < D) ? src[kk] : 0.f);
        }
    } else {
        float dt = timestamps[li] - last_updated[n];
        #pragma unroll
        for (int j = 0; j < 8; ++j) {
            int kk = k0 + j;
            o[j] = (f16)((kk < D) ? __cosf(dt * tw[kk] + tb[kk]) : 0.f);
        }
    }
    *(f16x8*)(MSG + (size_t)i * 704 + seg * 176 + k0) = o;
}

// Flattened gather_G: gid over 8192 rows x 90 chunks
__global__ __launch_bounds__(256, 4) void gather_G(
    const f16* __restrict__ FEAT, const float* __restrict__ edge_features,
    const float* __restrict__ timestamps, const float* __restrict__ nbr_edge_times,
    const int* __restrict__ neighbors, const int* __restrict__ nbr_edge_idxs,
    const int* __restrict__ sources,
    const float* __restrict__ tw, const float* __restrict__ tb,
    f16* __restrict__ G, f16* __restrict__ CAT2)
{
    int gid = blockIdx.x * 256 + threadIdx.x;
    if (gid >= BB * 90) return;
    int b = gid / 90, c = gid - b * 90;
    if (c < 22) {
        f16x8 v[KK];
        #pragma unroll
        for (int k = 0; k < KK; ++k)
            v[k] = *(const f16x8*)(FEAT + (size_t)neighbors[b * KK + k] * 176 + c * 8);
        float a[8] = {};
        #pragma unroll
        for (int k = 0; k < KK; ++k) {
            #pragma unroll
            for (int j = 0; j < 8; ++j) a[j] += (float)v[k][j];
        }
        f16x8 o;
        #pragma unroll
        for (int j = 0; j < 8; ++j) o[j] = (f16)a[j];
        *(f16x8*)(G + (size_t)b * 544 + c * 8) = o;
    } else if (c < 44) {
        int k0 = (c - 22) * 8;
        float ts = timestamps[b];
        float net[KK];
        #pragma unroll
        for (int k = 0; k < KK; ++k) net[k] = nbr_edge_times[b * KK + k];
        f16x8 o;
        #pragma unroll
        for (int j = 0; j < 8; ++j) {
            int kk = k0 + j;
            float a = 0.f;
            if (kk < D) {
                float w = tw[kk], bb = tb[kk];
                #pragma unroll
                for (int k = 0; k < KK; ++k) a += __cosf((ts - net[k]) * w + bb);
            }
            o[j] = (f16)a;
        }
        *(f16x8*)(G + (size_t)b * 544 + 176 + k0) = o;
    } else if (c < 66) {
        int k0 = (c - 44) * 8;
        const bool full = (c != 65);
        float4 e0[KK], e1[KK];
        #pragma unroll
        for (int k = 0; k < KK; ++k) {
            const float* e = edge_features + (size_t)nbr_edge_idxs[b * KK + k] * D + k0;
            e0[k] = *(const float4*)e;
            if (full) e1[k] = *(const float4*)(e + 4);
            else      e1[k] = make_float4(0.f, 0.f, 0.f, 0.f);
        }
        float a[8] = {};
        #pragma unroll
        for (int k = 0; k < KK; ++k) {
            a[0] += e0[k].x; a[1] += e0[k].y; a[2] += e0[k].z; a[3] += e0[k].w;
            a[4] += e1[k].x; a[5] += e1[k].y; a[6] += e1[k].z; a[7] += e1[k].w;
        }
        f16x8 o;
        #pragma unroll
        for (int j = 0; j < 8; ++j) o[j] = (f16)a[j];
        *(f16x8*)(G + (size_t)b * 544 + 352 + k0) = o;
    } else if (c < 68) {
        f16x8 z = {};
        *(f16x8*)(G + (size_t)b * 544 + 528 + (c - 66) * 8) = z;
    } else {
        int cc = c - 68;
        *(f16x8*)(CAT2 + (size_t)b * 352 + 176 + cc * 8) =
            *(const f16x8*)(FEAT + (size_t)sources[b] * 176 + cc * 8);
    }
}

// ---------------- MFMA GEMMs: one wave per 16x16 output tile ----------------
// Lane l: A row = R0+(l&15), B col = C0+(l&15), k-chunk = 8*(l>>4)+32*s.
// D: col = C0+(l&15), row = R0 + 4*(l>>4) + reg   [m89-verified]

// GEMM 1: MSG16[cnt x 704] @ Wc^T -> FEAT16[nid[r]] = fp16(tanh(acc+bcomb) + tnf)
__global__ __launch_bounds__(256, 8) void gemm_rnn(
    const f16* __restrict__ MSG, const f16* __restrict__ Wc, const float* __restrict__ bcomb,
    const int* __restrict__ nid, const int* __restrict__ cnt,
    const float* __restrict__ tnf, f16* __restrict__ FEAT)
{
    const int c = *cnt;
    const int w = (blockIdx.x * 256 + threadIdx.x) >> 6;
    const int mt = w / 11, nt = w - mt * 11;
    const int R0 = mt * 16, C0 = nt * 16;
    if (R0 >= c) return;
    const int l = threadIdx.x & 63;
    const int lane16 = l & 15, koff = (l >> 4) * 8;
    int rowA = R0 + lane16; if (rowA >= c) rowA = c - 1;
    const f16* Ap = MSG + (size_t)rowA * 704 + koff;
    const f16* Bp = Wc + (size_t)(C0 + lane16) * 704 + koff;
    f32x4 acc = {};
    #pragma unroll 4
    for (int s = 0; s < 22; ++s) {
        f16x8 a = *(const f16x8*)(Ap + s * 32);
        f16x8 b = *(const f16x8*)(Bp + s * 32);
        acc = __builtin_amdgcn_mfma_f32_16x16x32_f16(a, b, acc, 0, 0, 0);
    }
    const int col = C0 + lane16;
    const int rbase = R0 + (l >> 4) * 4;
    const float bc = (col < D) ? bcomb[col] : 0.f;
    #pragma unroll
    for (int reg = 0; reg < 4; ++reg) {
        int r = rbase + reg;
        if (r >= c || col >= D) continue;
        int n = nid[r];
        float v = tanhf(acc[reg] + bc) + tnf[(size_t)n * D + col];
        FEAT[(size_t)n * 176 + col] = (f16)v;
    }
}

// GEMM 2: G16[8192 x 544] @ W1^T -> CAT2[:,0:172] = relu(acc + 10*b1), pads 0
__global__ __launch_bounds__(256, 8) void gemm_lin1(
    const f16* __restrict__ G, const f16* __restrict__ W1,
    const float* __restrict__ lin1_b, f16* __restrict__ CAT2)
{
    const int w = (blockIdx.x * 256 + threadIdx.x) >> 6;
    const int mt = w / 11, nt = w - mt * 11;
    const int R0 = mt * 16, C0 = nt * 16;
    const int l = threadIdx.x & 63;
    const int lane16 = l & 15, koff = (l >> 4) * 8;
    const f16* Ap = G + (size_t)(R0 + lane16) * 544 + koff;
    const f16* Bp = W1 + (size_t)(C0 + lane16) * 544 + koff;
    f32x4 acc = {};
    #pragma unroll 4
    for (int s = 0; s < 17; ++s) {
        f16x8 a = *(const f16x8*)(Ap + s * 32);
        f16x8 b = *(const f16x8*)(Bp + s * 32);
        acc = __builtin_amdgcn_mfma_f32_16x16x32_f16(a, b, acc, 0, 0, 0);
    }
    const int col = C0 + lane16;
    const int rbase = R0 + (l >> 4) * 4;
    const float bb = (col < D) ? 10.0f * lin1_b[col] : 0.f;
    #pragma unroll
    for (int reg = 0; reg < 4; ++reg) {
        int r = rbase + reg;
        f16 v = (f16)0.f;
        if (col < D) v = (f16)fmaxf(acc[reg] + bb, 0.f);
        CAT2[(size_t)r * 352 + col] = v;
    }
}

// GEMM 3: CAT2[8192 x 352] @ W2^T -> EMB16 = acc + embc, cols 172..191 zero
__global__ __launch_bounds__(256, 8) void gemm_lin2(
    const f16* __restrict__ CAT2, const f16* __restrict__ W2,
    const float* __restrict__ embc, f16* __restrict__ EMB)
{
    const int w = (blockIdx.x * 256 + threadIdx.x) >> 6;
    const int mt = w / 11, nt = w - mt * 11;
    const int R0 = mt * 16, C0 = nt * 16;
    const int l = threadIdx.x & 63;
    const int lane16 = l & 15, koff = (l >> 4) * 8;
    const f16* Ap = CAT2 + (size_t)(R0 + lane16) * 352 + koff;
    const f16* Bp = W2 + (size_t)(C0 + lane16) * 352 + koff;
    f32x4 acc = {};
    #pragma unroll 4
    for (int s = 0; s < 11; ++s) {
        f16x8 a = *(const f16x8*)(Ap + s * 32);
        f16x8 b = *(const f16x8*)(Bp + s * 32);
        acc = __builtin_amdgcn_mfma_f32_16x16x32_f16(a, b, acc, 0, 0, 0);
    }
    const int col = C0 + lane16;
    const int rbase = R0 + (l >> 4) * 4;
    const float ec = (col < D) ? embc[col] : 0.f;
    #pragma unroll
    for (int reg = 0; reg < 4; ++reg) {
        int r = rbase + reg;
        f16 v = (f16)0.f;
        if (col < D) v = (f16)(acc[reg] + ec);
        EMB[(size_t)r * 192 + col] = v;
        if (nt == 10) EMB[(size_t)r * 192 + 176 + lane16] = (f16)0.f;
    }
}

// GEMM 4 + MLP tail fused: 320 threads = 5 waves; wave nt does col-tile nt of 16 rows
__global__ __launch_bounds__(320) void gemm_mlp(
    const f16* __restrict__ EMB, const f16* __restrict__ Wm1, const float* __restrict__ b1,
    const float* __restrict__ w2, const float* __restrict__ b2,
    const float* __restrict__ w3, const float* __restrict__ b3, float* __restrict__ out)
{
    __shared__ float sH[16][84];
    __shared__ float s_w2[10 * HIDD];
    __shared__ float s_b2[10], s_w3[10], s_b3;
    const int t = threadIdx.x;
    for (int i = t; i < 10 * HIDD; i += 320) s_w2[i] = w2[i];
    if (t < 10) { s_b2[t] = b2[t]; s_w3[t] = w3[t]; }
    if (t == 10) s_b3 = b3[0];
    const int wv = t >> 6, l = t & 63;
    const int lane16 = l & 15, koff = (l >> 4) * 8;
    const int R0 = blockIdx.x * 16, C0 = wv * 16;
    const f16* Ap = EMB + (size_t)(R0 + lane16) * 192 + koff;
    const f16* Bp = Wm1 + (size_t)(C0 + lane16) * 192 + koff;
    f32x4 acc = {};
    #pragma unroll
    for (int s = 0; s < 6; ++s) {
        f16x8 a = *(const f16x8*)(Ap + s * 32);
        f16x8 b = *(const f16x8*)(Bp + s * 32);
        acc = __builtin_amdgcn_mfma_f32_16x16x32_f16(a, b, acc, 0, 0, 0);
    }
    const int col = C0 + lane16;
    const int rloc = (l >> 4) * 4;
    #pragma unroll
    for (int reg = 0; reg < 4; ++reg)
        sH[rloc + reg][col] = fmaxf(acc[reg] + b1[col], 0.f);
    __syncthreads();
    if (t < 16) {
        float h2[10];
        #pragma unroll
        for (int j = 0; j < 10; ++j) h2[j] = s_b2[j];
        for (int f = 0; f < HIDD; ++f) {
            float hv = sH[t][f];
            #pragma unroll
            for (int j = 0; j < 10; ++j) h2[j] = fmaf(hv, s_w2[j * HIDD + f], h2[j]);
        }
        float logit = s_b3;
        #pragma unroll
        for (int j = 0; j < 10; ++j) logit += fmaxf(h2[j], 0.f) * s_w3[j];
        out[R0 + t] = 1.f / (1.f + expf(-logit));
    }
}

// ---------------- host ----------------

extern "C" void kernel_launch(void* const* d_in, const int* in_sizes, int n_in,
                              void* d_out, int out_size, void* d_ws, size_t ws_size,
                              hipStream_t stream) {
    const float* timestamps     = (const float*)d_in[0];
    const float* edge_features  = (const float*)d_in[1];
    const float* tnf            = (const float*)d_in[2];
    const float* node_mem       = (const float*)d_in[3];
    const float* last_updated   = (const float*)d_in[4];
    const float* nbr_edge_times = (const float*)d_in[5];
    const float* time_w         = (const float*)d_in[6];
    const float* time_b         = (const float*)d_in[7];
    const float* Wih            = (const float*)d_in[8];
    const float* Whh            = (const float*)d_in[9];
    const float* bih            = (const float*)d_in[10];
    const float* bhh            = (const float*)d_in[11];
    const float* lin1_w         = (const float*)d_in[12];
    const float* lin1_b         = (const float*)d_in[13];
    const float* lin2_w         = (const float*)d_in[14];
    const float* lin2_b         = (const float*)d_in[15];
    const float* w1             = (const float*)d_in[16];
    const float* b1             = (const float*)d_in[17];
    const float* w2             = (const float*)d_in[18];
    const float* b2             = (const float*)d_in[19];
    const float* w3             = (const float*)d_in[20];
    const float* b3             = (const float*)d_in[21];
    const int* sources          = (const int*)d_in[22];
    const int* destinations     = (const int*)d_in[23];
    const int* edge_idxs        = (const int*)d_in[24];
    const int* neighbors        = (const int*)d_in[25];
    const int* nbr_edge_idxs    = (const int*)d_in[26];
    float* out = (float*)d_out;

    char* p = (char*)d_ws;
    auto bump = [&p](size_t bytes) { char* r = p; p += (bytes + 255) & ~(size_t)255; return r; };
    int* last_idx = (int*)bump(N_NODES * 4);
    int* nid      = (int*)bump(N_NODES * 4);
    int* li_arr   = (int*)bump(N_NODES * 4);
    int* cnt      = (int*)bump(256);
    f16* Wc16     = (f16*)bump((size_t)176 * 704 * 2);
    f16* W1_16    = (f16*)bump((size_t)176 * 544 * 2);
    f16* W2_16    = (f16*)bump((size_t)176 * 352 * 2);
    f16* Wm1_16   = (f16*)bump((size_t)80 * 192 * 2);
    float* bcomb  = (float*)bump(D * 4);
    float* embc   = (float*)bump(D * 4);
    f16* FEAT16   = (f16*)bump((size_t)N_NODES * 176 * 2);
    f16* MSG16    = (f16*)bump((size_t)N_NODES * 704 * 2);
    f16* G16      = (f16*)bump((size_t)BB * 544 * 2);
    f16* CAT2_16  = (f16*)bump((size_t)BB * 352 * 2);
    f16* EMB16    = (f16*)bump((size_t)BB * 192 * 2);

    hipLaunchKernelGGL(init_lastidx, dim3((N_NODES + 255) / 256), dim3(256), 0, stream, last_idx, cnt);
    hipLaunchKernelGGL(scatter_last, dim3(BB / 256), dim3(256), 0, stream, sources, last_idx);
    hipLaunchKernelGGL(compact_nodes, dim3((N_NODES + 255) / 256), dim3(256), 0, stream,
                       last_idx, nid, li_arr, cnt);

    hipLaunchKernelGGL(conv_weights, dim3((176 * 704 + 255) / 256, 5), dim3(256), 0, stream,
                       Wih, Whh, lin1_w, lin2_w, w1, bih, bhh, lin2_b, time_b,
                       Wc16, W1_16, W2_16, Wm1_16, bcomb, embc);

    hipLaunchKernelGGL(copy_feat16, dim3((N_NODES * 22 + 255) / 256), dim3(256), 0, stream,
                       node_mem, tnf, FEAT16);
    hipLaunchKernelGGL(gather_msg, dim3((N_NODES * 88 + 255) / 256), dim3(256), 0, stream,
                       nid, li_arr, cnt, destinations, edge_idxs, timestamps, last_updated,
                       node_mem, edge_features, time_w, time_b, MSG16);
    // waves = ceil(8192/16)*11 = 5632 -> 1408 blocks of 4 waves
    hipLaunchKernelGGL(gemm_rnn, dim3(1408), dim3(256), 0, stream,
                       MSG16, Wc16, bcomb, nid, cnt, tnf, FEAT16);

    hipLaunchKernelGGL(gather_G, dim3((BB * 90 + 255) / 256), dim3(256), 0, stream,
                       FEAT16, edge_features, timestamps, nbr_edge_times,
                       neighbors, nbr_edge_idxs, sources, time_w, time_b, G16, CAT2_16);

    hipLaunchKernelGGL(gemm_lin1, dim3(1408), dim3(256), 0, stream,
                       G16, W1_16, lin1_b, CAT2_16);
    hipLaunchKernelGGL(gemm_lin2, dim3(1408), dim3(256), 0, stream,
                       CAT2_16, W2_16, embc, EMB16);
    hipLaunchKernelGGL(gemm_mlp, dim3(BB / 16), dim3(320), 0, stream,
                       EMB16, Wm1_16, b1, w2, b2, w3, b3, out);
}

// Round 7
// 125.703 us; speedup vs baseline: 14.9492x; 1.1302x over previous
//
#include <hip/hip_runtime.h>
#include <math.h>

#define N_NODES 10000
#define BB 8192
#define KK 10
#define D 172
#define HIDD 80

typedef _Float16 f16;
typedef f16 f16x8 __attribute__((ext_vector_type(8)));
typedef f16 f16x4 __attribute__((ext_vector_type(4)));
typedef float f32x4 __attribute__((ext_vector_type(4)));

// ---------------- index prep ----------------

__global__ void init_lastidx(int* __restrict__ last_idx, int* __restrict__ cnt) {
    int i = blockIdx.x * blockDim.x + threadIdx.x;
    if (i < N_NODES) last_idx[i] = -1;
    if (i == 0) *cnt = 0;
}

__global__ void scatter_last(const int* __restrict__ sources, int* __restrict__ last_idx) {
    int b = blockIdx.x * blockDim.x + threadIdx.x;
    if (b < BB) atomicMax(&last_idx[sources[b]], b);
}

__global__ void compact_nodes(const int* __restrict__ last_idx, int* __restrict__ nid,
                              int* __restrict__ li_arr, int* __restrict__ cnt) {
    int n = blockIdx.x * blockDim.x + threadIdx.x;
    if (n < N_NODES) {
        int li = last_idx[n];
        if (li >= 0) { int p = atomicAdd(cnt, 1); nid[p] = n; li_arr[p] = li; }
    }
}

// ---------------- weight conversion (192-row padded) + FEAT copy, 6 planes ----------------
// Wc[192][704], W1[192][544], W2[192][352], Wm1[80][192]
__global__ __launch_bounds__(256) void conv_weights(
    const float* __restrict__ Wih, const float* __restrict__ Whh,
    const float* __restrict__ lin1_w, const float* __restrict__ lin2_w,
    const float* __restrict__ w1,
    const float* __restrict__ bih, const float* __restrict__ bhh,
    const float* __restrict__ lin2_b, const float* __restrict__ tb,
    const float* __restrict__ node_mem, const float* __restrict__ tnf,
    f16* __restrict__ Wc, f16* __restrict__ W1, f16* __restrict__ W2,
    f16* __restrict__ Wm1, float* __restrict__ bcomb, float* __restrict__ embc,
    f16* __restrict__ FEAT)
{
    const int which = blockIdx.y;
    const int idx = blockIdx.x * 256 + threadIdx.x;
    if (which == 0) {
        if (idx >= 192 * 704) return;
        int n = idx / 704, k = idx % 704, seg = k / 176, kk = k % 176;
        float v = 0.f;
        if (n < D && kk < D) {
            v = Wih[n * 688 + seg * D + kk];
            if (seg == 0) v += Whh[n * D + kk];
        }
        Wc[idx] = (f16)v;
    } else if (which == 1) {
        if (idx >= 192 * 544) return;
        int n = idx / 544, k = idx % 544, seg = k / 176, kk = k % 176;
        float v = 0.f;
        if (n < D && seg < 3 && kk < D) v = lin1_w[n * 516 + seg * D + kk];
        W1[idx] = (f16)v;
    } else if (which == 2) {
        if (idx >= 192 * 352) return;
        int n = idx / 352, k = idx % 352, seg = k / 176, kk = k % 176;
        float v = 0.f;
        if (n < D && kk < D) v = lin2_w[n * 516 + seg * D + kk];
        W2[idx] = (f16)v;
    } else if (which == 3) {
        if (idx >= 80 * 192) return;
        int n = idx / 192, k = idx % 192;
        Wm1[idx] = (f16)((k < D) ? w1[n * D + k] : 0.f);
    } else if (which == 4) {
        if (idx < D) {
            bcomb[idx] = bih[idx] + bhh[idx];
            float acc = lin2_b[idx];
            for (int j = 0; j < D; ++j) acc += lin2_w[idx * 516 + 344 + j] * __cosf(tb[j]);
            embc[idx] = acc;
        }
    } else {
        if (idx >= N_NODES * 22) return;
        int n = idx / 22, k0 = (idx % 22) * 8;
        f16x8 o;
        #pragma unroll
        for (int j = 0; j < 8; ++j) {
            int kk = k0 + j;
            float v = (kk < D) ? node_mem[(size_t)n * D + kk] + tnf[(size_t)n * D + kk] : 0.f;
            o[j] = (f16)v;
        }
        *(f16x8*)(FEAT + (size_t)n * 176 + k0) = o;
    }
}

// ---------------- gather MSG ----------------
__global__ __launch_bounds__(256) void gather_msg(
    const int* __restrict__ nid, const int* __restrict__ li_arr, const int* __restrict__ cnt,
    const int* __restrict__ destinations, const int* __restrict__ edge_idxs,
    const float* __restrict__ timestamps, const float* __restrict__ last_updated,
    const float* __restrict__ node_mem, const float* __restrict__ edge_features,
    const float* __restrict__ tw, const float* __restrict__ tb, f16* __restrict__ MSG)
{
    int idx = blockIdx.x * 256 + threadIdx.x;
    int i = idx / 88;
    if (i >= *cnt) return;
    int t = idx % 88, seg = t / 22, k0 = (t % 22) * 8;
    int n = nid[i], li = li_arr[i];
    f16x8 o;
    if (seg < 3) {
        const float* src = (seg == 0) ? node_mem + (size_t)n * D
                         : (seg == 1) ? node_mem + (size_t)destinations[li] * D
                                      : edge_features + (size_t)edge_idxs[li] * D;
        #pragma unroll
        for (int j = 0; j < 8; ++j) {
            int kk = k0 + j;
            o[j] = (f16)((kk < D) ? src[kk] : 0.f);
        }
    } else {
        float dt = timestamps[li] - last_updated[n];
        #pragma unroll
        for (int j = 0; j < 8; ++j) {
            int kk = k0 + j;
            o[j] = (f16)((kk < D) ? __cosf(dt * tw[kk] + tb[kk]) : 0.f);
        }
    }
    *(f16x8*)(MSG + (size_t)i * 704 + seg * 176 + k0) = o;
}

// ---------------- gather_G: planar-major, uniform ~10-load threads ----------------
// P0 [0, 8192*22):            FEAT-sum chunk c (8 cols)  -> G[b][c*8]
// P1 [.., +8192*22):          timeenc chunk c (8 cols)   -> G[b][176+c*8]
// P2 [.., +8192*44):          ef-sum chunk c (4 cols)    -> G[b][352+c*4]
// P3 [.., +8192*24): c<22 src-copy -> CAT2[b][176+c*8]; c>=22 zero-pad G[b][528+...]
#define P0_END (BB * 22)
#define P1_END (BB * 44)
#define P2_END (BB * 88)
#define P3_END (BB * 112)

__global__ __launch_bounds__(256) void gather_G(
    const f16* __restrict__ FEAT, const float* __restrict__ edge_features,
    const float* __restrict__ timestamps, const float* __restrict__ nbr_edge_times,
    const int* __restrict__ neighbors, const int* __restrict__ nbr_edge_idxs,
    const int* __restrict__ sources,
    const float* __restrict__ tw, const float* __restrict__ tb,
    f16* __restrict__ G, f16* __restrict__ CAT2)
{
    int gid = blockIdx.x * 256 + threadIdx.x;
    if (gid < P0_END) {
        int b = gid / 22, c = gid - b * 22;
        int nb[KK];
        #pragma unroll
        for (int k = 0; k < KK; ++k) nb[k] = neighbors[b * KK + k];
        f16x8 v[KK];
        #pragma unroll
        for (int k = 0; k < KK; ++k)
            v[k] = *(const f16x8*)(FEAT + (size_t)nb[k] * 176 + c * 8);
        float a[8] = {};
        #pragma unroll
        for (int k = 0; k < KK; ++k) {
            #pragma unroll
            for (int j = 0; j < 8; ++j) a[j] += (float)v[k][j];
        }
        f16x8 o;
        #pragma unroll
        for (int j = 0; j < 8; ++j) o[j] = (f16)a[j];
        *(f16x8*)(G + (size_t)b * 544 + c * 8) = o;
    } else if (gid < P1_END) {
        int g = gid - P0_END;
        int b = g / 22, c = g - b * 22;
        int k0 = c * 8;
        float ts = timestamps[b];
        float net[KK];
        #pragma unroll
        for (int k = 0; k < KK; ++k) net[k] = nbr_edge_times[b * KK + k];
        f16x8 o;
        #pragma unroll
        for (int j = 0; j < 8; ++j) {
            int kk = k0 + j;
            float a = 0.f;
            if (kk < D) {
                float w = tw[kk], bb = tb[kk];
                #pragma unroll
                for (int k = 0; k < KK; ++k) a += __cosf((ts - net[k]) * w + bb);
            }
            o[j] = (f16)a;
        }
        *(f16x8*)(G + (size_t)b * 544 + 176 + k0) = o;
    } else if (gid < P2_END) {
        int g = gid - P1_END;
        int b = g / 44, c = g - b * 44;
        if (c == 43) {  // cols 172..175 invalid
            f16x4 z = {};
            *(f16x4*)(G + (size_t)b * 544 + 352 + c * 4) = z;
            return;
        }
        int ne[KK];
        #pragma unroll
        for (int k = 0; k < KK; ++k) ne[k] = nbr_edge_idxs[b * KK + k];
        float4 e[KK];
        #pragma unroll
        for (int k = 0; k < KK; ++k)
            e[k] = *(const float4*)(edge_features + (size_t)ne[k] * D + c * 4);
        float a0 = 0.f, a1 = 0.f, a2 = 0.f, a3 = 0.f;
        #pragma unroll
        for (int k = 0; k < KK; ++k) { a0 += e[k].x; a1 += e[k].y; a2 += e[k].z; a3 += e[k].w; }
        f16x4 o; o[0] = (f16)a0; o[1] = (f16)a1; o[2] = (f16)a2; o[3] = (f16)a3;
        *(f16x4*)(G + (size_t)b * 544 + 352 + c * 4) = o;
    } else if (gid < P3_END) {
        int g = gid - P2_END;
        int b = g / 24, c = g - b * 24;
        if (c < 22) {
            *(f16x8*)(CAT2 + (size_t)b * 352 + 176 + c * 8) =
                *(const f16x8*)(FEAT + (size_t)sources[b] * 176 + c * 8);
        } else {
            f16x8 z = {};
            *(f16x8*)(G + (size_t)b * 544 + 528 + (c - 22) * 8) = z;
        }
    }
}

// ---------------- MFMA GEMMs: one wave per 16x32 output tile (NFRAG=2) ----------------
// Lane l: A row = R0+(l&15), B cols = C0+(l&15), C0+16+(l&15); k-chunk = 8*(l>>4)+32*s.
// D: col = C0(+16)+(l&15), row = R0 + 4*(l>>4) + reg

// GEMM 1: MSG[cnt x 704] @ Wc^T[192] -> FEAT[nid[r]] = fp16(tanh(acc+bcomb) + tnf)
__global__ __launch_bounds__(256, 4) void gemm_rnn(
    const f16* __restrict__ MSG, const f16* __restrict__ Wc, const float* __restrict__ bcomb,
    const int* __restrict__ nid, const int* __restrict__ cnt,
    const float* __restrict__ tnf, f16* __restrict__ FEAT)
{
    const int c = *cnt;
    const int w = (blockIdx.x * 256 + threadIdx.x) >> 6;
    const int mt = w / 6, ng = w - mt * 6;
    const int R0 = mt * 16, C0 = ng * 32;
    if (R0 >= c) return;
    const int l = threadIdx.x & 63;
    const int lane16 = l & 15, koff = (l >> 4) * 8;
    int rowA = R0 + lane16; if (rowA >= c) rowA = c - 1;
    const f16* Ap  = MSG + (size_t)rowA * 704 + koff;
    const f16* Bp0 = Wc + (size_t)(C0 + lane16) * 704 + koff;
    const f16* Bp1 = Bp0 + (size_t)16 * 704;
    f32x4 acc0 = {}, acc1 = {};
    #pragma unroll 4
    for (int s = 0; s < 22; ++s) {
        f16x8 a  = *(const f16x8*)(Ap + s * 32);
        f16x8 b0 = *(const f16x8*)(Bp0 + s * 32);
        f16x8 b1 = *(const f16x8*)(Bp1 + s * 32);
        acc0 = __builtin_amdgcn_mfma_f32_16x16x32_f16(a, b0, acc0, 0, 0, 0);
        acc1 = __builtin_amdgcn_mfma_f32_16x16x32_f16(a, b1, acc1, 0, 0, 0);
    }
    const int col0 = C0 + lane16, col1 = col0 + 16;
    const int rbase = R0 + (l >> 4) * 4;
    const float bc0 = (col0 < D) ? bcomb[col0] : 0.f;
    const float bc1 = (col1 < D) ? bcomb[col1] : 0.f;
    #pragma unroll
    for (int reg = 0; reg < 4; ++reg) {
        int r = rbase + reg;
        if (r >= c) continue;
        int n = nid[r];
        if (col0 < D)
            FEAT[(size_t)n * 176 + col0] = (f16)(tanhf(acc0[reg] + bc0) + tnf[(size_t)n * D + col0]);
        if (col1 < D)
            FEAT[(size_t)n * 176 + col1] = (f16)(tanhf(acc1[reg] + bc1) + tnf[(size_t)n * D + col1]);
    }
}

// GEMM 2: G[8192 x 544] @ W1^T[192] -> CAT2[:,0:176) = relu(acc + 10*b1) (cols>=176 skipped)
__global__ __launch_bounds__(256, 4) void gemm_lin1(
    const f16* __restrict__ G, const f16* __restrict__ W1,
    const float* __restrict__ lin1_b, f16* __restrict__ CAT2)
{
    const int w = (blockIdx.x * 256 + threadIdx.x) >> 6;
    const int mt = w / 6, ng = w - mt * 6;
    const int R0 = mt * 16, C0 = ng * 32;
    const int l = threadIdx.x & 63;
    const int lane16 = l & 15, koff = (l >> 4) * 8;
    const f16* Ap  = G + (size_t)(R0 + lane16) * 544 + koff;
    const f16* Bp0 = W1 + (size_t)(C0 + lane16) * 544 + koff;
    const f16* Bp1 = Bp0 + (size_t)16 * 544;
    f32x4 acc0 = {}, acc1 = {};
    #pragma unroll 4
    for (int s = 0; s < 17; ++s) {
        f16x8 a  = *(const f16x8*)(Ap + s * 32);
        f16x8 b0 = *(const f16x8*)(Bp0 + s * 32);
        f16x8 b1 = *(const f16x8*)(Bp1 + s * 32);
        acc0 = __builtin_amdgcn_mfma_f32_16x16x32_f16(a, b0, acc0, 0, 0, 0);
        acc1 = __builtin_amdgcn_mfma_f32_16x16x32_f16(a, b1, acc1, 0, 0, 0);
    }
    const int col0 = C0 + lane16, col1 = col0 + 16;
    const int rbase = R0 + (l >> 4) * 4;
    const float bb0 = (col0 < D) ? 10.0f * lin1_b[col0] : 0.f;
    const float bb1 = (col1 < D) ? 10.0f * lin1_b[col1] : 0.f;
    #pragma unroll
    for (int reg = 0; reg < 4; ++reg) {
        int r = rbase + reg;
        if (col0 < 176)
            CAT2[(size_t)r * 352 + col0] = (col0 < D) ? (f16)fmaxf(acc0[reg] + bb0, 0.f) : (f16)0.f;
        if (col1 < 176)
            CAT2[(size_t)r * 352 + col1] = (col1 < D) ? (f16)fmaxf(acc1[reg] + bb1, 0.f) : (f16)0.f;
    }
}

// GEMM 3: CAT2[8192 x 352] @ W2^T[192] -> EMB[8192 x 192] = acc + embc (cols>=172 zero)
__global__ __launch_bounds__(256, 4) void gemm_lin2(
    const f16* __restrict__ CAT2, const f16* __restrict__ W2,
    const float* __restrict__ embc, f16* __restrict__ EMB)
{
    const int w = (blockIdx.x * 256 + threadIdx.x) >> 6;
    const int mt = w / 6, ng = w - mt * 6;
    const int R0 = mt * 16, C0 = ng * 32;
    const int l = threadIdx.x & 63;
    const int lane16 = l & 15, koff = (l >> 4) * 8;
    const f16* Ap  = CAT2 + (size_t)(R0 + lane16) * 352 + koff;
    const f16* Bp0 = W2 + (size_t)(C0 + lane16) * 352 + koff;
    const f16* Bp1 = Bp0 + (size_t)16 * 352;
    f32x4 acc0 = {}, acc1 = {};
    #pragma unroll 4
    for (int s = 0; s < 11; ++s) {
        f16x8 a  = *(const f16x8*)(Ap + s * 32);
        f16x8 b0 = *(const f16x8*)(Bp0 + s * 32);
        f16x8 b1 = *(const f16x8*)(Bp1 + s * 32);
        acc0 = __builtin_amdgcn_mfma_f32_16x16x32_f16(a, b0, acc0, 0, 0, 0);
        acc1 = __builtin_amdgcn_mfma_f32_16x16x32_f16(a, b1, acc1, 0, 0, 0);
    }
    const int col0 = C0 + lane16, col1 = col0 + 16;
    const int rbase = R0 + (l >> 4) * 4;
    const float ec0 = (col0 < D) ? embc[col0] : 0.f;
    const float ec1 = (col1 < D) ? embc[col1] : 0.f;
    #pragma unroll
    for (int reg = 0; reg < 4; ++reg) {
        int r = rbase + reg;
        EMB[(size_t)r * 192 + col0] = (col0 < D) ? (f16)(acc0[reg] + ec0) : (f16)0.f;
        EMB[(size_t)r * 192 + col1] = (col1 < D) ? (f16)(acc1[reg] + ec1) : (f16)0.f;
    }
}

// GEMM 4 + MLP tail fused: 320 threads = 5 waves; wave wv does col-tile wv of 16 rows
__global__ __launch_bounds__(320) void gemm_mlp(
    const f16* __restrict__ EMB, const f16* __restrict__ Wm1, const float* __restrict__ b1,
    const float* __restrict__ w2, const float* __restrict__ b2,
    const float* __restrict__ w3, const float* __restrict__ b3, float* __restrict__ out)
{
    __shared__ float sH[16][84];
    __shared__ float s_w2[10 * HIDD];
    __shared__ float s_b2[10], s_w3[10], s_b3;
    const int t = threadIdx.x;
    for (int i = t; i < 10 * HIDD; i += 320) s_w2[i] = w2[i];
    if (t < 10) { s_b2[t] = b2[t]; s_w3[t] = w3[t]; }
    if (t == 10) s_b3 = b3[0];
    const int wv = t >> 6, l = t & 63;
    const int lane16 = l & 15, koff = (l >> 4) * 8;
    const int R0 = blockIdx.x * 16, C0 = wv * 16;
    const f16* Ap = EMB + (size_t)(R0 + lane16) * 192 + koff;
    const f16* Bp = Wm1 + (size_t)(C0 + lane16) * 192 + koff;
    f32x4 acc = {};
    #pragma unroll
    for (int s = 0; s < 6; ++s) {
        f16x8 a = *(const f16x8*)(Ap + s * 32);
        f16x8 b = *(const f16x8*)(Bp + s * 32);
        acc = __builtin_amdgcn_mfma_f32_16x16x32_f16(a, b, acc, 0, 0, 0);
    }
    const int col = C0 + lane16;
    const int rloc = (l >> 4) * 4;
    #pragma unroll
    for (int reg = 0; reg < 4; ++reg)
        sH[rloc + reg][col] = fmaxf(acc[reg] + b1[col], 0.f);
    __syncthreads();
    if (t < 16) {
        float h2[10];
        #pragma unroll
        for (int j = 0; j < 10; ++j) h2[j] = s_b2[j];
        for (int f = 0; f < HIDD; ++f) {
            float hv = sH[t][f];
            #pragma unroll
            for (int j = 0; j < 10; ++j) h2[j] = fmaf(hv, s_w2[j * HIDD + f], h2[j]);
        }
        float logit = s_b3;
        #pragma unroll
        for (int j = 0; j < 10; ++j) logit += fmaxf(h2[j], 0.f) * s_w3[j];
        out[R0 + t] = 1.f / (1.f + expf(-logit));
    }
}

// ---------------- host ----------------

extern "C" void kernel_launch(void* const* d_in, const int* in_sizes, int n_in,
                              void* d_out, int out_size, void* d_ws, size_t ws_size,
                              hipStream_t stream) {
    const float* timestamps     = (const float*)d_in[0];
    const float* edge_features  = (const float*)d_in[1];
    const float* tnf            = (const float*)d_in[2];
    const float* node_mem       = (const float*)d_in[3];
    const float* last_updated   = (const float*)d_in[4];
    const float* nbr_edge_times = (const float*)d_in[5];
    const float* time_w         = (const float*)d_in[6];
    const float* time_b         = (const float*)d_in[7];
    const float* Wih            = (const float*)d_in[8];
    const float* Whh            = (const float*)d_in[9];
    const float* bih            = (const float*)d_in[10];
    const float* bhh            = (const float*)d_in[11];
    const float* lin1_w         = (const float*)d_in[12];
    const float* lin1_b         = (const float*)d_in[13];
    const float* lin2_w         = (const float*)d_in[14];
    const float* lin2_b         = (const float*)d_in[15];
    const float* w1             = (const float*)d_in[16];
    const float* b1             = (const float*)d_in[17];
    const float* w2             = (const float*)d_in[18];
    const float* b2             = (const float*)d_in[19];
    const float* w3             = (const float*)d_in[20];
    const float* b3             = (const float*)d_in[21];
    const int* sources          = (const int*)d_in[22];
    const int* destinations     = (const int*)d_in[23];
    const int* edge_idxs        = (const int*)d_in[24];
    const int* neighbors        = (const int*)d_in[25];
    const int* nbr_edge_idxs    = (const int*)d_in[26];
    float* out = (float*)d_out;

    char* p = (char*)d_ws;
    auto bump = [&p](size_t bytes) { char* r = p; p += (bytes + 255) & ~(size_t)255; return r; };
    int* last_idx = (int*)bump(N_NODES * 4);
    int* nid      = (int*)bump(N_NODES * 4);
    int* li_arr   = (int*)bump(N_NODES * 4);
    int* cnt      = (int*)bump(256);
    f16* Wc16     = (f16*)bump((size_t)192 * 704 * 2);
    f16* W1_16    = (f16*)bump((size_t)192 * 544 * 2);
    f16* W2_16    = (f16*)bump((size_t)192 * 352 * 2);
    f16* Wm1_16   = (f16*)bump((size_t)80 * 192 * 2);
    float* bcomb  = (float*)bump(D * 4);
    float* embc   = (float*)bump(D * 4);
    f16* FEAT16   = (f16*)bump((size_t)N_NODES * 176 * 2);
    f16* MSG16    = (f16*)bump((size_t)N_NODES * 704 * 2);
    f16* G16      = (f16*)bump((size_t)BB * 544 * 2);
    f16* CAT2_16  = (f16*)bump((size_t)BB * 352 * 2);
    f16* EMB16    = (f16*)bump((size_t)BB * 192 * 2);

    hipLaunchKernelGGL(init_lastidx, dim3((N_NODES + 255) / 256), dim3(256), 0, stream, last_idx, cnt);
    hipLaunchKernelGGL(scatter_last, dim3(BB / 256), dim3(256), 0, stream, sources, last_idx);
    hipLaunchKernelGGL(compact_nodes, dim3((N_NODES + 255) / 256), dim3(256), 0, stream,
                       last_idx, nid, li_arr, cnt);

    // plane grid: max(ceil(192*704/256)=528, ceil(10000*22/256)=860) = 860
    hipLaunchKernelGGL(conv_weights, dim3(860, 6), dim3(256), 0, stream,
                       Wih, Whh, lin1_w, lin2_w, w1, bih, bhh, lin2_b, time_b,
                       node_mem, tnf, Wc16, W1_16, W2_16, Wm1_16, bcomb, embc, FEAT16);

    hipLaunchKernelGGL(gather_msg, dim3((N_NODES * 88 + 255) / 256), dim3(256), 0, stream,
                       nid, li_arr, cnt, destinations, edge_idxs, timestamps, last_updated,
                       node_mem, edge_features, time_w, time_b, MSG16);
    // waves = ceil(10000/16)*6 = 3750 -> 938 blocks
    hipLaunchKernelGGL(gemm_rnn, dim3(938), dim3(256), 0, stream,
                       MSG16, Wc16, bcomb, nid, cnt, tnf, FEAT16);

    hipLaunchKernelGGL(gather_G, dim3((BB * 112 + 255) / 256), dim3(256), 0, stream,
                       FEAT16, edge_features, timestamps, nbr_edge_times,
                       neighbors, nbr_edge_idxs, sources, time_w, time_b, G16, CAT2_16);

    // waves = 512*6 = 3072 -> 768 blocks
    hipLaunchKernelGGL(gemm_lin1, dim3(768), dim3(256), 0, stream,
                       G16, W1_16, lin1_b, CAT2_16);
    hipLaunchKernelGGL(gemm_lin2, dim3(768), dim3(256), 0, stream,
                       CAT2_16, W2_16, embc, EMB16);
    hipLaunchKernelGGL(gemm_mlp, dim3(BB / 16), dim3(320), 0, stream,
                       EMB16, Wm1_16, b1, w2, b2, w3, b3, out);
}

// Round 9
// 118.879 us; speedup vs baseline: 15.8074x; 1.0574x over previous
//
#include <hip/hip_runtime.h>
#include <math.h>

#define N_NODES 10000
#define BB 8192
#define KK 10
#define D 172
#define HIDD 80

typedef _Float16 f16;
typedef f16 f16x8 __attribute__((ext_vector_type(8)));
typedef f16 f16x4 __attribute__((ext_vector_type(4)));
typedef float f32x4 __attribute__((ext_vector_type(4)));

// ---------------- index prep ----------------

__global__ void scatter_last(const int* __restrict__ sources, int* __restrict__ last_idx) {
    int b = blockIdx.x * blockDim.x + threadIdx.x;
    if (b < BB) atomicMax(&last_idx[sources[b]], b);
}

__global__ void compact_nodes(const int* __restrict__ last_idx, int* __restrict__ nid,
                              int* __restrict__ li_arr, int* __restrict__ cnt) {
    int n = blockIdx.x * blockDim.x + threadIdx.x;
    if (n < N_NODES) {
        int li = last_idx[n];
        if (li >= 0) { int p = atomicAdd(cnt, 1); nid[p] = n; li_arr[p] = li; }
    }
}

// ---------------- weight conversion (192-row padded) + FEAT copy, 6 planes ----------------
__global__ __launch_bounds__(256) void conv_weights(
    const float* __restrict__ Wih, const float* __restrict__ Whh,
    const float* __restrict__ lin1_w, const float* __restrict__ lin2_w,
    const float* __restrict__ w1,
    const float* __restrict__ bih, const float* __restrict__ bhh,
    const float* __restrict__ lin2_b, const float* __restrict__ tb,
    const float* __restrict__ node_mem, const float* __restrict__ tnf,
    f16* __restrict__ Wc, f16* __restrict__ W1, f16* __restrict__ W2,
    f16* __restrict__ Wm1, float* __restrict__ bcomb, float* __restrict__ embc,
    f16* __restrict__ FEAT)
{
    const int which = blockIdx.y;
    const int idx = blockIdx.x * 256 + threadIdx.x;
    if (which == 0) {
        if (idx >= 192 * 704) return;
        int n = idx / 704, k = idx % 704, seg = k / 176, kk = k % 176;
        float v = 0.f;
        if (n < D && kk < D) {
            v = Wih[n * 688 + seg * D + kk];
            if (seg == 0) v += Whh[n * D + kk];
        }
        Wc[idx] = (f16)v;
    } else if (which == 1) {
        if (idx >= 192 * 544) return;
        int n = idx / 544, k = idx % 544, seg = k / 176, kk = k % 176;
        float v = 0.f;
        if (n < D && seg < 3 && kk < D) v = lin1_w[n * 516 + seg * D + kk];
        W1[idx] = (f16)v;
    } else if (which == 2) {
        if (idx >= 192 * 352) return;
        int n = idx / 352, k = idx % 352, seg = k / 176, kk = k % 176;
        float v = 0.f;
        if (n < D && kk < D) v = lin2_w[n * 516 + seg * D + kk];
        W2[idx] = (f16)v;
    } else if (which == 3) {
        if (idx >= 80 * 192) return;
        int n = idx / 192, k = idx % 192;
        Wm1[idx] = (f16)((k < D) ? w1[n * D + k] : 0.f);
    } else if (which == 4) {
        if (idx < D) {
            bcomb[idx] = bih[idx] + bhh[idx];
            float acc = lin2_b[idx];
            for (int j = 0; j < D; ++j) acc += lin2_w[idx * 516 + 344 + j] * __cosf(tb[j]);
            embc[idx] = acc;
        }
    } else {
        if (idx >= N_NODES * 22) return;
        int n = idx / 22, k0 = (idx % 22) * 8;
        f16x8 o;
        #pragma unroll
        for (int j = 0; j < 8; ++j) {
            int kk = k0 + j;
            float v = (kk < D) ? node_mem[(size_t)n * D + kk] + tnf[(size_t)n * D + kk] : 0.f;
            o[j] = (f16)v;
        }
        *(f16x8*)(FEAT + (size_t)n * 176 + k0) = o;
    }
}

// ---------------- GEMM 1 fused: stage MSG rows in LDS, MFMA (2 row-halves/wave), update FEAT ----------------
#define LDA_R 712   // 704 + 8 pad halfs

__global__ __launch_bounds__(384) void gemm_rnn_fused(
    const f16* __restrict__ Wc, const float* __restrict__ bcomb,
    const int* __restrict__ nid, const int* __restrict__ li_arr, const int* __restrict__ cnt,
    const int* __restrict__ destinations, const int* __restrict__ edge_idxs,
    const float* __restrict__ timestamps, const float* __restrict__ last_updated,
    const float* __restrict__ node_mem, const float* __restrict__ edge_features,
    const float* __restrict__ tw, const float* __restrict__ tb,
    const float* __restrict__ tnf, f16* __restrict__ FEAT)
{
    const int c = *cnt;
    const int R0 = blockIdx.x * 32;
    if (R0 >= c) return;
    __shared__ f16 As[32 * LDA_R];
    __shared__ int s_n[32], s_dst[32], s_ei[32];
    __shared__ float s_dt[32];
    const int t = threadIdx.x;
    if (t < 32) {
        int i = R0 + t; if (i > c - 1) i = c - 1;
        int n = nid[i], li = li_arr[i];
        s_n[t] = n; s_dst[t] = destinations[li]; s_ei[t] = edge_idxs[li];
        s_dt[t] = timestamps[li] - last_updated[n];
    }
    __syncthreads();
    for (int idx = t; idx < 32 * 88; idx += 384) {
        int row = idx / 88, sub = idx - row * 88;
        int seg = sub / 22, cpos = sub - seg * 22, k0 = cpos * 8;
        f16x8 o;
        if (seg < 3) {
            int n = (seg == 0) ? s_n[row] : (seg == 1) ? s_dst[row] : s_ei[row];
            const float* src = ((seg < 2) ? node_mem : edge_features) + (size_t)n * D + k0;
            float4 lo = *(const float4*)src;
            float4 hi = (cpos < 21) ? *(const float4*)(src + 4) : make_float4(0.f, 0.f, 0.f, 0.f);
            o[0] = (f16)lo.x; o[1] = (f16)lo.y; o[2] = (f16)lo.z; o[3] = (f16)lo.w;
            o[4] = (f16)hi.x; o[5] = (f16)hi.y; o[6] = (f16)hi.z; o[7] = (f16)hi.w;
        } else {
            float dt = s_dt[row];
            #pragma unroll
            for (int j = 0; j < 8; ++j) {
                int kk = k0 + j;
                o[j] = (f16)((kk < D) ? __cosf(dt * tw[kk] + tb[kk]) : 0.f);
            }
        }
        *(f16x8*)(As + row * LDA_R + seg * 176 + k0) = o;
    }
    __syncthreads();
    const int w = t >> 6, l = t & 63;
    const int lane16 = l & 15, koff = (l >> 4) * 8;
    const int C0 = w * 32;
    const f16* Al0 = As + lane16 * LDA_R + koff;
    const f16* Al1 = As + (16 + lane16) * LDA_R + koff;
    const f16* Bp0 = Wc + (size_t)(C0 + lane16) * 704 + koff;
    const f16* Bp1 = Bp0 + (size_t)16 * 704;
    f32x4 acc00 = {}, acc01 = {}, acc10 = {}, acc11 = {};
    #pragma unroll 2
    for (int s = 0; s < 22; ++s) {
        f16x8 a0 = *(const f16x8*)(Al0 + s * 32);
        f16x8 a1 = *(const f16x8*)(Al1 + s * 32);
        f16x8 b0 = *(const f16x8*)(Bp0 + s * 32);
        f16x8 b1 = *(const f16x8*)(Bp1 + s * 32);
        acc00 = __builtin_amdgcn_mfma_f32_16x16x32_f16(a0, b0, acc00, 0, 0, 0);
        acc01 = __builtin_amdgcn_mfma_f32_16x16x32_f16(a0, b1, acc01, 0, 0, 0);
        acc10 = __builtin_amdgcn_mfma_f32_16x16x32_f16(a1, b0, acc10, 0, 0, 0);
        acc11 = __builtin_amdgcn_mfma_f32_16x16x32_f16(a1, b1, acc11, 0, 0, 0);
    }
    const int col0 = C0 + lane16, col1 = col0 + 16;
    const int rloc = (l >> 4) * 4;
    const float bc0 = (col0 < D) ? bcomb[col0] : 0.f;
    const float bc1 = (col1 < D) ? bcomb[col1] : 0.f;
    #pragma unroll
    for (int rh = 0; rh < 2; ++rh) {
        const f32x4& A0 = rh ? acc10 : acc00;
        const f32x4& A1 = rh ? acc11 : acc01;
        #pragma unroll
        for (int reg = 0; reg < 4; ++reg) {
            int rl = rh * 16 + rloc + reg;
            int r = R0 + rl;
            if (r >= c) continue;
            int n = s_n[rl];
            if (col0 < D)
                FEAT[(size_t)n * 176 + col0] = (f16)(tanhf(A0[reg] + bc0) + tnf[(size_t)n * D + col0]);
            if (col1 < D)
                FEAT[(size_t)n * 176 + col1] = (f16)(tanhf(A1[reg] + bc1) + tnf[(size_t)n * D + col1]);
        }
    }
}

// ---------------- GEMM 2 fused: stage G rows in LDS (gathers), MFMA (2 row-halves), write CAT2 ----------------
#define LDA_1 552   // 544 + 8

__global__ __launch_bounds__(384) void gemm_lin1_fused(
    const f16* __restrict__ W1, const float* __restrict__ lin1_b,
    const f16* __restrict__ FEAT, const float* __restrict__ edge_features,
    const float* __restrict__ timestamps, const float* __restrict__ nbr_edge_times,
    const int* __restrict__ neighbors, const int* __restrict__ nbr_edge_idxs,
    const int* __restrict__ sources,
    const float* __restrict__ tw, const float* __restrict__ tb,
    f16* __restrict__ CAT2)
{
    __shared__ f16 As[32 * LDA_1];
    __shared__ int s_nbr[320], s_nei[320], s_src[32];
    __shared__ float s_net[320], s_ts[32];
    const int t = threadIdx.x;
    const int R0 = blockIdx.x * 32;
    if (t < 320) {
        s_nbr[t] = neighbors[R0 * KK + t];
        s_nei[t] = nbr_edge_idxs[R0 * KK + t];
        s_net[t] = nbr_edge_times[R0 * KK + t];
    } else if (t < 352) {
        s_ts[t - 320] = timestamps[R0 + t - 320];
    } else if (t < 384) {
        s_src[t - 352] = sources[R0 + t - 352];
    }
    __syncthreads();
    for (int idx = t; idx < 32 * 90 + 32 * 22; idx += 384) {
        if (idx < 32 * 90) {
            int row = idx / 90, c = idx - row * 90;
            if (c < 22) {
                int k0 = c * 8;
                float a[8] = {};
                #pragma unroll
                for (int k = 0; k < KK; ++k) {
                    f16x8 v = *(const f16x8*)(FEAT + (size_t)s_nbr[row * KK + k] * 176 + k0);
                    #pragma unroll
                    for (int j = 0; j < 8; ++j) a[j] += (float)v[j];
                }
                f16x8 o;
                #pragma unroll
                for (int j = 0; j < 8; ++j) o[j] = (f16)a[j];
                *(f16x8*)(As + row * LDA_1 + k0) = o;
            } else if (c < 44) {
                int k0 = (c - 22) * 8;
                float ts = s_ts[row];
                f16x8 o;
                #pragma unroll
                for (int j = 0; j < 8; ++j) {
                    int kk = k0 + j;
                    float a = 0.f;
                    if (kk < D) {
                        float w = tw[kk], bb = tb[kk];
                        #pragma unroll
                        for (int k = 0; k < KK; ++k) a += __cosf((ts - s_net[row * KK + k]) * w + bb);
                    }
                    o[j] = (f16)a;
                }
                *(f16x8*)(As + row * LDA_1 + 176 + k0) = o;
            } else if (c < 88) {
                int cc = c - 44;
                f16x4 o;
                if (cc == 43) {
                    o[0] = o[1] = o[2] = o[3] = (f16)0.f;
                } else {
                    float a0 = 0.f, a1 = 0.f, a2 = 0.f, a3 = 0.f;
                    #pragma unroll
                    for (int k = 0; k < KK; ++k) {
                        float4 e = *(const float4*)(edge_features + (size_t)s_nei[row * KK + k] * D + cc * 4);
                        a0 += e.x; a1 += e.y; a2 += e.z; a3 += e.w;
                    }
                    o[0] = (f16)a0; o[1] = (f16)a1; o[2] = (f16)a2; o[3] = (f16)a3;
                }
                *(f16x4*)(As + row * LDA_1 + 352 + cc * 4) = o;
            } else {
                f16x8 z = {};
                *(f16x8*)(As + row * LDA_1 + 528 + (c - 88) * 8) = z;
            }
        } else {
            int j = idx - 32 * 90;
            int row = j / 22, cc = j - row * 22;
            *(f16x8*)(CAT2 + (size_t)(R0 + row) * 352 + 176 + cc * 8) =
                *(const f16x8*)(FEAT + (size_t)s_src[row] * 176 + cc * 8);
        }
    }
    __syncthreads();
    const int w = t >> 6, l = t & 63;
    const int lane16 = l & 15, koff = (l >> 4) * 8;
    const int C0 = w * 32;
    const f16* Al0 = As + lane16 * LDA_1 + koff;
    const f16* Al1 = As + (16 + lane16) * LDA_1 + koff;
    const f16* Bp0 = W1 + (size_t)(C0 + lane16) * 544 + koff;
    const f16* Bp1 = Bp0 + (size_t)16 * 544;
    f32x4 acc00 = {}, acc01 = {}, acc10 = {}, acc11 = {};
    #pragma unroll 2
    for (int s = 0; s < 17; ++s) {
        f16x8 a0 = *(const f16x8*)(Al0 + s * 32);
        f16x8 a1 = *(const f16x8*)(Al1 + s * 32);
        f16x8 b0 = *(const f16x8*)(Bp0 + s * 32);
        f16x8 b1 = *(const f16x8*)(Bp1 + s * 32);
        acc00 = __builtin_amdgcn_mfma_f32_16x16x32_f16(a0, b0, acc00, 0, 0, 0);
        acc01 = __builtin_amdgcn_mfma_f32_16x16x32_f16(a0, b1, acc01, 0, 0, 0);
        acc10 = __builtin_amdgcn_mfma_f32_16x16x32_f16(a1, b0, acc10, 0, 0, 0);
        acc11 = __builtin_amdgcn_mfma_f32_16x16x32_f16(a1, b1, acc11, 0, 0, 0);
    }
    const int col0 = C0 + lane16, col1 = col0 + 16;
    const int rloc = (l >> 4) * 4;
    const float bb0 = (col0 < D) ? 10.0f * lin1_b[col0] : 0.f;
    const float bb1 = (col1 < D) ? 10.0f * lin1_b[col1] : 0.f;
    #pragma unroll
    for (int rh = 0; rh < 2; ++rh) {
        const f32x4& A0 = rh ? acc10 : acc00;
        const f32x4& A1 = rh ? acc11 : acc01;
        #pragma unroll
        for (int reg = 0; reg < 4; ++reg) {
            int r = R0 + rh * 16 + rloc + reg;
            if (col0 < 176)
                CAT2[(size_t)r * 352 + col0] = (col0 < D) ? (f16)fmaxf(A0[reg] + bb0, 0.f) : (f16)0.f;
            if (col1 < 176)
                CAT2[(size_t)r * 352 + col1] = (col1 < D) ? (f16)fmaxf(A1[reg] + bb1, 0.f) : (f16)0.f;
        }
    }
}

// ---------------- GEMM 3 + GEMM 4 + tail fused ----------------
#define LDE 200   // 192 + 8

__global__ __launch_bounds__(384) void gemm_lin2_mlp(
    const f16* __restrict__ CAT2, const f16* __restrict__ W2, const float* __restrict__ embc,
    const f16* __restrict__ Wm1, const float* __restrict__ b1,
    const float* __restrict__ w2, const float* __restrict__ b2,
    const float* __restrict__ w3, const float* __restrict__ b3, float* __restrict__ out)
{
    __shared__ f16 Emb[32 * LDE];
    __shared__ float sH[32][84];
    __shared__ float s_w2[10 * HIDD];
    __shared__ float s_b2[10], s_w3[10], s_b3;
    const int t = threadIdx.x;
    const int R0 = blockIdx.x * 32;
    for (int i = t; i < 10 * HIDD; i += 384) s_w2[i] = w2[i];
    if (t < 10) { s_b2[t] = b2[t]; s_w3[t] = w3[t]; }
    if (t == 10) s_b3 = b3[0];
    const int w = t >> 6, l = t & 63;
    const int lane16 = l & 15, koff = (l >> 4) * 8;
    const int rloc = (l >> 4) * 4;
    {   // lin2: 6 waves x 32 cols x 2 row-halves, A direct from global CAT2
        const int C0 = w * 32;
        const f16* Ap0 = CAT2 + (size_t)(R0 + lane16) * 352 + koff;
        const f16* Ap1 = CAT2 + (size_t)(R0 + 16 + lane16) * 352 + koff;
        const f16* Bp0 = W2 + (size_t)(C0 + lane16) * 352 + koff;
        const f16* Bp1 = Bp0 + (size_t)16 * 352;
        f32x4 acc00 = {}, acc01 = {}, acc10 = {}, acc11 = {};
        #pragma unroll 2
        for (int s = 0; s < 11; ++s) {
            f16x8 a0 = *(const f16x8*)(Ap0 + s * 32);
            f16x8 a1 = *(const f16x8*)(Ap1 + s * 32);
            f16x8 b0 = *(const f16x8*)(Bp0 + s * 32);
            f16x8 b1 = *(const f16x8*)(Bp1 + s * 32);
            acc00 = __builtin_amdgcn_mfma_f32_16x16x32_f16(a0, b0, acc00, 0, 0, 0);
            acc01 = __builtin_amdgcn_mfma_f32_16x16x32_f16(a0, b1, acc01, 0, 0, 0);
            acc10 = __builtin_amdgcn_mfma_f32_16x16x32_f16(a1, b0, acc10, 0, 0, 0);
            acc11 = __builtin_amdgcn_mfma_f32_16x16x32_f16(a1, b1, acc11, 0, 0, 0);
        }
        const int col0 = C0 + lane16, col1 = col0 + 16;
        const float ec0 = (col0 < D) ? embc[col0] : 0.f;
        const float ec1 = (col1 < D) ? embc[col1] : 0.f;
        #pragma unroll
        for (int rh = 0; rh < 2; ++rh) {
            const f32x4& A0 = rh ? acc10 : acc00;
            const f32x4& A1 = rh ? acc11 : acc01;
            #pragma unroll
            for (int reg = 0; reg < 4; ++reg) {
                int r = rh * 16 + rloc + reg;
                Emb[r * LDE + col0] = (col0 < D) ? (f16)(A0[reg] + ec0) : (f16)0.f;
                Emb[r * LDE + col1] = (col1 < D) ? (f16)(A1[reg] + ec1) : (f16)0.f;
            }
        }
    }
    __syncthreads();
    if (w < 5) {  // mlp1: wave w -> cols w*16..+16, two row-halves
        const int C0 = w * 16;
        const f16* Bp = Wm1 + (size_t)(C0 + lane16) * 192 + koff;
        #pragma unroll
        for (int rh = 0; rh < 2; ++rh) {
            const f16* Al = Emb + (rh * 16 + lane16) * LDE + koff;
            f32x4 acc = {};
            #pragma unroll
            for (int s = 0; s < 6; ++s) {
                f16x8 a = *(const f16x8*)(Al + s * 32);
                f16x8 b = *(const f16x8*)(Bp + s * 32);
                acc = __builtin_amdgcn_mfma_f32_16x16x32_f16(a, b, acc, 0, 0, 0);
            }
            const int col = C0 + lane16;
            #pragma unroll
            for (int reg = 0; reg < 4; ++reg)
                sH[rh * 16 + rloc + reg][col] = fmaxf(acc[reg] + b1[col], 0.f);
        }
    }
    __syncthreads();
    if (t < 32) {
        float h2[10];
        #pragma unroll
        for (int j = 0; j < 10; ++j) h2[j] = s_b2[j];
        for (int f = 0; f < HIDD; ++f) {
            float hv = sH[t][f];
            #pragma unroll
            for (int j = 0; j < 10; ++j) h2[j] = fmaf(hv, s_w2[j * HIDD + f], h2[j]);
        }
        float logit = s_b3;
        #pragma unroll
        for (int j = 0; j < 10; ++j) logit += fmaxf(h2[j], 0.f) * s_w3[j];
        out[R0 + t] = 1.f / (1.f + expf(-logit));
    }
}

// ---------------- host ----------------

extern "C" void kernel_launch(void* const* d_in, const int* in_sizes, int n_in,
                              void* d_out, int out_size, void* d_ws, size_t ws_size,
                              hipStream_t stream) {
    const float* timestamps     = (const float*)d_in[0];
    const float* edge_features  = (const float*)d_in[1];
    const float* tnf            = (const float*)d_in[2];
    const float* node_mem       = (const float*)d_in[3];
    const float* last_updated   = (const float*)d_in[4];
    const float* nbr_edge_times = (const float*)d_in[5];
    const float* time_w         = (const float*)d_in[6];
    const float* time_b         = (const float*)d_in[7];
    const float* Wih            = (const float*)d_in[8];
    const float* Whh            = (const float*)d_in[9];
    const float* bih            = (const float*)d_in[10];
    const float* bhh            = (const float*)d_in[11];
    const float* lin1_w         = (const float*)d_in[12];
    const float* lin1_b         = (const float*)d_in[13];
    const float* lin2_w         = (const float*)d_in[14];
    const float* lin2_b         = (const float*)d_in[15];
    const float* w1             = (const float*)d_in[16];
    const float* b1             = (const float*)d_in[17];
    const float* w2             = (const float*)d_in[18];
    const float* b2             = (const float*)d_in[19];
    const float* w3             = (const float*)d_in[20];
    const float* b3             = (const float*)d_in[21];
    const int* sources          = (const int*)d_in[22];
    const int* destinations     = (const int*)d_in[23];
    const int* edge_idxs        = (const int*)d_in[24];
    const int* neighbors        = (const int*)d_in[25];
    const int* nbr_edge_idxs    = (const int*)d_in[26];
    float* out = (float*)d_out;

    char* p = (char*)d_ws;
    auto bump = [&p](size_t bytes) { char* r = p; p += (bytes + 255) & ~(size_t)255; return r; };
    int* last_idx = (int*)bump(N_NODES * 4);
    int* nid      = (int*)bump(N_NODES * 4);
    int* li_arr   = (int*)bump(N_NODES * 4);
    int* cnt      = (int*)bump(256);
    f16* Wc16     = (f16*)bump((size_t)192 * 704 * 2);
    f16* W1_16    = (f16*)bump((size_t)192 * 544 * 2);
    f16* W2_16    = (f16*)bump((size_t)192 * 352 * 2);
    f16* Wm1_16   = (f16*)bump((size_t)80 * 192 * 2);
    float* bcomb  = (float*)bump(D * 4);
    float* embc   = (float*)bump(D * 4);
    f16* FEAT16   = (f16*)bump((size_t)N_NODES * 176 * 2);
    f16* CAT2_16  = (f16*)bump((size_t)BB * 352 * 2);

    hipMemsetAsync(last_idx, 0xFF, (size_t)N_NODES * 4, stream);
    hipMemsetAsync(cnt, 0, 4, stream);
    hipLaunchKernelGGL(scatter_last, dim3(BB / 256), dim3(256), 0, stream, sources, last_idx);
    hipLaunchKernelGGL(compact_nodes, dim3((N_NODES + 255) / 256), dim3(256), 0, stream,
                       last_idx, nid, li_arr, cnt);

    hipLaunchKernelGGL(conv_weights, dim3(860, 6), dim3(256), 0, stream,
                       Wih, Whh, lin1_w, lin2_w, w1, bih, bhh, lin2_b, time_b,
                       node_mem, tnf, Wc16, W1_16, W2_16, Wm1_16, bcomb, embc, FEAT16);

    hipLaunchKernelGGL(gemm_rnn_fused, dim3((N_NODES + 31) / 32), dim3(384), 0, stream,
                       Wc16, bcomb, nid, li_arr, cnt, destinations, edge_idxs,
                       timestamps, last_updated, node_mem, edge_features,
                       time_w, time_b, tnf, FEAT16);

    hipLaunchKernelGGL(gemm_lin1_fused, dim3(BB / 32), dim3(384), 0, stream,
                       W1_16, lin1_b, FEAT16, edge_features, timestamps, nbr_edge_times,
                       neighbors, nbr_edge_idxs, sources, time_w, time_b, CAT2_16);

    hipLaunchKernelGGL(gemm_lin2_mlp, dim3(BB / 32), dim3(384), 0, stream,
                       CAT2_16, W2_16, embc, Wm1_16, b1, w2, b2, w3, b3, out);
}

// Round 10
// 103.134 us; speedup vs baseline: 18.2205x; 1.1527x over previous
//
#include <hip/hip_runtime.h>
#include <math.h>

#define N_NODES 10000
#define BB 8192
#define KK 10
#define D 172
#define HIDD 80

typedef _Float16 f16;
typedef f16 f16x8 __attribute__((ext_vector_type(8)));
typedef f16 f16x4 __attribute__((ext_vector_type(4)));
typedef float f32x4 __attribute__((ext_vector_type(4)));

// ---------------- index prep ----------------

__global__ void scatter_last(const int* __restrict__ sources, int* __restrict__ last_idx) {
    int b = blockIdx.x * blockDim.x + threadIdx.x;
    if (b < BB) atomicMax(&last_idx[sources[b]], b);
}

__global__ void compact_nodes(const int* __restrict__ last_idx, int* __restrict__ nid,
                              int* __restrict__ li_arr, int* __restrict__ cnt) {
    int n = blockIdx.x * blockDim.x + threadIdx.x;
    if (n < N_NODES) {
        int li = last_idx[n];
        if (li >= 0) { int p = atomicAdd(cnt, 1); nid[p] = n; li_arr[p] = li; }
    }
}

// ---------------- weight conversion (192-row padded) + FEAT copy, 6 planes ----------------
__global__ __launch_bounds__(256) void conv_weights(
    const float* __restrict__ Wih, const float* __restrict__ Whh,
    const float* __restrict__ lin1_w, const float* __restrict__ lin2_w,
    const float* __restrict__ w1,
    const float* __restrict__ bih, const float* __restrict__ bhh,
    const float* __restrict__ lin2_b, const float* __restrict__ tb,
    const float* __restrict__ node_mem, const float* __restrict__ tnf,
    f16* __restrict__ Wc, f16* __restrict__ W1, f16* __restrict__ W2,
    f16* __restrict__ Wm1, float* __restrict__ bcomb, float* __restrict__ embc,
    f16* __restrict__ FEAT)
{
    const int which = blockIdx.y;
    const int idx = blockIdx.x * 256 + threadIdx.x;
    if (which == 0) {
        if (idx >= 192 * 704) return;
        int n = idx / 704, k = idx % 704, seg = k / 176, kk = k % 176;
        float v = 0.f;
        if (n < D && kk < D) {
            v = Wih[n * 688 + seg * D + kk];
            if (seg == 0) v += Whh[n * D + kk];
        }
        Wc[idx] = (f16)v;
    } else if (which == 1) {
        if (idx >= 192 * 544) return;
        int n = idx / 544, k = idx % 544, seg = k / 176, kk = k % 176;
        float v = 0.f;
        if (n < D && seg < 3 && kk < D) v = lin1_w[n * 516 + seg * D + kk];
        W1[idx] = (f16)v;
    } else if (which == 2) {
        if (idx >= 192 * 352) return;
        int n = idx / 352, k = idx % 352, seg = k / 176, kk = k % 176;
        float v = 0.f;
        if (n < D && kk < D) v = lin2_w[n * 516 + seg * D + kk];
        W2[idx] = (f16)v;
    } else if (which == 3) {
        if (idx >= 80 * 192) return;
        int n = idx / 192, k = idx % 192;
        Wm1[idx] = (f16)((k < D) ? w1[n * D + k] : 0.f);
    } else if (which == 4) {
        if (idx < D) {
            bcomb[idx] = bih[idx] + bhh[idx];
            float acc = lin2_b[idx];
            for (int j = 0; j < D; ++j) acc += lin2_w[idx * 516 + 344 + j] * __cosf(tb[j]);
            embc[idx] = acc;
        }
    } else {
        if (idx >= N_NODES * 22) return;
        int n = idx / 22, k0 = (idx % 22) * 8;
        f16x8 o;
        #pragma unroll
        for (int j = 0; j < 8; ++j) {
            int kk = k0 + j;
            float v = (kk < D) ? node_mem[(size_t)n * D + kk] + tnf[(size_t)n * D + kk] : 0.f;
            o[j] = (f16)v;
        }
        *(f16x8*)(FEAT + (size_t)n * 176 + k0) = o;
    }
}

// ---------------- GEMM 1 fused: stage MSG rows in LDS, MFMA (12 waves x 16 cols x 2 rh) ----------------
#define LDA_R 712   // 704 + 8 pad halfs

__global__ __launch_bounds__(768) void gemm_rnn_fused(
    const f16* __restrict__ Wc, const float* __restrict__ bcomb,
    const int* __restrict__ nid, const int* __restrict__ li_arr, const int* __restrict__ cnt,
    const int* __restrict__ destinations, const int* __restrict__ edge_idxs,
    const float* __restrict__ timestamps, const float* __restrict__ last_updated,
    const float* __restrict__ node_mem, const float* __restrict__ edge_features,
    const float* __restrict__ tw, const float* __restrict__ tb,
    const float* __restrict__ tnf, f16* __restrict__ FEAT)
{
    const int c = *cnt;
    const int R0 = blockIdx.x * 32;
    if (R0 >= c) return;
    __shared__ f16 As[32 * LDA_R];
    __shared__ int s_n[32], s_dst[32], s_ei[32];
    __shared__ float s_dt[32];
    const int t = threadIdx.x;
    if (t < 32) {
        int i = R0 + t; if (i > c - 1) i = c - 1;
        int n = nid[i], li = li_arr[i];
        s_n[t] = n; s_dst[t] = destinations[li]; s_ei[t] = edge_idxs[li];
        s_dt[t] = timestamps[li] - last_updated[n];
    }
    __syncthreads();
    for (int idx = t; idx < 32 * 88; idx += 768) {
        int row = idx / 88, sub = idx - row * 88;
        int seg = sub / 22, cpos = sub - seg * 22, k0 = cpos * 8;
        f16x8 o;
        if (seg < 3) {
            int n = (seg == 0) ? s_n[row] : (seg == 1) ? s_dst[row] : s_ei[row];
            const float* src = ((seg < 2) ? node_mem : edge_features) + (size_t)n * D + k0;
            float4 lo = *(const float4*)src;
            float4 hi = (cpos < 21) ? *(const float4*)(src + 4) : make_float4(0.f, 0.f, 0.f, 0.f);
            o[0] = (f16)lo.x; o[1] = (f16)lo.y; o[2] = (f16)lo.z; o[3] = (f16)lo.w;
            o[4] = (f16)hi.x; o[5] = (f16)hi.y; o[6] = (f16)hi.z; o[7] = (f16)hi.w;
        } else {
            float dt = s_dt[row];
            #pragma unroll
            for (int j = 0; j < 8; ++j) {
                int kk = k0 + j;
                o[j] = (f16)((kk < D) ? __cosf(dt * tw[kk] + tb[kk]) : 0.f);
            }
        }
        *(f16x8*)(As + row * LDA_R + seg * 176 + k0) = o;
    }
    __syncthreads();
    const int w = t >> 6, l = t & 63;
    const int lane16 = l & 15, koff = (l >> 4) * 8;
    const int C0 = w * 16;
    const f16* Al0 = As + lane16 * LDA_R + koff;
    const f16* Al1 = As + (16 + lane16) * LDA_R + koff;
    const f16* Bp  = Wc + (size_t)(C0 + lane16) * 704 + koff;
    f32x4 acc0 = {}, acc1 = {};
    #pragma unroll 2
    for (int s = 0; s < 22; ++s) {
        f16x8 a0 = *(const f16x8*)(Al0 + s * 32);
        f16x8 a1 = *(const f16x8*)(Al1 + s * 32);
        f16x8 b  = *(const f16x8*)(Bp + s * 32);
        acc0 = __builtin_amdgcn_mfma_f32_16x16x32_f16(a0, b, acc0, 0, 0, 0);
        acc1 = __builtin_amdgcn_mfma_f32_16x16x32_f16(a1, b, acc1, 0, 0, 0);
    }
    const int col = C0 + lane16;
    const int rloc = (l >> 4) * 4;
    const float bc = (col < D) ? bcomb[col] : 0.f;
    if (col < D) {
        #pragma unroll
        for (int rh = 0; rh < 2; ++rh) {
            const f32x4& A = rh ? acc1 : acc0;
            #pragma unroll
            for (int reg = 0; reg < 4; ++reg) {
                int rl = rh * 16 + rloc + reg;
                int r = R0 + rl;
                if (r >= c) continue;
                int n = s_n[rl];
                FEAT[(size_t)n * 176 + col] = (f16)(tanhf(A[reg] + bc) + tnf[(size_t)n * D + col]);
            }
        }
    }
}

// ---------------- GEMM 2 fused: stage G rows in LDS (gathers), MFMA (12 waves), write CAT2 ----------------
#define LDA_1 552   // 544 + 8

__global__ __launch_bounds__(768) void gemm_lin1_fused(
    const f16* __restrict__ W1, const float* __restrict__ lin1_b,
    const f16* __restrict__ FEAT, const float* __restrict__ edge_features,
    const float* __restrict__ timestamps, const float* __restrict__ nbr_edge_times,
    const int* __restrict__ neighbors, const int* __restrict__ nbr_edge_idxs,
    const int* __restrict__ sources,
    const float* __restrict__ tw, const float* __restrict__ tb,
    f16* __restrict__ CAT2)
{
    __shared__ f16 As[32 * LDA_1];
    __shared__ int s_nbr[320], s_nei[320], s_src[32];
    __shared__ float s_net[320], s_ts[32];
    const int t = threadIdx.x;
    const int R0 = blockIdx.x * 32;
    if (t < 320) {
        s_nbr[t] = neighbors[R0 * KK + t];
        s_nei[t] = nbr_edge_idxs[R0 * KK + t];
        s_net[t] = nbr_edge_times[R0 * KK + t];
    } else if (t < 352) {
        s_ts[t - 320] = timestamps[R0 + t - 320];
    } else if (t < 384) {
        s_src[t - 352] = sources[R0 + t - 352];
    }
    __syncthreads();
    for (int idx = t; idx < 32 * 90 + 32 * 22; idx += 768) {
        if (idx < 32 * 90) {
            int row = idx / 90, c = idx - row * 90;
            if (c < 22) {
                int k0 = c * 8;
                f16x8 v[KK];
                #pragma unroll
                for (int k = 0; k < KK; ++k)
                    v[k] = *(const f16x8*)(FEAT + (size_t)s_nbr[row * KK + k] * 176 + k0);
                float a[8] = {};
                #pragma unroll
                for (int k = 0; k < KK; ++k) {
                    #pragma unroll
                    for (int j = 0; j < 8; ++j) a[j] += (float)v[k][j];
                }
                f16x8 o;
                #pragma unroll
                for (int j = 0; j < 8; ++j) o[j] = (f16)a[j];
                *(f16x8*)(As + row * LDA_1 + k0) = o;
            } else if (c < 44) {
                int k0 = (c - 22) * 8;
                float ts = s_ts[row];
                f16x8 o;
                #pragma unroll
                for (int j = 0; j < 8; ++j) {
                    int kk = k0 + j;
                    float a = 0.f;
                    if (kk < D) {
                        float w = tw[kk], bb = tb[kk];
                        #pragma unroll
                        for (int k = 0; k < KK; ++k) a += __cosf((ts - s_net[row * KK + k]) * w + bb);
                    }
                    o[j] = (f16)a;
                }
                *(f16x8*)(As + row * LDA_1 + 176 + k0) = o;
            } else if (c < 88) {
                int cc = c - 44;
                f16x4 o;
                if (cc == 43) {
                    o[0] = o[1] = o[2] = o[3] = (f16)0.f;
                } else {
                    float4 e[KK];
                    #pragma unroll
                    for (int k = 0; k < KK; ++k)
                        e[k] = *(const float4*)(edge_features + (size_t)s_nei[row * KK + k] * D + cc * 4);
                    float a0 = 0.f, a1 = 0.f, a2 = 0.f, a3 = 0.f;
                    #pragma unroll
                    for (int k = 0; k < KK; ++k) { a0 += e[k].x; a1 += e[k].y; a2 += e[k].z; a3 += e[k].w; }
                    o[0] = (f16)a0; o[1] = (f16)a1; o[2] = (f16)a2; o[3] = (f16)a3;
                }
                *(f16x4*)(As + row * LDA_1 + 352 + cc * 4) = o;
            } else {
                f16x8 z = {};
                *(f16x8*)(As + row * LDA_1 + 528 + (c - 88) * 8) = z;
            }
        } else {
            int j = idx - 32 * 90;
            int row = j / 22, cc = j - row * 22;
            *(f16x8*)(CAT2 + (size_t)(R0 + row) * 352 + 176 + cc * 8) =
                *(const f16x8*)(FEAT + (size_t)s_src[row] * 176 + cc * 8);
        }
    }
    __syncthreads();
    const int w = t >> 6, l = t & 63;
    const int lane16 = l & 15, koff = (l >> 4) * 8;
    const int C0 = w * 16;
    const f16* Al0 = As + lane16 * LDA_1 + koff;
    const f16* Al1 = As + (16 + lane16) * LDA_1 + koff;
    const f16* Bp  = W1 + (size_t)(C0 + lane16) * 544 + koff;
    f32x4 acc0 = {}, acc1 = {};
    #pragma unroll 2
    for (int s = 0; s < 17; ++s) {
        f16x8 a0 = *(const f16x8*)(Al0 + s * 32);
        f16x8 a1 = *(const f16x8*)(Al1 + s * 32);
        f16x8 b  = *(const f16x8*)(Bp + s * 32);
        acc0 = __builtin_amdgcn_mfma_f32_16x16x32_f16(a0, b, acc0, 0, 0, 0);
        acc1 = __builtin_amdgcn_mfma_f32_16x16x32_f16(a1, b, acc1, 0, 0, 0);
    }
    const int col = C0 + lane16;
    const int rloc = (l >> 4) * 4;
    const float bb = (col < D) ? 10.0f * lin1_b[col] : 0.f;
    #pragma unroll
    for (int rh = 0; rh < 2; ++rh) {
        const f32x4& A = rh ? acc1 : acc0;
        #pragma unroll
        for (int reg = 0; reg < 4; ++reg) {
            int r = R0 + rh * 16 + rloc + reg;
            CAT2[(size_t)r * 352 + col] = (col < D) ? (f16)fmaxf(A[reg] + bb, 0.f) : (f16)0.f;
        }
    }
}

// ---------------- GEMM 3 + GEMM 4 + tail fused (12 waves) ----------------
#define LDE 200   // 192 + 8

__global__ __launch_bounds__(768) void gemm_lin2_mlp(
    const f16* __restrict__ CAT2, const f16* __restrict__ W2, const float* __restrict__ embc,
    const f16* __restrict__ Wm1, const float* __restrict__ b1,
    const float* __restrict__ w2, const float* __restrict__ b2,
    const float* __restrict__ w3, const float* __restrict__ b3, float* __restrict__ out)
{
    __shared__ f16 Emb[32 * LDE];
    __shared__ float sH[32][84];
    __shared__ float s_w2[10 * HIDD];
    __shared__ float s_b2[10], s_w3[10], s_b3;
    const int t = threadIdx.x;
    const int R0 = blockIdx.x * 32;
    for (int i = t; i < 10 * HIDD; i += 768) s_w2[i] = w2[i];
    if (t < 10) { s_b2[t] = b2[t]; s_w3[t] = w3[t]; }
    if (t == 10) s_b3 = b3[0];
    const int w = t >> 6, l = t & 63;
    const int lane16 = l & 15, koff = (l >> 4) * 8;
    const int rloc = (l >> 4) * 4;
    {   // lin2: 12 waves x 16 cols x 2 row-halves, A direct from global CAT2
        const int C0 = w * 16;
        const f16* Ap0 = CAT2 + (size_t)(R0 + lane16) * 352 + koff;
        const f16* Ap1 = CAT2 + (size_t)(R0 + 16 + lane16) * 352 + koff;
        const f16* Bp  = W2 + (size_t)(C0 + lane16) * 352 + koff;
        f32x4 acc0 = {}, acc1 = {};
        #pragma unroll 2
        for (int s = 0; s < 11; ++s) {
            f16x8 a0 = *(const f16x8*)(Ap0 + s * 32);
            f16x8 a1 = *(const f16x8*)(Ap1 + s * 32);
            f16x8 b  = *(const f16x8*)(Bp + s * 32);
            acc0 = __builtin_amdgcn_mfma_f32_16x16x32_f16(a0, b, acc0, 0, 0, 0);
            acc1 = __builtin_amdgcn_mfma_f32_16x16x32_f16(a1, b, acc1, 0, 0, 0);
        }
        const int col = C0 + lane16;
        const float ec = (col < D) ? embc[col] : 0.f;
        #pragma unroll
        for (int rh = 0; rh < 2; ++rh) {
            const f32x4& A = rh ? acc1 : acc0;
            #pragma unroll
            for (int reg = 0; reg < 4; ++reg) {
                int r = rh * 16 + rloc + reg;
                Emb[r * LDE + col] = (col < D) ? (f16)(A[reg] + ec) : (f16)0.f;
            }
        }
    }
    __syncthreads();
    if (w < 10) {  // mlp1: wave w -> col-tile (w>>1), row-half (w&1)
        const int C0 = (w >> 1) * 16;
        const int rh = w & 1;
        const f16* Bp = Wm1 + (size_t)(C0 + lane16) * 192 + koff;
        const f16* Al = Emb + (rh * 16 + lane16) * LDE + koff;
        f32x4 acc = {};
        #pragma unroll
        for (int s = 0; s < 6; ++s) {
            f16x8 a = *(const f16x8*)(Al + s * 32);
            f16x8 b = *(const f16x8*)(Bp + s * 32);
            acc = __builtin_amdgcn_mfma_f32_16x16x32_f16(a, b, acc, 0, 0, 0);
        }
        const int col = C0 + lane16;
        #pragma unroll
        for (int reg = 0; reg < 4; ++reg)
            sH[rh * 16 + rloc + reg][col] = fmaxf(acc[reg] + b1[col], 0.f);
    }
    __syncthreads();
    if (t < 32) {
        float h2[10];
        #pragma unroll
        for (int j = 0; j < 10; ++j) h2[j] = s_b2[j];
        for (int f = 0; f < HIDD; ++f) {
            float hv = sH[t][f];
            #pragma unroll
            for (int j = 0; j < 10; ++j) h2[j] = fmaf(hv, s_w2[j * HIDD + f], h2[j]);
        }
        float logit = s_b3;
        #pragma unroll
        for (int j = 0; j < 10; ++j) logit += fmaxf(h2[j], 0.f) * s_w3[j];
        out[R0 + t] = 1.f / (1.f + expf(-logit));
    }
}

// ---------------- host ----------------

extern "C" void kernel_launch(void* const* d_in, const int* in_sizes, int n_in,
                              void* d_out, int out_size, void* d_ws, size_t ws_size,
                              hipStream_t stream) {
    const float* timestamps     = (const float*)d_in[0];
    const float* edge_features  = (const float*)d_in[1];
    const float* tnf            = (const float*)d_in[2];
    const float* node_mem       = (const float*)d_in[3];
    const float* last_updated   = (const float*)d_in[4];
    const float* nbr_edge_times = (const float*)d_in[5];
    const float* time_w         = (const float*)d_in[6];
    const float* time_b         = (const float*)d_in[7];
    const float* Wih            = (const float*)d_in[8];
    const float* Whh            = (const float*)d_in[9];
    const float* bih            = (const float*)d_in[10];
    const float* bhh            = (const float*)d_in[11];
    const float* lin1_w         = (const float*)d_in[12];
    const float* lin1_b         = (const float*)d_in[13];
    const float* lin2_w         = (const float*)d_in[14];
    const float* lin2_b         = (const float*)d_in[15];
    const float* w1             = (const float*)d_in[16];
    const float* b1             = (const float*)d_in[17];
    const float* w2             = (const float*)d_in[18];
    const float* b2             = (const float*)d_in[19];
    const float* w3             = (const float*)d_in[20];
    const float* b3             = (const float*)d_in[21];
    const int* sources          = (const int*)d_in[22];
    const int* destinations     = (const int*)d_in[23];
    const int* edge_idxs        = (const int*)d_in[24];
    const int* neighbors        = (const int*)d_in[25];
    const int* nbr_edge_idxs    = (const int*)d_in[26];
    float* out = (float*)d_out;

    char* p = (char*)d_ws;
    auto bump = [&p](size_t bytes) { char* r = p; p += (bytes + 255) & ~(size_t)255; return r; };
    int* last_idx = (int*)bump(N_NODES * 4);
    int* nid      = (int*)bump(N_NODES * 4);
    int* li_arr   = (int*)bump(N_NODES * 4);
    int* cnt      = (int*)bump(256);
    f16* Wc16     = (f16*)bump((size_t)192 * 704 * 2);
    f16* W1_16    = (f16*)bump((size_t)192 * 544 * 2);
    f16* W2_16    = (f16*)bump((size_t)192 * 352 * 2);
    f16* Wm1_16   = (f16*)bump((size_t)80 * 192 * 2);
    float* bcomb  = (float*)bump(D * 4);
    float* embc   = (float*)bump(D * 4);
    f16* FEAT16   = (f16*)bump((size_t)N_NODES * 176 * 2);
    f16* CAT2_16  = (f16*)bump((size_t)BB * 352 * 2);

    hipMemsetAsync(last_idx, 0xFF, (size_t)N_NODES * 4, stream);
    hipMemsetAsync(cnt, 0, 4, stream);
    hipLaunchKernelGGL(scatter_last, dim3(BB / 256), dim3(256), 0, stream, sources, last_idx);
    hipLaunchKernelGGL(compact_nodes, dim3((N_NODES + 255) / 256), dim3(256), 0, stream,
                       last_idx, nid, li_arr, cnt);

    hipLaunchKernelGGL(conv_weights, dim3(860, 6), dim3(256), 0, stream,
                       Wih, Whh, lin1_w, lin2_w, w1, bih, bhh, lin2_b, time_b,
                       node_mem, tnf, Wc16, W1_16, W2_16, Wm1_16, bcomb, embc, FEAT16);

    hipLaunchKernelGGL(gemm_rnn_fused, dim3((N_NODES + 31) / 32), dim3(768), 0, stream,
                       Wc16, bcomb, nid, li_arr, cnt, destinations, edge_idxs,
                       timestamps, last_updated, node_mem, edge_features,
                       time_w, time_b, tnf, FEAT16);

    hipLaunchKernelGGL(gemm_lin1_fused, dim3(BB / 32), dim3(768), 0, stream,
                       W1_16, lin1_b, FEAT16, edge_features, timestamps, nbr_edge_times,
                       neighbors, nbr_edge_idxs, sources, time_w, time_b, CAT2_16);

    hipLaunchKernelGGL(gemm_lin2_mlp, dim3(BB / 32), dim3(768), 0, stream,
                       CAT2_16, W2_16, embc, Wm1_16, b1, w2, b2, w3, b3, out);
}

// Round 12
// 90.622 us; speedup vs baseline: 20.7363x; 1.1381x over previous
//
#include <hip/hip_runtime.h>
#include <math.h>

#define N_NODES 10000
#define BB 8192
#define KK 10
#define D 172
#define HIDD 80

typedef _Float16 f16;
typedef f16 f16x8 __attribute__((ext_vector_type(8)));
typedef f16 f16x4 __attribute__((ext_vector_type(4)));
typedef float f32x4 __attribute__((ext_vector_type(4)));

// ---------------- index prep ----------------

__global__ void scatter_last(const int* __restrict__ sources, int* __restrict__ last_idx) {
    int b = blockIdx.x * blockDim.x + threadIdx.x;
    if (b < BB) atomicMax(&last_idx[sources[b]], b);
}

__global__ void compact_nodes(const int* __restrict__ last_idx, int* __restrict__ nid,
                              int* __restrict__ li_arr, int* __restrict__ cnt) {
    int n = blockIdx.x * blockDim.x + threadIdx.x;
    if (n < N_NODES) {
        int li = last_idx[n];
        if (li >= 0) { int p = atomicAdd(cnt, 1); nid[p] = n; li_arr[p] = li; }
    }
}

// ---------------- conv_weights: flat 1D, 7 ranges (weights, consts, FEAT, init) ----------------
#define CR0 135168              // Wc 192*704
#define CR1 (CR0 + 104448)      // W1 192*544
#define CR2 (CR1 + 67584)      // W2 192*352
#define CR3 (CR2 + 15360)       // Wm1 80*192
#define CR4 (CR3 + 192)         // bcomb/embc
#define CR5 (CR4 + 220000)      // FEAT 10000*22
#define CR6 (CR5 + 10001)       // last_idx init + cnt

__global__ __launch_bounds__(256) void conv_weights(
    const float* __restrict__ Wih, const float* __restrict__ Whh,
    const float* __restrict__ lin1_w, const float* __restrict__ lin2_w,
    const float* __restrict__ w1,
    const float* __restrict__ bih, const float* __restrict__ bhh,
    const float* __restrict__ lin2_b, const float* __restrict__ tb,
    const float* __restrict__ node_mem, const float* __restrict__ tnf,
    f16* __restrict__ Wc, f16* __restrict__ W1, f16* __restrict__ W2,
    f16* __restrict__ Wm1, float* __restrict__ bcomb, float* __restrict__ embc,
    f16* __restrict__ FEAT, int* __restrict__ last_idx, int* __restrict__ cnt)
{
    const int idx = blockIdx.x * 256 + threadIdx.x;
    if (idx < CR0) {
        int n = idx / 704, k = idx % 704, seg = k / 176, kk = k % 176;
        float v = 0.f;
        if (n < D && kk < D) {
            v = Wih[n * 688 + seg * D + kk];
            if (seg == 0) v += Whh[n * D + kk];
        }
        Wc[idx] = (f16)v;
    } else if (idx < CR1) {
        int i = idx - CR0;
        int n = i / 544, k = i % 544, seg = k / 176, kk = k % 176;
        float v = 0.f;
        if (n < D && seg < 3 && kk < D) v = lin1_w[n * 516 + seg * D + kk];
        W1[i] = (f16)v;
    } else if (idx < CR2) {
        int i = idx - CR1;
        int n = i / 352, k = i % 352, seg = k / 176, kk = k % 176;
        float v = 0.f;
        if (n < D && kk < D) v = lin2_w[n * 516 + seg * D + kk];
        W2[i] = (f16)v;
    } else if (idx < CR3) {
        int i = idx - CR2;
        int n = i / 192, k = i % 192;
        Wm1[i] = (f16)((k < D) ? w1[n * D + k] : 0.f);
    } else if (idx < CR4) {
        int i = idx - CR3;
        if (i < D) {
            bcomb[i] = bih[i] + bhh[i];
            float acc = lin2_b[i];
            for (int j = 0; j < D; ++j) acc += lin2_w[i * 516 + 344 + j] * __cosf(tb[j]);
            embc[i] = acc;
        }
    } else if (idx < CR5) {
        int i = idx - CR4;
        int n = i / 22, k0 = (i % 22) * 8;
        f16x8 o;
        #pragma unroll
        for (int j = 0; j < 8; ++j) {
            int kk = k0 + j;
            float v = (kk < D) ? node_mem[(size_t)n * D + kk] + tnf[(size_t)n * D + kk] : 0.f;
            o[j] = (f16)v;
        }
        *(f16x8*)(FEAT + (size_t)n * 176 + k0) = o;
    } else if (idx < CR6) {
        int i = idx - CR5;
        if (i < N_NODES) last_idx[i] = -1;
        else *cnt = 0;
    }
}

// ---------------- GEMM 1 fused: BM=16 rows, 768 thr (11 MFMA waves x 16 cols) ----------------
#define LDA_R 712   // 704 + 8 pad halfs

__global__ __launch_bounds__(768) void gemm_rnn_fused(
    const f16* __restrict__ Wc, const float* __restrict__ bcomb,
    const int* __restrict__ nid, const int* __restrict__ li_arr, const int* __restrict__ cnt,
    const int* __restrict__ destinations, const int* __restrict__ edge_idxs,
    const float* __restrict__ timestamps, const float* __restrict__ last_updated,
    const float* __restrict__ node_mem, const float* __restrict__ edge_features,
    const float* __restrict__ tw, const float* __restrict__ tb,
    const float* __restrict__ tnf, f16* __restrict__ FEAT)
{
    const int c = *cnt;
    const int R0 = blockIdx.x * 16;
    if (R0 >= c) return;
    __shared__ f16 As[16 * LDA_R];
    __shared__ int s_n[16], s_dst[16], s_ei[16];
    __shared__ float s_dt[16];
    const int t = threadIdx.x;
    if (t < 16) {
        int i = R0 + t; if (i > c - 1) i = c - 1;
        int n = nid[i], li = li_arr[i];
        s_n[t] = n; s_dst[t] = destinations[li]; s_ei[t] = edge_idxs[li];
        s_dt[t] = timestamps[li] - last_updated[n];
    }
    __syncthreads();
    for (int idx = t; idx < 16 * 88; idx += 768) {
        int row = idx / 88, sub = idx - row * 88;
        int seg = sub / 22, cpos = sub - seg * 22, k0 = cpos * 8;
        f16x8 o;
        if (seg < 3) {
            int n = (seg == 0) ? s_n[row] : (seg == 1) ? s_dst[row] : s_ei[row];
            const float* src = ((seg < 2) ? node_mem : edge_features) + (size_t)n * D + k0;
            float4 lo = *(const float4*)src;
            float4 hi = (cpos < 21) ? *(const float4*)(src + 4) : make_float4(0.f, 0.f, 0.f, 0.f);
            o[0] = (f16)lo.x; o[1] = (f16)lo.y; o[2] = (f16)lo.z; o[3] = (f16)lo.w;
            o[4] = (f16)hi.x; o[5] = (f16)hi.y; o[6] = (f16)hi.z; o[7] = (f16)hi.w;
        } else {
            float dt = s_dt[row];
            #pragma unroll
            for (int j = 0; j < 8; ++j) {
                int kk = k0 + j;
                o[j] = (f16)((kk < D) ? __cosf(dt * tw[kk] + tb[kk]) : 0.f);
            }
        }
        *(f16x8*)(As + row * LDA_R + seg * 176 + k0) = o;
    }
    __syncthreads();
    const int w = t >> 6, l = t & 63;
    if (w >= 11) return;
    const int lane16 = l & 15, koff = (l >> 4) * 8;
    const int C0 = w * 16;
    const f16* Al = As + lane16 * LDA_R + koff;
    const f16* Bp = Wc + (size_t)(C0 + lane16) * 704 + koff;
    f32x4 acc = {};
    #pragma unroll 2
    for (int s = 0; s < 22; ++s) {
        f16x8 a = *(const f16x8*)(Al + s * 32);
        f16x8 b = *(const f16x8*)(Bp + s * 32);
        acc = __builtin_amdgcn_mfma_f32_16x16x32_f16(a, b, acc, 0, 0, 0);
    }
    const int col = C0 + lane16;
    const int rloc = (l >> 4) * 4;
    if (col < D) {
        const float bc = bcomb[col];
        #pragma unroll
        for (int reg = 0; reg < 4; ++reg) {
            int rl = rloc + reg;
            int r = R0 + rl;
            if (r >= c) continue;
            int n = s_n[rl];
            FEAT[(size_t)n * 176 + col] = (f16)(tanhf(acc[reg] + bc) + tnf[(size_t)n * D + col]);
        }
    }
}

// ---------------- embed_fused: stage G + srcfeat -> lin1 -> lin2 -> mlp -> out ----------------
#define LDA_1 552   // G leading dim: 544 + 8
#define LDA_2 360   // Acat leading dim: 352 + 8
#define LDE  200    // Emb leading dim: 192 + 8

__global__ __launch_bounds__(768) void embed_fused(
    const f16* __restrict__ W1, const float* __restrict__ lin1_b,
    const f16* __restrict__ W2, const float* __restrict__ embc,
    const f16* __restrict__ Wm1, const float* __restrict__ b1,
    const float* __restrict__ w2, const float* __restrict__ b2,
    const float* __restrict__ w3, const float* __restrict__ b3,
    const f16* __restrict__ FEAT, const float* __restrict__ edge_features,
    const float* __restrict__ timestamps, const float* __restrict__ nbr_edge_times,
    const int* __restrict__ neighbors, const int* __restrict__ nbr_edge_idxs,
    const int* __restrict__ sources,
    const float* __restrict__ tw, const float* __restrict__ tb,
    float* __restrict__ out)
{
    __shared__ f16 As[32 * LDA_1];      // G staging; reused as Emb after lin1/lin2
    __shared__ f16 Acat[32 * LDA_2];    // [H1(0:176) | srcfeat(176:352)]
    __shared__ float sH[32][84];
    __shared__ float s_w2[10 * HIDD];
    __shared__ float s_b2[10], s_w3[10], s_b3;
    __shared__ int s_nbr[320], s_nei[320], s_src[32];
    __shared__ float s_net[320], s_ts[32];
    const int t = threadIdx.x;
    const int R0 = blockIdx.x * 32;
    for (int i = t; i < 10 * HIDD; i += 768) s_w2[i] = w2[i];
    if (t < 10) { s_b2[t] = b2[t]; s_w3[t] = w3[t]; }
    if (t == 10) s_b3 = b3[0];
    if (t >= 64 && t < 384) {
        int u = t - 64;
        s_nbr[u] = neighbors[R0 * KK + u];
    } else if (t >= 384 && t < 704) {
        int u = t - 384;
        s_nei[u] = nbr_edge_idxs[R0 * KK + u];
        s_net[u] = nbr_edge_times[R0 * KK + u];
    } else if (t >= 704 && t < 736) {
        s_ts[t - 704] = timestamps[R0 + t - 704];
    } else if (t >= 736) {
        s_src[t - 736] = sources[R0 + t - 736];
    }
    __syncthreads();
    // stage: G rows (90 chunks) + srcfeat (22 chunks) per row
    for (int idx = t; idx < 32 * 90 + 32 * 22; idx += 768) {
        if (idx < 32 * 90) {
            int row = idx / 90, c = idx - row * 90;
            if (c < 22) {
                int k0 = c * 8;
                f16x8 v[KK];
                #pragma unroll
                for (int k = 0; k < KK; ++k)
                    v[k] = *(const f16x8*)(FEAT + (size_t)s_nbr[row * KK + k] * 176 + k0);
                float a[8] = {};
                #pragma unroll
                for (int k = 0; k < KK; ++k) {
                    #pragma unroll
                    for (int j = 0; j < 8; ++j) a[j] += (float)v[k][j];
                }
                f16x8 o;
                #pragma unroll
                for (int j = 0; j < 8; ++j) o[j] = (f16)a[j];
                *(f16x8*)(As + row * LDA_1 + k0) = o;
            } else if (c < 44) {
                int k0 = (c - 22) * 8;
                float ts = s_ts[row];
                f16x8 o;
                #pragma unroll
                for (int j = 0; j < 8; ++j) {
                    int kk = k0 + j;
                    float a = 0.f;
                    if (kk < D) {
                        float w = tw[kk], bb = tb[kk];
                        #pragma unroll
                        for (int k = 0; k < KK; ++k) a += __cosf((ts - s_net[row * KK + k]) * w + bb);
                    }
                    o[j] = (f16)a;
                }
                *(f16x8*)(As + row * LDA_1 + 176 + k0) = o;
            } else if (c < 88) {
                int cc = c - 44;
                f16x4 o;
                if (cc == 43) {
                    o[0] = o[1] = o[2] = o[3] = (f16)0.f;
                } else {
                    float4 e[KK];
                    #pragma unroll
                    for (int k = 0; k < KK; ++k)
                        e[k] = *(const float4*)(edge_features + (size_t)s_nei[row * KK + k] * D + cc * 4);
                    float a0 = 0.f, a1 = 0.f, a2 = 0.f, a3 = 0.f;
                    #pragma unroll
                    for (int k = 0; k < KK; ++k) { a0 += e[k].x; a1 += e[k].y; a2 += e[k].z; a3 += e[k].w; }
                    o[0] = (f16)a0; o[1] = (f16)a1; o[2] = (f16)a2; o[3] = (f16)a3;
                }
                *(f16x4*)(As + row * LDA_1 + 352 + cc * 4) = o;
            } else {
                f16x8 z = {};
                *(f16x8*)(As + row * LDA_1 + 528 + (c - 88) * 8) = z;
            }
        } else {
            int j = idx - 32 * 90;
            int row = j / 22, cc = j - row * 22;
            *(f16x8*)(Acat + row * LDA_2 + 176 + cc * 8) =
                *(const f16x8*)(FEAT + (size_t)s_src[row] * 176 + cc * 8);
        }
    }
    __syncthreads();
    const int w = t >> 6, l = t & 63;
    const int lane16 = l & 15, koff = (l >> 4) * 8;
    const int rloc = (l >> 4) * 4;
    const int C0 = w * 16;
    {   // lin1: 12 waves x 16 cols x 2 rh, A from As (LDS), write H1 -> Acat[:,0:176)
        const f16* Al0 = As + lane16 * LDA_1 + koff;
        const f16* Al1 = As + (16 + lane16) * LDA_1 + koff;
        const f16* Bp  = W1 + (size_t)(C0 + lane16) * 544 + koff;
        f32x4 acc0 = {}, acc1 = {};
        #pragma unroll 2
        for (int s = 0; s < 17; ++s) {
            f16x8 a0 = *(const f16x8*)(Al0 + s * 32);
            f16x8 a1 = *(const f16x8*)(Al1 + s * 32);
            f16x8 b  = *(const f16x8*)(Bp + s * 32);
            acc0 = __builtin_amdgcn_mfma_f32_16x16x32_f16(a0, b, acc0, 0, 0, 0);
            acc1 = __builtin_amdgcn_mfma_f32_16x16x32_f16(a1, b, acc1, 0, 0, 0);
        }
        const int col = C0 + lane16;
        if (col < 176) {
            const float bb = (col < D) ? 10.0f * lin1_b[col] : 0.f;
            #pragma unroll
            for (int rh = 0; rh < 2; ++rh) {
                const f32x4& A = rh ? acc1 : acc0;
                #pragma unroll
                for (int reg = 0; reg < 4; ++reg) {
                    int r = rh * 16 + rloc + reg;
                    Acat[r * LDA_2 + col] = (col < D) ? (f16)fmaxf(A[reg] + bb, 0.f) : (f16)0.f;
                }
            }
        }
    }
    __syncthreads();
    f16* Emb = As;   // reuse
    {   // lin2: 12 waves x 16 cols x 2 rh, A from Acat (LDS), write Emb
        const f16* Al0 = Acat + lane16 * LDA_2 + koff;
        const f16* Al1 = Acat + (16 + lane16) * LDA_2 + koff;
        const f16* Bp  = W2 + (size_t)(C0 + lane16) * 352 + koff;
        f32x4 acc0 = {}, acc1 = {};
        #pragma unroll 2
        for (int s = 0; s < 11; ++s) {
            f16x8 a0 = *(const f16x8*)(Al0 + s * 32);
            f16x8 a1 = *(const f16x8*)(Al1 + s * 32);
            f16x8 b  = *(const f16x8*)(Bp + s * 32);
            acc0 = __builtin_amdgcn_mfma_f32_16x16x32_f16(a0, b, acc0, 0, 0, 0);
            acc1 = __builtin_amdgcn_mfma_f32_16x16x32_f16(a1, b, acc1, 0, 0, 0);
        }
        const int col = C0 + lane16;
        const float ec = (col < D) ? embc[col] : 0.f;
        #pragma unroll
        for (int rh = 0; rh < 2; ++rh) {
            const f32x4& A = rh ? acc1 : acc0;
            #pragma unroll
            for (int reg = 0; reg < 4; ++reg) {
                int r = rh * 16 + rloc + reg;
                Emb[r * LDE + col] = (col < D) ? (f16)(A[reg] + ec) : (f16)0.f;
            }
        }
    }
    __syncthreads();
    if (w < 10) {  // mlp1: wave w -> col-tile (w>>1), row-half (w&1)
        const int Cm = (w >> 1) * 16;
        const int rh = w & 1;
        const f16* Bp = Wm1 + (size_t)(Cm + lane16) * 192 + koff;
        const f16* Al = Emb + (rh * 16 + lane16) * LDE + koff;
        f32x4 acc = {};
        #pragma unroll
        for (int s = 0; s < 6; ++s) {
            f16x8 a = *(const f16x8*)(Al + s * 32);
            f16x8 b = *(const f16x8*)(Bp + s * 32);
            acc = __builtin_amdgcn_mfma_f32_16x16x32_f16(a, b, acc, 0, 0, 0);
        }
        const int col = Cm + lane16;
        #pragma unroll
        for (int reg = 0; reg < 4; ++reg)
            sH[rh * 16 + rloc + reg][col] = fmaxf(acc[reg] + b1[col], 0.f);
    }
    __syncthreads();
    if (t < 32) {
        float h2[10];
        #pragma unroll
        for (int j = 0; j < 10; ++j) h2[j] = s_b2[j];
        for (int f = 0; f < HIDD; ++f) {
            float hv = sH[t][f];
            #pragma unroll
            for (int j = 0; j < 10; ++j) h2[j] = fmaf(hv, s_w2[j * HIDD + f], h2[j]);
        }
        float logit = s_b3;
        #pragma unroll
        for (int j = 0; j < 10; ++j) logit += fmaxf(h2[j], 0.f) * s_w3[j];
        out[R0 + t] = 1.f / (1.f + expf(-logit));
    }
}

// ---------------- host ----------------

extern "C" void kernel_launch(void* const* d_in, const int* in_sizes, int n_in,
                              void* d_out, int out_size, void* d_ws, size_t ws_size,
                              hipStream_t stream) {
    const float* timestamps     = (const float*)d_in[0];
    const float* edge_features  = (const float*)d_in[1];
    const float* tnf            = (const float*)d_in[2];
    const float* node_mem       = (const float*)d_in[3];
    const float* last_updated   = (const float*)d_in[4];
    const float* nbr_edge_times = (const float*)d_in[5];
    const float* time_w         = (const float*)d_in[6];
    const float* time_b         = (const float*)d_in[7];
    const float* Wih            = (const float*)d_in[8];
    const float* Whh            = (const float*)d_in[9];
    const float* bih            = (const float*)d_in[10];
    const float* bhh            = (const float*)d_in[11];
    const float* lin1_w         = (const float*)d_in[12];
    const float* lin1_b         = (const float*)d_in[13];
    const float* lin2_w         = (const float*)d_in[14];
    const float* lin2_b         = (const float*)d_in[15];
    const float* w1             = (const float*)d_in[16];
    const float* b1             = (const float*)d_in[17];
    const float* w2             = (const float*)d_in[18];
    const float* b2             = (const float*)d_in[19];
    const float* w3             = (const float*)d_in[20];
    const float* b3             = (const float*)d_in[21];
    const int* sources          = (const int*)d_in[22];
    const int* destinations     = (const int*)d_in[23];
    const int* edge_idxs        = (const int*)d_in[24];
    const int* neighbors        = (const int*)d_in[25];
    const int* nbr_edge_idxs    = (const int*)d_in[26];
    float* out = (float*)d_out;

    char* p = (char*)d_ws;
    auto bump = [&p](size_t bytes) { char* r = p; p += (bytes + 255) & ~(size_t)255; return r; };
    int* last_idx = (int*)bump(N_NODES * 4);
    int* nid      = (int*)bump(N_NODES * 4);
    int* li_arr   = (int*)bump(N_NODES * 4);
    int* cnt      = (int*)bump(256);
    f16* Wc16     = (f16*)bump((size_t)192 * 704 * 2);
    f16* W1_16    = (f16*)bump((size_t)192 * 544 * 2);
    f16* W2_16    = (f16*)bump((size_t)192 * 352 * 2);
    f16* Wm1_16   = (f16*)bump((size_t)80 * 192 * 2);
    float* bcomb  = (float*)bump(D * 4);
    float* embc   = (float*)bump(D * 4);
    f16* FEAT16   = (f16*)bump((size_t)N_NODES * 176 * 2);

    hipLaunchKernelGGL(conv_weights, dim3((CR6 + 255) / 256), dim3(256), 0, stream,
                       Wih, Whh, lin1_w, lin2_w, w1, bih, bhh, lin2_b, time_b,
                       node_mem, tnf, Wc16, W1_16, W2_16, Wm1_16, bcomb, embc,
                       FEAT16, last_idx, cnt);

    hipLaunchKernelGGL(scatter_last, dim3(BB / 256), dim3(256), 0, stream, sources, last_idx);
    hipLaunchKernelGGL(compact_nodes, dim3((N_NODES + 255) / 256), dim3(256), 0, stream,
                       last_idx, nid, li_arr, cnt);

    hipLaunchKernelGGL(gemm_rnn_fused, dim3((N_NODES + 15) / 16), dim3(768), 0, stream,
                       Wc16, bcomb, nid, li_arr, cnt, destinations, edge_idxs,
                       timestamps, last_updated, node_mem, edge_features,
                       time_w, time_b, tnf, FEAT16);

    hipLaunchKernelGGL(embed_fused, dim3(BB / 32), dim3(768), 0, stream,
                       W1_16, lin1_b, W2_16, embc, Wm1_16, b1, w2, b2, w3, b3,
                       FEAT16, edge_features, timestamps, nbr_edge_times,
                       neighbors, nbr_edge_idxs, sources, time_w, time_b, out);
}

// Round 13
// 90.493 us; speedup vs baseline: 20.7658x; 1.0014x over previous
//
#include <hip/hip_runtime.h>
#include <math.h>

#define N_NODES 10000
#define BB 8192
#define KK 10
#define D 172
#define HIDD 80

typedef _Float16 f16;
typedef f16 f16x8 __attribute__((ext_vector_type(8)));
typedef f16 f16x4 __attribute__((ext_vector_type(4)));
typedef float f32x4 __attribute__((ext_vector_type(4)));

// ---------------- index prep ----------------

__global__ void scatter_last(const int* __restrict__ sources, int* __restrict__ last_idx) {
    int b = blockIdx.x * blockDim.x + threadIdx.x;
    if (b < BB) atomicMax(&last_idx[sources[b]], b);
}

__global__ void compact_nodes(const int* __restrict__ last_idx, int* __restrict__ nid,
                              int* __restrict__ li_arr, int* __restrict__ cnt) {
    int n = blockIdx.x * blockDim.x + threadIdx.x;
    if (n < N_NODES) {
        int li = last_idx[n];
        if (li >= 0) { int p = atomicAdd(cnt, 1); nid[p] = n; li_arr[p] = li; }
    }
}

// ---------------- conv_weights: flat 1D, 7 ranges (weights, consts, FEAT, init) ----------------
#define CR0 135168              // Wc 192*704
#define CR1 (CR0 + 104448)      // W1 192*544
#define CR2 (CR1 + 67584)       // W2 192*352
#define CR3 (CR2 + 15360)       // Wm1 80*192
#define CR4 (CR3 + 192)         // bcomb/embc
#define CR5 (CR4 + 220000)      // FEAT 10000*22
#define CR6 (CR5 + 10001)       // last_idx init + cnt

__global__ __launch_bounds__(256) void conv_weights(
    const float* __restrict__ Wih, const float* __restrict__ Whh,
    const float* __restrict__ lin1_w, const float* __restrict__ lin2_w,
    const float* __restrict__ w1,
    const float* __restrict__ bih, const float* __restrict__ bhh,
    const float* __restrict__ lin2_b, const float* __restrict__ tb,
    const float* __restrict__ node_mem, const float* __restrict__ tnf,
    f16* __restrict__ Wc, f16* __restrict__ W1, f16* __restrict__ W2,
    f16* __restrict__ Wm1, float* __restrict__ bcomb, float* __restrict__ embc,
    f16* __restrict__ FEAT, int* __restrict__ last_idx, int* __restrict__ cnt)
{
    const int idx = blockIdx.x * 256 + threadIdx.x;
    if (idx < CR0) {
        int n = idx / 704, k = idx % 704, seg = k / 176, kk = k % 176;
        float v = 0.f;
        if (n < D && kk < D) {
            v = Wih[n * 688 + seg * D + kk];
            if (seg == 0) v += Whh[n * D + kk];
        }
        Wc[idx] = (f16)v;
    } else if (idx < CR1) {
        int i = idx - CR0;
        int n = i / 544, k = i % 544, seg = k / 176, kk = k % 176;
        float v = 0.f;
        if (n < D && seg < 3 && kk < D) v = lin1_w[n * 516 + seg * D + kk];
        W1[i] = (f16)v;
    } else if (idx < CR2) {
        int i = idx - CR1;
        int n = i / 352, k = i % 352, seg = k / 176, kk = k % 176;
        float v = 0.f;
        if (n < D && kk < D) v = lin2_w[n * 516 + seg * D + kk];
        W2[i] = (f16)v;
    } else if (idx < CR3) {
        int i = idx - CR2;
        int n = i / 192, k = i % 192;
        Wm1[i] = (f16)((k < D) ? w1[n * D + k] : 0.f);
    } else if (idx < CR4) {
        int i = idx - CR3;
        if (i < D) {
            bcomb[i] = bih[i] + bhh[i];
            float acc = lin2_b[i];
            for (int j = 0; j < D; ++j) acc += lin2_w[i * 516 + 344 + j] * __cosf(tb[j]);
            embc[i] = acc;
        }
    } else if (idx < CR5) {
        int i = idx - CR4;
        int n = i / 22, k0 = (i % 22) * 8;
        f16x8 o;
        #pragma unroll
        for (int j = 0; j < 8; ++j) {
            int kk = k0 + j;
            float v = (kk < D) ? node_mem[(size_t)n * D + kk] + tnf[(size_t)n * D + kk] : 0.f;
            o[j] = (f16)v;
        }
        *(f16x8*)(FEAT + (size_t)n * 176 + k0) = o;
    } else if (idx < CR6) {
        int i = idx - CR5;
        if (i < N_NODES) last_idx[i] = -1;
        else *cnt = 0;
    }
}

// ---------------- GEMM 1 fused: BM=16 rows, 768 thr (11 MFMA waves x 16 cols) ----------------
#define LDA_R 712   // 704 + 8 pad halfs

__global__ __launch_bounds__(768) void gemm_rnn_fused(
    const f16* __restrict__ Wc, const float* __restrict__ bcomb,
    const int* __restrict__ nid, const int* __restrict__ li_arr, const int* __restrict__ cnt,
    const int* __restrict__ destinations, const int* __restrict__ edge_idxs,
    const float* __restrict__ timestamps, const float* __restrict__ last_updated,
    const float* __restrict__ node_mem, const float* __restrict__ edge_features,
    const float* __restrict__ tw, const float* __restrict__ tb,
    const float* __restrict__ tnf, f16* __restrict__ FEAT)
{
    const int c = *cnt;
    const int R0 = blockIdx.x * 16;
    if (R0 >= c) return;
    __shared__ f16 As[16 * LDA_R];
    __shared__ int s_n[16], s_dst[16], s_ei[16];
    __shared__ float s_dt[16];
    const int t = threadIdx.x;
    if (t < 16) {
        int i = R0 + t; if (i > c - 1) i = c - 1;
        int n = nid[i], li = li_arr[i];
        s_n[t] = n; s_dst[t] = destinations[li]; s_ei[t] = edge_idxs[li];
        s_dt[t] = timestamps[li] - last_updated[n];
    }
    __syncthreads();
    for (int idx = t; idx < 16 * 88; idx += 768) {
        int row = idx / 88, sub = idx - row * 88;
        int seg = sub / 22, cpos = sub - seg * 22, k0 = cpos * 8;
        f16x8 o;
        if (seg < 3) {
            int n = (seg == 0) ? s_n[row] : (seg == 1) ? s_dst[row] : s_ei[row];
            const float* src = ((seg < 2) ? node_mem : edge_features) + (size_t)n * D + k0;
            float4 lo = *(const float4*)src;
            float4 hi = (cpos < 21) ? *(const float4*)(src + 4) : make_float4(0.f, 0.f, 0.f, 0.f);
            o[0] = (f16)lo.x; o[1] = (f16)lo.y; o[2] = (f16)lo.z; o[3] = (f16)lo.w;
            o[4] = (f16)hi.x; o[5] = (f16)hi.y; o[6] = (f16)hi.z; o[7] = (f16)hi.w;
        } else {
            float dt = s_dt[row];
            #pragma unroll
            for (int j = 0; j < 8; ++j) {
                int kk = k0 + j;
                o[j] = (f16)((kk < D) ? __cosf(dt * tw[kk] + tb[kk]) : 0.f);
            }
        }
        *(f16x8*)(As + row * LDA_R + seg * 176 + k0) = o;
    }
    __syncthreads();
    const int w = t >> 6, l = t & 63;
    if (w >= 11) return;
    const int lane16 = l & 15, koff = (l >> 4) * 8;
    const int C0 = w * 16;
    const f16* Al = As + lane16 * LDA_R + koff;
    const f16* Bp = Wc + (size_t)(C0 + lane16) * 704 + koff;
    f32x4 acc = {};
    #pragma unroll 2
    for (int s = 0; s < 22; ++s) {
        f16x8 a = *(const f16x8*)(Al + s * 32);
        f16x8 b = *(const f16x8*)(Bp + s * 32);
        acc = __builtin_amdgcn_mfma_f32_16x16x32_f16(a, b, acc, 0, 0, 0);
    }
    const int col = C0 + lane16;
    const int rloc = (l >> 4) * 4;
    if (col < D) {
        const float bc = bcomb[col];
        #pragma unroll
        for (int reg = 0; reg < 4; ++reg) {
            int rl = rloc + reg;
            int r = R0 + rl;
            if (r >= c) continue;
            int n = s_n[rl];
            FEAT[(size_t)n * 176 + col] = (f16)(tanhf(acc[reg] + bc) + tnf[(size_t)n * D + col]);
        }
    }
}

// ---------------- embed_fused (BM=16): stage G + srcfeat -> lin1 -> lin2 -> mlp -> out ----------------
#define LDA_1 552   // G leading dim: 544 + 8
#define LDA_2 360   // Acat leading dim: 352 + 8
#define LDE  200    // Emb leading dim: 192 + 8

__global__ __launch_bounds__(768) void embed_fused(
    const f16* __restrict__ W1, const float* __restrict__ lin1_b,
    const f16* __restrict__ W2, const float* __restrict__ embc,
    const f16* __restrict__ Wm1, const float* __restrict__ b1,
    const float* __restrict__ w2, const float* __restrict__ b2,
    const float* __restrict__ w3, const float* __restrict__ b3,
    const f16* __restrict__ FEAT, const float* __restrict__ edge_features,
    const float* __restrict__ timestamps, const float* __restrict__ nbr_edge_times,
    const int* __restrict__ neighbors, const int* __restrict__ nbr_edge_idxs,
    const int* __restrict__ sources,
    const float* __restrict__ tw, const float* __restrict__ tb,
    float* __restrict__ out)
{
    __shared__ f16 As[16 * LDA_1];      // G staging; reused as Emb after lin1/lin2
    __shared__ f16 Acat[16 * LDA_2];    // [H1(0:176) | srcfeat(176:352)]
    __shared__ float sH[16][84];
    __shared__ float s_w2[10 * HIDD];
    __shared__ float s_b2[10], s_w3[10], s_b3;
    __shared__ int s_nbr[160], s_nei[160], s_src[16];
    __shared__ float s_net[160], s_ts[16];
    const int t = threadIdx.x;
    const int R0 = blockIdx.x * 16;
    for (int i = t; i < 10 * HIDD; i += 768) s_w2[i] = w2[i];
    if (t < 10) { s_b2[t] = b2[t]; s_w3[t] = w3[t]; }
    if (t == 10) s_b3 = b3[0];
    if (t >= 64 && t < 224) {
        int u = t - 64;
        s_nbr[u] = neighbors[R0 * KK + u];
    } else if (t >= 224 && t < 384) {
        int u = t - 224;
        s_nei[u] = nbr_edge_idxs[R0 * KK + u];
        s_net[u] = nbr_edge_times[R0 * KK + u];
    } else if (t >= 384 && t < 400) {
        s_ts[t - 384] = timestamps[R0 + t - 384];
    } else if (t >= 400 && t < 416) {
        s_src[t - 400] = sources[R0 + t - 400];
    }
    __syncthreads();
    // stage: G rows (90 chunks) + srcfeat (22 chunks) per row; 16*112 = 1792 items
    for (int idx = t; idx < 16 * 90 + 16 * 22; idx += 768) {
        if (idx < 16 * 90) {
            int row = idx / 90, c = idx - row * 90;
            if (c < 22) {
                int k0 = c * 8;
                f16x8 v[KK];
                #pragma unroll
                for (int k = 0; k < KK; ++k)
                    v[k] = *(const f16x8*)(FEAT + (size_t)s_nbr[row * KK + k] * 176 + k0);
                float a[8] = {};
                #pragma unroll
                for (int k = 0; k < KK; ++k) {
                    #pragma unroll
                    for (int j = 0; j < 8; ++j) a[j] += (float)v[k][j];
                }
                f16x8 o;
                #pragma unroll
                for (int j = 0; j < 8; ++j) o[j] = (f16)a[j];
                *(f16x8*)(As + row * LDA_1 + k0) = o;
            } else if (c < 44) {
                int k0 = (c - 22) * 8;
                float ts = s_ts[row];
                f16x8 o;
                #pragma unroll
                for (int j = 0; j < 8; ++j) {
                    int kk = k0 + j;
                    float a = 0.f;
                    if (kk < D) {
                        float w = tw[kk], bb = tb[kk];
                        #pragma unroll
                        for (int k = 0; k < KK; ++k) a += __cosf((ts - s_net[row * KK + k]) * w + bb);
                    }
                    o[j] = (f16)a;
                }
                *(f16x8*)(As + row * LDA_1 + 176 + k0) = o;
            } else if (c < 88) {
                int cc = c - 44;
                f16x4 o;
                if (cc == 43) {
                    o[0] = o[1] = o[2] = o[3] = (f16)0.f;
                } else {
                    float4 e[KK];
                    #pragma unroll
                    for (int k = 0; k < KK; ++k)
                        e[k] = *(const float4*)(edge_features + (size_t)s_nei[row * KK + k] * D + cc * 4);
                    float a0 = 0.f, a1 = 0.f, a2 = 0.f, a3 = 0.f;
                    #pragma unroll
                    for (int k = 0; k < KK; ++k) { a0 += e[k].x; a1 += e[k].y; a2 += e[k].z; a3 += e[k].w; }
                    o[0] = (f16)a0; o[1] = (f16)a1; o[2] = (f16)a2; o[3] = (f16)a3;
                }
                *(f16x4*)(As + row * LDA_1 + 352 + cc * 4) = o;
            } else {
                f16x8 z = {};
                *(f16x8*)(As + row * LDA_1 + 528 + (c - 88) * 8) = z;
            }
        } else {
            int j = idx - 16 * 90;
            int row = j / 22, cc = j - row * 22;
            *(f16x8*)(Acat + row * LDA_2 + 176 + cc * 8) =
                *(const f16x8*)(FEAT + (size_t)s_src[row] * 176 + cc * 8);
        }
    }
    __syncthreads();
    const int w = t >> 6, l = t & 63;
    const int lane16 = l & 15, koff = (l >> 4) * 8;
    const int rloc = (l >> 4) * 4;
    const int C0 = w * 16;
    if (w < 11) {   // lin1: 11 waves x 16 cols, A from As (LDS), write H1 -> Acat[:,0:176)
        const f16* Al = As + lane16 * LDA_1 + koff;
        const f16* Bp = W1 + (size_t)(C0 + lane16) * 544 + koff;
        f32x4 acc = {};
        #pragma unroll 2
        for (int s = 0; s < 17; ++s) {
            f16x8 a = *(const f16x8*)(Al + s * 32);
            f16x8 b = *(const f16x8*)(Bp + s * 32);
            acc = __builtin_amdgcn_mfma_f32_16x16x32_f16(a, b, acc, 0, 0, 0);
        }
        const int col = C0 + lane16;
        if (col < 176) {
            const float bb = (col < D) ? 10.0f * lin1_b[col] : 0.f;
            #pragma unroll
            for (int reg = 0; reg < 4; ++reg) {
                int r = rloc + reg;
                Acat[r * LDA_2 + col] = (col < D) ? (f16)fmaxf(acc[reg] + bb, 0.f) : (f16)0.f;
            }
        }
    }
    __syncthreads();
    f16* Emb = As;   // reuse
    if (w < 11) {   // lin2: 11 waves x 16 cols, A from Acat (LDS), write Emb
        const f16* Al = Acat + lane16 * LDA_2 + koff;
        const f16* Bp = W2 + (size_t)(C0 + lane16) * 352 + koff;
        f32x4 acc = {};
        #pragma unroll 2
        for (int s = 0; s < 11; ++s) {
            f16x8 a = *(const f16x8*)(Al + s * 32);
            f16x8 b = *(const f16x8*)(Bp + s * 32);
            acc = __builtin_amdgcn_mfma_f32_16x16x32_f16(a, b, acc, 0, 0, 0);
        }
        const int col = C0 + lane16;
        const float ec = (col < D) ? embc[col] : 0.f;
        #pragma unroll
        for (int reg = 0; reg < 4; ++reg) {
            int r = rloc + reg;
            Emb[r * LDE + col] = (col < D) ? (f16)(acc[reg] + ec) : (f16)0.f;
        }
    }
    __syncthreads();
    if (w < 5) {  // mlp1: wave w -> cols w*16..+16
        const int Cm = w * 16;
        const f16* Bp = Wm1 + (size_t)(Cm + lane16) * 192 + koff;
        const f16* Al = Emb + (lane16) * LDE + koff;
        f32x4 acc = {};
        #pragma unroll
        for (int s = 0; s < 6; ++s) {
            f16x8 a = *(const f16x8*)(Al + s * 32);
            f16x8 b = *(const f16x8*)(Bp + s * 32);
            acc = __builtin_amdgcn_mfma_f32_16x16x32_f16(a, b, acc, 0, 0, 0);
        }
        const int col = Cm + lane16;
        #pragma unroll
        for (int reg = 0; reg < 4; ++reg)
            sH[rloc + reg][col] = fmaxf(acc[reg] + b1[col], 0.f);
    }
    __syncthreads();
    if (t < 16) {
        float h2[10];
        #pragma unroll
        for (int j = 0; j < 10; ++j) h2[j] = s_b2[j];
        for (int f = 0; f < HIDD; ++f) {
            float hv = sH[t][f];
            #pragma unroll
            for (int j = 0; j < 10; ++j) h2[j] = fmaf(hv, s_w2[j * HIDD + f], h2[j]);
        }
        float logit = s_b3;
        #pragma unroll
        for (int j = 0; j < 10; ++j) logit += fmaxf(h2[j], 0.f) * s_w3[j];
        out[R0 + t] = 1.f / (1.f + expf(-logit));
    }
}

// ---------------- host ----------------

extern "C" void kernel_launch(void* const* d_in, const int* in_sizes, int n_in,
                              void* d_out, int out_size, void* d_ws, size_t ws_size,
                              hipStream_t stream) {
    const float* timestamps     = (const float*)d_in[0];
    const float* edge_features  = (const float*)d_in[1];
    const float* tnf            = (const float*)d_in[2];
    const float* node_mem       = (const float*)d_in[3];
    const float* last_updated   = (const float*)d_in[4];
    const float* nbr_edge_times = (const float*)d_in[5];
    const float* time_w         = (const float*)d_in[6];
    const float* time_b         = (const float*)d_in[7];
    const float* Wih            = (const float*)d_in[8];
    const float* Whh            = (const float*)d_in[9];
    const float* bih            = (const float*)d_in[10];
    const float* bhh            = (const float*)d_in[11];
    const float* lin1_w         = (const float*)d_in[12];
    const float* lin1_b         = (const float*)d_in[13];
    const float* lin2_w         = (const float*)d_in[14];
    const float* lin2_b         = (const float*)d_in[15];
    const float* w1             = (const float*)d_in[16];
    const float* b1             = (const float*)d_in[17];
    const float* w2             = (const float*)d_in[18];
    const float* b2             = (const float*)d_in[19];
    const float* w3             = (const float*)d_in[20];
    const float* b3             = (const float*)d_in[21];
    const int* sources          = (const int*)d_in[22];
    const int* destinations     = (const int*)d_in[23];
    const int* edge_idxs        = (const int*)d_in[24];
    const int* neighbors        = (const int*)d_in[25];
    const int* nbr_edge_idxs    = (const int*)d_in[26];
    float* out = (float*)d_out;

    char* p = (char*)d_ws;
    auto bump = [&p](size_t bytes) { char* r = p; p += (bytes + 255) & ~(size_t)255; return r; };
    int* last_idx = (int*)bump(N_NODES * 4);
    int* nid      = (int*)bump(N_NODES * 4);
    int* li_arr   = (int*)bump(N_NODES * 4);
    int* cnt      = (int*)bump(256);
    f16* Wc16     = (f16*)bump((size_t)192 * 704 * 2);
    f16* W1_16    = (f16*)bump((size_t)192 * 544 * 2);
    f16* W2_16    = (f16*)bump((size_t)192 * 352 * 2);
    f16* Wm1_16   = (f16*)bump((size_t)80 * 192 * 2);
    float* bcomb  = (float*)bump(D * 4);
    float* embc   = (float*)bump(D * 4);
    f16* FEAT16   = (f16*)bump((size_t)N_NODES * 176 * 2);

    hipLaunchKernelGGL(conv_weights, dim3((CR6 + 255) / 256), dim3(256), 0, stream,
                       Wih, Whh, lin1_w, lin2_w, w1, bih, bhh, lin2_b, time_b,
                       node_mem, tnf, Wc16, W1_16, W2_16, Wm1_16, bcomb, embc,
                       FEAT16, last_idx, cnt);

    hipLaunchKernelGGL(scatter_last, dim3(BB / 256), dim3(256), 0, stream, sources, last_idx);
    hipLaunchKernelGGL(compact_nodes, dim3((N_NODES + 255) / 256), dim3(256), 0, stream,
                       last_idx, nid, li_arr, cnt);

    hipLaunchKernelGGL(gemm_rnn_fused, dim3((N_NODES + 15) / 16), dim3(768), 0, stream,
                       Wc16, bcomb, nid, li_arr, cnt, destinations, edge_idxs,
                       timestamps, last_updated, node_mem, edge_features,
                       time_w, time_b, tnf, FEAT16);

    hipLaunchKernelGGL(embed_fused, dim3(BB / 16), dim3(768), 0, stream,
                       W1_16, lin1_b, W2_16, embc, Wm1_16, b1, w2, b2, w3, b3,
                       FEAT16, edge_features, timestamps, nbr_edge_times,
                       neighbors, nbr_edge_idxs, sources, time_w, time_b, out);
}